// Round 1
// baseline (10066.785 us; speedup 1.0000x reference)
//
#include <hip/hip_runtime.h>
#include <cstdint>
#include <cstddef>

#define T_SEQ 2048
#define DM    1024
#define HK    256
#define HV    512
#define NH    4
#define KDIM  1024
#define VDIM  2048

typedef __attribute__((ext_vector_type(8))) short bf16x8;
typedef __attribute__((ext_vector_type(4))) float f32x4;
#define AS1 __attribute__((address_space(1)))
#define AS3 __attribute__((address_space(3)))

// ---------------- f32 -> (hi, lo) bf16 split (RNE), vectorized x4 ------------
static __device__ inline unsigned short f2bf(float f) {
  unsigned u = __float_as_uint(f);
  unsigned rnd = 0x7fffu + ((u >> 16) & 1u);
  return (unsigned short)((u + rnd) >> 16);
}
static __device__ inline float bf2f(unsigned short h) {
  unsigned u = ((unsigned)h) << 16;
  return __uint_as_float(u);
}

__global__ __launch_bounds__(256) void cast_split(const float* __restrict__ in,
                                                  unsigned short* __restrict__ hi,
                                                  unsigned short* __restrict__ lo,
                                                  int n4) {
  int i = blockIdx.x * 256 + threadIdx.x;
  if (i >= n4) return;
  float4 v = ((const float4*)in)[i];
  ushort4 h, l;
  h.x = f2bf(v.x); l.x = f2bf(v.x - bf2f(h.x));
  h.y = f2bf(v.y); l.y = f2bf(v.y - bf2f(h.y));
  h.z = f2bf(v.z); l.z = f2bf(v.z - bf2f(h.z));
  h.w = f2bf(v.w); l.w = f2bf(v.w - bf2f(h.w));
  ((ushort4*)hi)[i] = h;
  ((ushort4*)lo)[i] = l;
}

// -------- split-precision bf16 MFMA GEMM: C = A @ W^T, A=Ah+Al, W=Wh+Wl ------
// C ~= Ah*Wh + Ah*Wl + Al*Wh (f32 accumulate; lo*lo term ~2^-16 rel, dropped).
// 128x128 tile, BK=32, 4 waves 2x2, wave = 64x64 = 4x4 16x16x32 frags.
__global__ __launch_bounds__(256) void gemm_bf16s(const unsigned short* __restrict__ Ah,
                                                  const unsigned short* __restrict__ Al,
                                                  const unsigned short* __restrict__ Wh,
                                                  const unsigned short* __restrict__ Wl,
                                                  float* __restrict__ C,
                                                  int M, int N, int K) {
  __shared__ unsigned short AhS[128 * 32];
  __shared__ unsigned short AlS[128 * 32];
  __shared__ unsigned short WhS[128 * 32];
  __shared__ unsigned short WlS[128 * 32];
  const int t = threadIdx.x;
  const int l = t & 63;
  const int w = t >> 6;
  const int bm = blockIdx.y * 128;
  const int bn = blockIdx.x * 128;
  const int wm = (w >> 1) * 64;
  const int wn = (w & 1) * 64;

  f32x4 acc[4][4];
#pragma unroll
  for (int i = 0; i < 4; ++i)
#pragma unroll
    for (int j = 0; j < 4; ++j)
#pragma unroll
      for (int r = 0; r < 4; ++r) acc[i][j][r] = 0.f;

  const int srow = w * 32 + (l >> 2);
  const int scol = (l & 3) * 8;
  const size_t gOffA = (size_t)(bm + srow) * K + scol;
  const size_t gOffW = (size_t)(bn + srow) * K + scol;
  const size_t rowStep = (size_t)16 * K;
  unsigned short* lAh0 = &AhS[(w * 32) * 32];
  unsigned short* lAh1 = &AhS[(w * 32 + 16) * 32];
  unsigned short* lAl0 = &AlS[(w * 32) * 32];
  unsigned short* lAl1 = &AlS[(w * 32 + 16) * 32];
  unsigned short* lWh0 = &WhS[(w * 32) * 32];
  unsigned short* lWh1 = &WhS[(w * 32 + 16) * 32];
  unsigned short* lWl0 = &WlS[(w * 32) * 32];
  unsigned short* lWl1 = &WlS[(w * 32 + 16) * 32];

  for (int k0 = 0; k0 < K; k0 += 32) {
    __syncthreads();
    __builtin_amdgcn_global_load_lds((const AS1 void*)(Ah + gOffA + k0),           (AS3 void*)lAh0, 16, 0, 0);
    __builtin_amdgcn_global_load_lds((const AS1 void*)(Ah + gOffA + rowStep + k0), (AS3 void*)lAh1, 16, 0, 0);
    __builtin_amdgcn_global_load_lds((const AS1 void*)(Al + gOffA + k0),           (AS3 void*)lAl0, 16, 0, 0);
    __builtin_amdgcn_global_load_lds((const AS1 void*)(Al + gOffA + rowStep + k0), (AS3 void*)lAl1, 16, 0, 0);
    __builtin_amdgcn_global_load_lds((const AS1 void*)(Wh + gOffW + k0),           (AS3 void*)lWh0, 16, 0, 0);
    __builtin_amdgcn_global_load_lds((const AS1 void*)(Wh + gOffW + rowStep + k0), (AS3 void*)lWh1, 16, 0, 0);
    __builtin_amdgcn_global_load_lds((const AS1 void*)(Wl + gOffW + k0),           (AS3 void*)lWl0, 16, 0, 0);
    __builtin_amdgcn_global_load_lds((const AS1 void*)(Wl + gOffW + rowStep + k0), (AS3 void*)lWl1, 16, 0, 0);
    __syncthreads();

    bf16x8 ah[4], al[4], bh[4], bl[4];
#pragma unroll
    for (int i = 0; i < 4; ++i) {
      int aoff = (wm + i * 16 + (l & 15)) * 32 + (l >> 4) * 8;
      int boff = (wn + i * 16 + (l & 15)) * 32 + (l >> 4) * 8;
      ah[i] = *(const bf16x8*)&AhS[aoff];
      al[i] = *(const bf16x8*)&AlS[aoff];
      bh[i] = *(const bf16x8*)&WhS[boff];
      bl[i] = *(const bf16x8*)&WlS[boff];
    }
#pragma unroll
    for (int i = 0; i < 4; ++i)
#pragma unroll
      for (int j = 0; j < 4; ++j) {
        acc[i][j] = __builtin_amdgcn_mfma_f32_16x16x32_bf16(ah[i], bh[j], acc[i][j], 0, 0, 0);
        acc[i][j] = __builtin_amdgcn_mfma_f32_16x16x32_bf16(ah[i], bl[j], acc[i][j], 0, 0, 0);
        acc[i][j] = __builtin_amdgcn_mfma_f32_16x16x32_bf16(al[i], bh[j], acc[i][j], 0, 0, 0);
      }
  }

  const int cr = (l >> 4) * 4;
  const int cc = l & 15;
#pragma unroll
  for (int i = 0; i < 4; ++i)
#pragma unroll
    for (int j = 0; j < 4; ++j)
#pragma unroll
      for (int r = 0; r < 4; ++r)
        C[(size_t)(bm + wm + i * 16 + cr + r) * N + (bn + wn + j * 16 + cc)] = acc[i][j][r];
}

// ---------------- RoPE (in-place on q and k), q also scaled by HK^-0.5 -------
__global__ __launch_bounds__(256) void rope_kernel(float* __restrict__ q,
                                                   float* __restrict__ k) {
  int idx = blockIdx.x * 256 + threadIdx.x;     // over B*T*H*128 = 4,194,304
  int f  = idx & 127;
  int h  = (idx >> 7) & 3;
  int tt = (idx >> 9) & 2047;
  int b  = idx >> 20;
  size_t a0 = ((size_t)(b * T_SEQ + tt)) * KDIM + h * HK + f;
  size_t a1 = a0 + 128;
  float invf = powf(10000.0f, -(float)f * (1.0f / 128.0f));
  float ang  = (float)tt * invf;
  float s, c;
  sincosf(ang, &s, &c);
  float q1 = q[a0], q2 = q[a1];
  q[a0] = (q1 * c - q2 * s) * 0.0625f;
  q[a1] = (q2 * c + q1 * s) * 0.0625f;
  float k1 = k[a0], k2 = k[a1];
  k[a0] = k1 * c - k2 * s;
  k[a1] = k2 * c + k1 * s;
}

// ---------------- Retention pass 1: intra-chunk (fully parallel) -------------
__global__ __launch_bounds__(256) void retn_intra(const float* __restrict__ q,
                                                  const float* __restrict__ k,
                                                  const float* __restrict__ v,
                                                  float* __restrict__ o) {
  const int n = blockIdx.x, h = blockIdx.y, b = blockIdx.z;
  const int t = threadIdx.x;
  const int t0 = n * 64;
  __shared__ float gpow[65];
  __shared__ float qS[64][65];
  __shared__ float kS[64][65];
  __shared__ float attnS[64][65];
  if (t <= 64) {
    float gamma = 1.0f - exp2f(-5.0f - (float)h);
    gpow[t] = powf(gamma, (float)t);
  }
  const size_t baseQK = (size_t)(b * T_SEQ + t0) * KDIM + h * HK;
  const size_t baseV  = (size_t)(b * T_SEQ + t0) * VDIM + h * HV;
  const int i0 = (t >> 4) * 4;
  const int j0 = (t & 15) * 4;
  float acc[4][4] = {};
  for (int s = 0; s < 4; ++s) {              // dk slices of 64
    __syncthreads();
#pragma unroll
    for (int r = 0; r < 16; ++r) {
      int idx = t + 256 * r;
      int row = idx >> 6, col = idx & 63;
      qS[row][col] = q[baseQK + (size_t)row * KDIM + s * 64 + col];
      kS[row][col] = k[baseQK + (size_t)row * KDIM + s * 64 + col];
    }
    __syncthreads();
    for (int d = 0; d < 64; ++d) {
      float a0 = qS[i0][d], a1 = qS[i0 + 1][d], a2 = qS[i0 + 2][d], a3 = qS[i0 + 3][d];
#pragma unroll
      for (int jj = 0; jj < 4; ++jj) {
        float bv = kS[j0 + jj][d];
        acc[0][jj] = fmaf(a0, bv, acc[0][jj]);
        acc[1][jj] = fmaf(a1, bv, acc[1][jj]);
        acc[2][jj] = fmaf(a2, bv, acc[2][jj]);
        acc[3][jj] = fmaf(a3, bv, acc[3][jj]);
      }
    }
  }
  __syncthreads();
#pragma unroll
  for (int ii = 0; ii < 4; ++ii)
#pragma unroll
    for (int jj = 0; jj < 4; ++jj) {
      int i = i0 + ii, j = j0 + jj;
      attnS[i][j] = (i >= j) ? acc[ii][jj] * gpow[i - j] : 0.0f;
    }
  float (*vS)[65] = qS;
  for (int vb = 0; vb < 8; ++vb) {
    __syncthreads();
#pragma unroll
    for (int r = 0; r < 16; ++r) {
      int idx = t + 256 * r;
      int row = idx >> 6, col = idx & 63;
      vS[row][col] = v[baseV + (size_t)row * VDIM + vb * 64 + col];
    }
    __syncthreads();
    float oa[4][4] = {};
    for (int j = 0; j < 64; ++j) {
      float a0 = attnS[i0][j], a1 = attnS[i0 + 1][j], a2 = attnS[i0 + 2][j], a3 = attnS[i0 + 3][j];
#pragma unroll
      for (int jj = 0; jj < 4; ++jj) {
        float bv = vS[j][j0 + jj];
        oa[0][jj] = fmaf(a0, bv, oa[0][jj]);
        oa[1][jj] = fmaf(a1, bv, oa[1][jj]);
        oa[2][jj] = fmaf(a2, bv, oa[2][jj]);
        oa[3][jj] = fmaf(a3, bv, oa[3][jj]);
      }
    }
#pragma unroll
    for (int ii = 0; ii < 4; ++ii)
#pragma unroll
      for (int jj = 0; jj < 4; ++jj)
        o[baseV + (size_t)(i0 + ii) * VDIM + vb * 64 + j0 + jj] = oa[ii][jj];
  }
}

// =================== Retention inter-chunk: two-level scan ===================
// The old single-pass scan used a 4-way dk split with atomicAdd for the o_inter
// reduction: 67.1M f32 atomics -> 1.07 GB HBM write traffic (measured
// WRITE_SIZE), cross-XCD line bouncing, 893us at 18% VALU. Replaced by:
//   A) retn_gstate: per (b,h,group of 8 chunks) local state sums T_g (g=0..2),
//      fully parallel, 64x64 tiles. Output in d_out scratch (24MB of 32MB).
//   B) retn_scan: elementwise exclusive scan over groups: T_g -> S_in[g+1].
//   C) retn_inter2: per (b,h,g,dv-tile64) WG carries the FULL dk=256 state in
//      registers (64/thread), seeded from S_in[g]; 8-chunk serial scan; o
//      updated with plain load+add+store (sole writer, NO atomics).
// Grid layouts put dv-siblings (which share the same q/k slab) 64 apart in
// linear block id => same XCD under %8 round-robin => L2 reuse.

// ---- pass A: group-local state sums --------------------------------------
__global__ __launch_bounds__(256) void retn_gstate(const float* __restrict__ k,
                                                   const float* __restrict__ v,
                                                   float* __restrict__ Tbuf) {
  // grid (16, 3, 32): x = b*4+h, y = g (0..2), z: dkt = z>>3, dvt = z&7
  const int bh = blockIdx.x; const int b = bh >> 2, h = bh & 3;
  const int g = blockIdx.y;
  const int dkt = blockIdx.z >> 3, dvt = blockIdx.z & 7;
  const int t = threadIdx.x;
  __shared__ float gpow[65];
  __shared__ __align__(16) float kS[64][68];
  __shared__ __align__(16) float vS[64][68];
  if (t <= 64) gpow[t] = powf(1.0f - exp2f(-5.0f - (float)h), (float)t);
  __syncthreads();
  const float gC = gpow[64];
  const size_t baseK = (size_t)(b * T_SEQ + g * 512) * KDIM + h * HK + dkt * 64;
  const size_t baseV = (size_t)(b * T_SEQ + g * 512) * VDIM + h * HV + dvt * 64;
  const int dk0 = (t & 15) * 4, c0 = (t >> 4) * 4;
  float S[4][4] = {};
  for (int c = 0; c < 8; ++c) {
    const int t0 = c * 64;
    __syncthreads();
#pragma unroll
    for (int r = 0; r < 4; ++r) {
      int idx = t + 256 * r; int row = idx >> 4, c4 = (idx & 15) * 4;
      float4 kv = *(const float4*)&k[baseK + (size_t)(t0 + row) * KDIM + c4];
      float kd = gpow[63 - row];
      kv.x *= kd; kv.y *= kd; kv.z *= kd; kv.w *= kd;
      *(float4*)&kS[row][c4] = kv;
      *(float4*)&vS[row][c4] = *(const float4*)&v[baseV + (size_t)(t0 + row) * VDIM + c4];
    }
    __syncthreads();
#pragma unroll
    for (int ii = 0; ii < 4; ++ii)
#pragma unroll
      for (int jj = 0; jj < 4; ++jj) S[ii][jj] *= gC;
    for (int j = 0; j < 64; ++j) {
      float kv[4], vv[4];
      *(float4*)&kv[0] = *(const float4*)&kS[j][dk0];
      *(float4*)&vv[0] = *(const float4*)&vS[j][c0];
#pragma unroll
      for (int ii = 0; ii < 4; ++ii)
#pragma unroll
        for (int jj = 0; jj < 4; ++jj)
          S[ii][jj] = fmaf(kv[ii], vv[jj], S[ii][jj]);
    }
  }
  const size_t tb = (((size_t)g * 16 + bh) * 256 + dkt * 64 + dk0) * 512 + (size_t)dvt * 64 + c0;
#pragma unroll
  for (int ii = 0; ii < 4; ++ii)
    *(float4*)&Tbuf[tb + (size_t)ii * 512] = make_float4(S[ii][0], S[ii][1], S[ii][2], S[ii][3]);
}

// ---- pass B: exclusive scan over the 4 groups (in-place) ------------------
// slot g holds T_g on entry; on exit slot g holds S_in[g+1]:
//   S_in[1]=T0 (slot0 unchanged), S_in[2]=gG*T0+T1, S_in[3]=gG*S_in[2]+T2.
__global__ __launch_bounds__(256) void retn_scan(float* __restrict__ Tbuf) {
  int i = blockIdx.x * 256 + threadIdx.x;   // float4 index within one g-slab
  int h = (i >> 15) & 3;                    // (i*4)>>17 & 3
  float gamma = 1.0f - exp2f(-5.0f - (float)h);
  float gG = powf(gamma, 512.0f);           // gC^8 = gamma^(64*8)
  float4* T = (float4*)Tbuf;
  const int slab = 524288;                  // 16*256*512/4
  float4 t0 = T[i], t1 = T[i + slab], t2 = T[i + 2 * slab];
  float4 s2, s3;
  s2.x = fmaf(gG, t0.x, t1.x); s2.y = fmaf(gG, t0.y, t1.y);
  s2.z = fmaf(gG, t0.z, t1.z); s2.w = fmaf(gG, t0.w, t1.w);
  s3.x = fmaf(gG, s2.x, t2.x); s3.y = fmaf(gG, s2.y, t2.y);
  s3.z = fmaf(gG, s2.z, t2.z); s3.w = fmaf(gG, s2.w, t2.w);
  T[i + slab] = s2; T[i + 2 * slab] = s3;
}

// ---- pass C: inter-chunk output, full-dk state in regs, no atomics --------
__global__ __launch_bounds__(256) void retn_inter2(const float* __restrict__ q,
                                                   const float* __restrict__ k,
                                                   const float* __restrict__ v,
                                                   float* __restrict__ o,
                                                   const float* __restrict__ Sbuf) {
  // grid (16, 4, 8): x = b*4+h, y = g, z = dvt
  const int bh = blockIdx.x; const int b = bh >> 2, h = bh & 3;
  const int g = blockIdx.y;
  const int dvt = blockIdx.z;
  const int t = threadIdx.x;
  __shared__ float gpow[65];
  __shared__ __align__(16) float xS[64][68];  // shared q-block / k-block stage
  __shared__ __align__(16) float sS[64][68];  // state-block publish
  __shared__ __align__(16) float vS[64][68];  // v chunk
  if (t <= 64) gpow[t] = powf(1.0f - exp2f(-5.0f - (float)h), (float)t);
  __syncthreads();
  const float gC = gpow[64];
  const int rq = (t & 15) * 4;        // state rows within a dk-block
  const int c0 = (t >> 4) * 4;        // state cols (dv within tile)
  const int i0 = (t >> 4) * 4;        // o-tile rows
  const int v0 = (t & 15) * 4;        // o-tile cols
  const size_t baseQK = (size_t)(b * T_SEQ + g * 512) * KDIM + h * HK;
  const size_t baseV  = (size_t)(b * T_SEQ + g * 512) * VDIM + h * HV + (size_t)dvt * 64;

  float S[4][4][4];                   // [dk-block][row][col], 64 regs
  if (g > 0) {
    const size_t sb = (((size_t)(g - 1) * 16 + bh) * 256) * 512 + (size_t)dvt * 64;
#pragma unroll
    for (int b4 = 0; b4 < 4; ++b4)
#pragma unroll
      for (int i = 0; i < 4; ++i)
        *(float4*)&S[b4][i][0] = *(const float4*)&Sbuf[sb + (size_t)(b4 * 64 + rq + i) * 512 + c0];
  } else {
#pragma unroll
    for (int b4 = 0; b4 < 4; ++b4)
#pragma unroll
      for (int i = 0; i < 4; ++i)
#pragma unroll
        for (int j = 0; j < 4; ++j) S[b4][i][j] = 0.f;
  }

  for (int c = 0; c < 8; ++c) {
    const int t0 = c * 64;
    // ---- o phase: oa = (q * cross_dec) @ S_incoming (skip when S == 0) ----
    if (g > 0 || c > 0) {
      float oa[4][4] = {};
#pragma unroll
      for (int b4 = 0; b4 < 4; ++b4) {
        __syncthreads();   // prev readers of sS/xS done
#pragma unroll
        for (int i = 0; i < 4; ++i)
          *(float4*)&sS[rq + i][c0] = *(float4*)&S[b4][i][0];
#pragma unroll
        for (int r = 0; r < 4; ++r) {
          int idx = t + 256 * r; int row = idx >> 4, c4 = (idx & 15) * 4;
          float4 qv = *(const float4*)&q[baseQK + (size_t)(t0 + row) * KDIM + b4 * 64 + c4];
          float gp = gpow[row + 1];
          qv.x *= gp; qv.y *= gp; qv.z *= gp; qv.w *= gp;
          *(float4*)&xS[row][c4] = qv;
        }
        __syncthreads();
        for (int d = 0; d < 64; d += 4) {
          float a_[4][4], s_[4][4];
#pragma unroll
          for (int ii = 0; ii < 4; ++ii)
            *(float4*)&a_[ii][0] = *(const float4*)&xS[i0 + ii][d];
#pragma unroll
          for (int dd = 0; dd < 4; ++dd)
            *(float4*)&s_[dd][0] = *(const float4*)&sS[d + dd][v0];
#pragma unroll
          for (int dd = 0; dd < 4; ++dd)
#pragma unroll
            for (int ii = 0; ii < 4; ++ii)
#pragma unroll
              for (int jj = 0; jj < 4; ++jj)
                oa[ii][jj] = fmaf(a_[ii][dd], s_[dd][jj], oa[ii][jj]);
        }
      }
      // o += oa : sole-writer read-modify-write, coalesced float4
#pragma unroll
      for (int ii = 0; ii < 4; ++ii) {
        size_t addr = baseV + (size_t)(t0 + i0 + ii) * VDIM + v0;
        float4 ov = *(const float4*)&o[addr];
        ov.x += oa[ii][0]; ov.y += oa[ii][1]; ov.z += oa[ii][2]; ov.w += oa[ii][3];
        *(float4*)&o[addr] = ov;
      }
    }
    // ---- update phase: S = gC*S + (k*k_dec)^T v ----
    __syncthreads();   // o-phase readers of xS done; prev chunk's vS readers done
#pragma unroll
    for (int r = 0; r < 4; ++r) {
      int idx = t + 256 * r; int row = idx >> 4, c4 = (idx & 15) * 4;
      *(float4*)&vS[row][c4] = *(const float4*)&v[baseV + (size_t)(t0 + row) * VDIM + c4];
    }
#pragma unroll
    for (int b4 = 0; b4 < 4; ++b4) {
      if (b4 > 0) __syncthreads();   // prev j-loop readers of xS done
#pragma unroll
      for (int r = 0; r < 4; ++r) {
        int idx = t + 256 * r; int row = idx >> 4, c4 = (idx & 15) * 4;
        float4 kv = *(const float4*)&k[baseQK + (size_t)(t0 + row) * KDIM + b4 * 64 + c4];
        float kd = gpow[63 - row];
        kv.x *= kd; kv.y *= kd; kv.z *= kd; kv.w *= kd;
        *(float4*)&xS[row][c4] = kv;
      }
      __syncthreads();
#pragma unroll
      for (int ii = 0; ii < 4; ++ii)
#pragma unroll
        for (int jj = 0; jj < 4; ++jj) S[b4][ii][jj] *= gC;
      for (int j = 0; j < 64; ++j) {
        float kv[4], vv[4];
        *(float4*)&kv[0] = *(const float4*)&xS[j][rq];
        *(float4*)&vv[0] = *(const float4*)&vS[j][c0];
#pragma unroll
        for (int ii = 0; ii < 4; ++ii)
#pragma unroll
          for (int jj = 0; jj < 4; ++jj)
            S[b4][ii][jj] = fmaf(kv[ii], vv[jj], S[b4][ii][jj]);
      }
    }
  }
}

// ---------------- RMS group-norm over HEAD_V + SiLU(g) gate (in-place) -------
__global__ __launch_bounds__(256) void norm_gate(float* __restrict__ o,
                                                 const float* __restrict__ g,
                                                 const float* __restrict__ gnw) {
  const int row = blockIdx.x;
  const size_t base = (size_t)row * 512;
  const int t = threadIdx.x;
  float x0 = o[base + t], x1 = o[base + t + 256];
  float ss = x0 * x0 + x1 * x1;
#pragma unroll
  for (int off = 32; off > 0; off >>= 1) ss += __shfl_down(ss, off, 64);
  __shared__ float wsum[4];
  if ((t & 63) == 0) wsum[t >> 6] = ss;
  __syncthreads();
  float tot = wsum[0] + wsum[1] + wsum[2] + wsum[3];
  float scale = rsqrtf(tot * (1.0f / 512.0f) + 1e-5f);
  float g0 = g[base + t], g1 = g[base + t + 256];
  o[base + t]       = x0 * scale * gnw[t]       * (g0 / (1.0f + expf(-g0)));
  o[base + t + 256] = x1 * scale * gnw[t + 256] * (g1 / (1.0f + expf(-g1)));
}

extern "C" void kernel_launch(void* const* d_in, const int* in_sizes, int n_in,
                              void* d_out, int out_size, void* d_ws, size_t ws_size,
                              hipStream_t stream) {
  const float* x   = (const float*)d_in[0];
  const float* Wq  = (const float*)d_in[1];
  const float* Wk  = (const float*)d_in[2];
  const float* Wv  = (const float*)d_in[3];
  const float* Wg  = (const float*)d_in[4];
  const float* Wo  = (const float*)d_in[5];
  const float* gnw = (const float*)d_in[6];
  float* out = (float*)d_out;

  // workspace = 256 MiB exactly:
  // [q 32][k 32][v 64][o 64][x-splits 32][W-splits 32]
  // o-splits (64) alias dead v; g (64) aliases dead q+k.
  // d_out (32 MiB) doubles as group-state scratch (24 MiB) until final GEMM.
  const size_t M8 = (size_t)8192;
  float* q  = (float*)d_ws;
  float* kk = q  + M8 * 1024;
  float* v  = kk + M8 * 1024;
  float* o  = v  + M8 * 2048;
  unsigned short* xh  = (unsigned short*)(o + M8 * 2048);
  unsigned short* xl  = xh  + M8 * 1024;
  unsigned short* wqh = xl  + M8 * 1024;
  unsigned short* wql = wqh + (size_t)1024 * 1024;
  unsigned short* wkh = wql + (size_t)1024 * 1024;
  unsigned short* wkl = wkh + (size_t)1024 * 1024;
  unsigned short* wvh = wkl + (size_t)1024 * 1024;
  unsigned short* wvl = wvh + (size_t)2048 * 1024;
  unsigned short* wgh = wvl + (size_t)2048 * 1024;
  unsigned short* wgl = wgh + (size_t)2048 * 1024;
  unsigned short* woh = wgl + (size_t)2048 * 1024;
  unsigned short* wol = woh + (size_t)2048 * 1024;
  unsigned short* oh  = (unsigned short*)v;
  unsigned short* ol  = oh + M8 * 2048;
  float* g = q;
  float* Tbuf = (float*)d_out;   // 24 MiB scratch, dead until final GEMM

  dim3 blk(256);
  cast_split<<<dim3(8192), blk, 0, stream>>>(x,  xh,  xl,  2097152);
  cast_split<<<dim3(1024), blk, 0, stream>>>(Wq, wqh, wql, 262144);
  cast_split<<<dim3(1024), blk, 0, stream>>>(Wk, wkh, wkl, 262144);
  cast_split<<<dim3(2048), blk, 0, stream>>>(Wv, wvh, wvl, 524288);
  cast_split<<<dim3(2048), blk, 0, stream>>>(Wg, wgh, wgl, 524288);
  cast_split<<<dim3(2048), blk, 0, stream>>>(Wo, woh, wol, 524288);

  gemm_bf16s<<<dim3(8, 64),  blk, 0, stream>>>(xh, xl, wqh, wql, q,  8192, 1024, 1024);
  gemm_bf16s<<<dim3(8, 64),  blk, 0, stream>>>(xh, xl, wkh, wkl, kk, 8192, 1024, 1024);
  gemm_bf16s<<<dim3(16, 64), blk, 0, stream>>>(xh, xl, wvh, wvl, v,  8192, 2048, 1024);
  rope_kernel<<<dim3(16384), blk, 0, stream>>>(q, kk);
  retn_gstate<<<dim3(16, 3, 32), blk, 0, stream>>>(kk, v, Tbuf);
  retn_scan<<<dim3(2048), blk, 0, stream>>>(Tbuf);
  retn_intra<<<dim3(32, 4, 4),  blk, 0, stream>>>(q, kk, v, o);
  retn_inter2<<<dim3(16, 4, 8), blk, 0, stream>>>(q, kk, v, o, Tbuf);
  gemm_bf16s<<<dim3(16, 64), blk, 0, stream>>>(xh, xl, wgh, wgl, g, 8192, 2048, 1024);
  norm_gate<<<dim3(32768), blk, 0, stream>>>(o, g, gnw);
  cast_split<<<dim3(16384), blk, 0, stream>>>(o, oh, ol, 4194304);
  gemm_bf16s<<<dim3(8, 64),  blk, 0, stream>>>(oh, ol, woh, wol, out, 8192, 1024, 2048);
}

// Round 2
// 9975.648 us; speedup vs baseline: 1.0091x; 1.0091x over previous
//
#include <hip/hip_runtime.h>
#include <cstdint>
#include <cstddef>

#define T_SEQ 2048
#define DM    1024
#define HK    256
#define HV    512
#define NH    4
#define KDIM  1024
#define VDIM  2048

typedef __attribute__((ext_vector_type(8))) short bf16x8;
typedef __attribute__((ext_vector_type(4))) float f32x4;
#define AS1 __attribute__((address_space(1)))
#define AS3 __attribute__((address_space(3)))

// ---------------- f32 -> (hi, lo) bf16 split (RNE), vectorized x4 ------------
static __device__ inline unsigned short f2bf(float f) {
  unsigned u = __float_as_uint(f);
  unsigned rnd = 0x7fffu + ((u >> 16) & 1u);
  return (unsigned short)((u + rnd) >> 16);
}
static __device__ inline float bf2f(unsigned short h) {
  unsigned u = ((unsigned)h) << 16;
  return __uint_as_float(u);
}

__global__ __launch_bounds__(256) void cast_split(const float* __restrict__ in,
                                                  unsigned short* __restrict__ hi,
                                                  unsigned short* __restrict__ lo,
                                                  int n4) {
  int i = blockIdx.x * 256 + threadIdx.x;
  if (i >= n4) return;
  float4 v = ((const float4*)in)[i];
  ushort4 h, l;
  h.x = f2bf(v.x); l.x = f2bf(v.x - bf2f(h.x));
  h.y = f2bf(v.y); l.y = f2bf(v.y - bf2f(h.y));
  h.z = f2bf(v.z); l.z = f2bf(v.z - bf2f(h.z));
  h.w = f2bf(v.w); l.w = f2bf(v.w - bf2f(h.w));
  ((ushort4*)hi)[i] = h;
  ((ushort4*)lo)[i] = l;
}

// -------- split-precision bf16 MFMA GEMM: C = A @ W^T, A=Ah+Al, W=Wh+Wl ------
// C ~= Ah*Wh + Ah*Wl + Al*Wh (f32 accumulate; lo*lo term ~2^-16 rel, dropped).
// 128x128 tile, BK=32, 4 waves 2x2, wave = 64x64 = 4x4 16x16x32 frags.
__global__ __launch_bounds__(256) void gemm_bf16s(const unsigned short* __restrict__ Ah,
                                                  const unsigned short* __restrict__ Al,
                                                  const unsigned short* __restrict__ Wh,
                                                  const unsigned short* __restrict__ Wl,
                                                  float* __restrict__ C,
                                                  int M, int N, int K) {
  __shared__ unsigned short AhS[128 * 32];
  __shared__ unsigned short AlS[128 * 32];
  __shared__ unsigned short WhS[128 * 32];
  __shared__ unsigned short WlS[128 * 32];
  const int t = threadIdx.x;
  const int l = t & 63;
  const int w = t >> 6;
  const int bm = blockIdx.y * 128;
  const int bn = blockIdx.x * 128;
  const int wm = (w >> 1) * 64;
  const int wn = (w & 1) * 64;

  f32x4 acc[4][4];
#pragma unroll
  for (int i = 0; i < 4; ++i)
#pragma unroll
    for (int j = 0; j < 4; ++j)
#pragma unroll
      for (int r = 0; r < 4; ++r) acc[i][j][r] = 0.f;

  const int srow = w * 32 + (l >> 2);
  const int scol = (l & 3) * 8;
  const size_t gOffA = (size_t)(bm + srow) * K + scol;
  const size_t gOffW = (size_t)(bn + srow) * K + scol;
  const size_t rowStep = (size_t)16 * K;
  unsigned short* lAh0 = &AhS[(w * 32) * 32];
  unsigned short* lAh1 = &AhS[(w * 32 + 16) * 32];
  unsigned short* lAl0 = &AlS[(w * 32) * 32];
  unsigned short* lAl1 = &AlS[(w * 32 + 16) * 32];
  unsigned short* lWh0 = &WhS[(w * 32) * 32];
  unsigned short* lWh1 = &WhS[(w * 32 + 16) * 32];
  unsigned short* lWl0 = &WlS[(w * 32) * 32];
  unsigned short* lWl1 = &WlS[(w * 32 + 16) * 32];

  for (int k0 = 0; k0 < K; k0 += 32) {
    __syncthreads();
    __builtin_amdgcn_global_load_lds((const AS1 void*)(Ah + gOffA + k0),           (AS3 void*)lAh0, 16, 0, 0);
    __builtin_amdgcn_global_load_lds((const AS1 void*)(Ah + gOffA + rowStep + k0), (AS3 void*)lAh1, 16, 0, 0);
    __builtin_amdgcn_global_load_lds((const AS1 void*)(Al + gOffA + k0),           (AS3 void*)lAl0, 16, 0, 0);
    __builtin_amdgcn_global_load_lds((const AS1 void*)(Al + gOffA + rowStep + k0), (AS3 void*)lAl1, 16, 0, 0);
    __builtin_amdgcn_global_load_lds((const AS1 void*)(Wh + gOffW + k0),           (AS3 void*)lWh0, 16, 0, 0);
    __builtin_amdgcn_global_load_lds((const AS1 void*)(Wh + gOffW + rowStep + k0), (AS3 void*)lWh1, 16, 0, 0);
    __builtin_amdgcn_global_load_lds((const AS1 void*)(Wl + gOffW + k0),           (AS3 void*)lWl0, 16, 0, 0);
    __builtin_amdgcn_global_load_lds((const AS1 void*)(Wl + gOffW + rowStep + k0), (AS3 void*)lWl1, 16, 0, 0);
    __syncthreads();

    bf16x8 ah[4], al[4], bh[4], bl[4];
#pragma unroll
    for (int i = 0; i < 4; ++i) {
      int aoff = (wm + i * 16 + (l & 15)) * 32 + (l >> 4) * 8;
      int boff = (wn + i * 16 + (l & 15)) * 32 + (l >> 4) * 8;
      ah[i] = *(const bf16x8*)&AhS[aoff];
      al[i] = *(const bf16x8*)&AlS[aoff];
      bh[i] = *(const bf16x8*)&WhS[boff];
      bl[i] = *(const bf16x8*)&WlS[boff];
    }
#pragma unroll
    for (int i = 0; i < 4; ++i)
#pragma unroll
      for (int j = 0; j < 4; ++j) {
        acc[i][j] = __builtin_amdgcn_mfma_f32_16x16x32_bf16(ah[i], bh[j], acc[i][j], 0, 0, 0);
        acc[i][j] = __builtin_amdgcn_mfma_f32_16x16x32_bf16(ah[i], bl[j], acc[i][j], 0, 0, 0);
        acc[i][j] = __builtin_amdgcn_mfma_f32_16x16x32_bf16(al[i], bh[j], acc[i][j], 0, 0, 0);
      }
  }

  const int cr = (l >> 4) * 4;
  const int cc = l & 15;
#pragma unroll
  for (int i = 0; i < 4; ++i)
#pragma unroll
    for (int j = 0; j < 4; ++j)
#pragma unroll
      for (int r = 0; r < 4; ++r)
        C[(size_t)(bm + wm + i * 16 + cr + r) * N + (bn + wn + j * 16 + cc)] = acc[i][j][r];
}

// ---------------- RoPE (in-place on q and k), q also scaled by HK^-0.5 -------
__global__ __launch_bounds__(256) void rope_kernel(float* __restrict__ q,
                                                   float* __restrict__ k) {
  int idx = blockIdx.x * 256 + threadIdx.x;     // over B*T*H*128 = 4,194,304
  int f  = idx & 127;
  int h  = (idx >> 7) & 3;
  int tt = (idx >> 9) & 2047;
  int b  = idx >> 20;
  size_t a0 = ((size_t)(b * T_SEQ + tt)) * KDIM + h * HK + f;
  size_t a1 = a0 + 128;
  float invf = powf(10000.0f, -(float)f * (1.0f / 128.0f));
  float ang  = (float)tt * invf;
  float s, c;
  sincosf(ang, &s, &c);
  float q1 = q[a0], q2 = q[a1];
  q[a0] = (q1 * c - q2 * s) * 0.0625f;
  q[a1] = (q2 * c + q1 * s) * 0.0625f;
  float k1 = k[a0], k2 = k[a1];
  k[a0] = k1 * c - k2 * s;
  k[a1] = k2 * c + k1 * s;
}

// ---------------- Retention pass 1: intra-chunk (fully parallel) -------------
__global__ __launch_bounds__(256) void retn_intra(const float* __restrict__ q,
                                                  const float* __restrict__ k,
                                                  const float* __restrict__ v,
                                                  float* __restrict__ o) {
  const int n = blockIdx.x, h = blockIdx.y, b = blockIdx.z;
  const int t = threadIdx.x;
  const int t0 = n * 64;
  __shared__ float gpow[65];
  __shared__ float qS[64][65];
  __shared__ float kS[64][65];
  __shared__ float attnS[64][65];
  if (t <= 64) {
    float gamma = 1.0f - exp2f(-5.0f - (float)h);
    gpow[t] = powf(gamma, (float)t);
  }
  const size_t baseQK = (size_t)(b * T_SEQ + t0) * KDIM + h * HK;
  const size_t baseV  = (size_t)(b * T_SEQ + t0) * VDIM + h * HV;
  const int i0 = (t >> 4) * 4;
  const int j0 = (t & 15) * 4;
  float acc[4][4] = {};
  for (int s = 0; s < 4; ++s) {              // dk slices of 64
    __syncthreads();
#pragma unroll
    for (int r = 0; r < 16; ++r) {
      int idx = t + 256 * r;
      int row = idx >> 6, col = idx & 63;
      qS[row][col] = q[baseQK + (size_t)row * KDIM + s * 64 + col];
      kS[row][col] = k[baseQK + (size_t)row * KDIM + s * 64 + col];
    }
    __syncthreads();
    for (int d = 0; d < 64; ++d) {
      float a0 = qS[i0][d], a1 = qS[i0 + 1][d], a2 = qS[i0 + 2][d], a3 = qS[i0 + 3][d];
#pragma unroll
      for (int jj = 0; jj < 4; ++jj) {
        float bv = kS[j0 + jj][d];
        acc[0][jj] = fmaf(a0, bv, acc[0][jj]);
        acc[1][jj] = fmaf(a1, bv, acc[1][jj]);
        acc[2][jj] = fmaf(a2, bv, acc[2][jj]);
        acc[3][jj] = fmaf(a3, bv, acc[3][jj]);
      }
    }
  }
  __syncthreads();
#pragma unroll
  for (int ii = 0; ii < 4; ++ii)
#pragma unroll
    for (int jj = 0; jj < 4; ++jj) {
      int i = i0 + ii, j = j0 + jj;
      attnS[i][j] = (i >= j) ? acc[ii][jj] * gpow[i - j] : 0.0f;
    }
  float (*vS)[65] = qS;
  for (int vb = 0; vb < 8; ++vb) {
    __syncthreads();
#pragma unroll
    for (int r = 0; r < 16; ++r) {
      int idx = t + 256 * r;
      int row = idx >> 6, col = idx & 63;
      vS[row][col] = v[baseV + (size_t)row * VDIM + vb * 64 + col];
    }
    __syncthreads();
    float oa[4][4] = {};
    for (int j = 0; j < 64; ++j) {
      float a0 = attnS[i0][j], a1 = attnS[i0 + 1][j], a2 = attnS[i0 + 2][j], a3 = attnS[i0 + 3][j];
#pragma unroll
      for (int jj = 0; jj < 4; ++jj) {
        float bv = vS[j][j0 + jj];
        oa[0][jj] = fmaf(a0, bv, oa[0][jj]);
        oa[1][jj] = fmaf(a1, bv, oa[1][jj]);
        oa[2][jj] = fmaf(a2, bv, oa[2][jj]);
        oa[3][jj] = fmaf(a3, bv, oa[3][jj]);
      }
    }
#pragma unroll
    for (int ii = 0; ii < 4; ++ii)
#pragma unroll
      for (int jj = 0; jj < 4; ++jj)
        o[baseV + (size_t)(i0 + ii) * VDIM + vb * 64 + j0 + jj] = oa[ii][jj];
  }
}

// =================== Retention inter-chunk: two-level scan ===================
//   A) retn_gstate: per (b,h,group of 8 chunks) local state sums T_g (g=0..2),
//      fully parallel, 64x64 tiles. Output in d_out scratch (24MB of 32MB).
//   B) retn_scan: elementwise exclusive scan over groups: T_g -> S_in[g+1].
//   C) retn_inter2: per (b,h,g,dv-tile64) WG carries the FULL dk=256 state in
//      registers (64/thread), seeded from S_in[g]; 8-chunk serial scan; o
//      updated with plain load+add+store (sole writer, NO atomics).
// ROUND-1 POST-MORTEM: v1 of retn_inter2 took the address of S via float4*
// punning (seed load + publish), which defeated SROA -> S demoted to scratch:
// VGPR pinned at 256, FETCH 12GB / WRITE 5.9GB (25x algorithmic bytes),
// VALUBusy 2%, 9.1ms. Fix: S is ONLY accessed with compile-time scalar
// indices; float4 data moves go through temps (load) / make_float4 (publish).

// ---- pass A: group-local state sums --------------------------------------
__global__ __launch_bounds__(256) void retn_gstate(const float* __restrict__ k,
                                                   const float* __restrict__ v,
                                                   float* __restrict__ Tbuf) {
  // grid (16, 3, 32): x = b*4+h, y = g (0..2), z: dkt = z>>3, dvt = z&7
  const int bh = blockIdx.x; const int b = bh >> 2, h = bh & 3;
  const int g = blockIdx.y;
  const int dkt = blockIdx.z >> 3, dvt = blockIdx.z & 7;
  const int t = threadIdx.x;
  __shared__ float gpow[65];
  __shared__ __align__(16) float kS[64][68];
  __shared__ __align__(16) float vS[64][68];
  if (t <= 64) gpow[t] = powf(1.0f - exp2f(-5.0f - (float)h), (float)t);
  __syncthreads();
  const float gC = gpow[64];
  const size_t baseK = (size_t)(b * T_SEQ + g * 512) * KDIM + h * HK + dkt * 64;
  const size_t baseV = (size_t)(b * T_SEQ + g * 512) * VDIM + h * HV + dvt * 64;
  const int dk0 = (t & 15) * 4, c0 = (t >> 4) * 4;
  float S[4][4] = {};
  for (int c = 0; c < 8; ++c) {
    const int t0 = c * 64;
    __syncthreads();
#pragma unroll
    for (int r = 0; r < 4; ++r) {
      int idx = t + 256 * r; int row = idx >> 4, c4 = (idx & 15) * 4;
      float4 kv = *(const float4*)&k[baseK + (size_t)(t0 + row) * KDIM + c4];
      float kd = gpow[63 - row];
      kv.x *= kd; kv.y *= kd; kv.z *= kd; kv.w *= kd;
      *(float4*)&kS[row][c4] = kv;
      *(float4*)&vS[row][c4] = *(const float4*)&v[baseV + (size_t)(t0 + row) * VDIM + c4];
    }
    __syncthreads();
#pragma unroll
    for (int ii = 0; ii < 4; ++ii)
#pragma unroll
      for (int jj = 0; jj < 4; ++jj) S[ii][jj] *= gC;
    for (int j = 0; j < 64; ++j) {
      float4 kv = *(const float4*)&kS[j][dk0];
      float4 vv = *(const float4*)&vS[j][c0];
      S[0][0] = fmaf(kv.x, vv.x, S[0][0]); S[0][1] = fmaf(kv.x, vv.y, S[0][1]);
      S[0][2] = fmaf(kv.x, vv.z, S[0][2]); S[0][3] = fmaf(kv.x, vv.w, S[0][3]);
      S[1][0] = fmaf(kv.y, vv.x, S[1][0]); S[1][1] = fmaf(kv.y, vv.y, S[1][1]);
      S[1][2] = fmaf(kv.y, vv.z, S[1][2]); S[1][3] = fmaf(kv.y, vv.w, S[1][3]);
      S[2][0] = fmaf(kv.z, vv.x, S[2][0]); S[2][1] = fmaf(kv.z, vv.y, S[2][1]);
      S[2][2] = fmaf(kv.z, vv.z, S[2][2]); S[2][3] = fmaf(kv.z, vv.w, S[2][3]);
      S[3][0] = fmaf(kv.w, vv.x, S[3][0]); S[3][1] = fmaf(kv.w, vv.y, S[3][1]);
      S[3][2] = fmaf(kv.w, vv.z, S[3][2]); S[3][3] = fmaf(kv.w, vv.w, S[3][3]);
    }
  }
  const size_t tb = (((size_t)g * 16 + bh) * 256 + dkt * 64 + dk0) * 512 + (size_t)dvt * 64 + c0;
#pragma unroll
  for (int ii = 0; ii < 4; ++ii)
    *(float4*)&Tbuf[tb + (size_t)ii * 512] = make_float4(S[ii][0], S[ii][1], S[ii][2], S[ii][3]);
}

// ---- pass B: exclusive scan over the 4 groups (in-place) ------------------
// slot g holds T_g on entry; on exit slot g holds S_in[g+1]:
//   S_in[1]=T0 (slot0 unchanged), S_in[2]=gG*T0+T1, S_in[3]=gG*S_in[2]+T2.
__global__ __launch_bounds__(256) void retn_scan(float* __restrict__ Tbuf) {
  int i = blockIdx.x * 256 + threadIdx.x;   // float4 index within one g-slab
  int h = (i >> 15) & 3;                    // (i*4)>>17 & 3
  float gamma = 1.0f - exp2f(-5.0f - (float)h);
  float gG = powf(gamma, 512.0f);           // gC^8 = gamma^(64*8)
  float4* T = (float4*)Tbuf;
  const int slab = 524288;                  // 16*256*512/4
  float4 t0 = T[i], t1 = T[i + slab], t2 = T[i + 2 * slab];
  float4 s2, s3;
  s2.x = fmaf(gG, t0.x, t1.x); s2.y = fmaf(gG, t0.y, t1.y);
  s2.z = fmaf(gG, t0.z, t1.z); s2.w = fmaf(gG, t0.w, t1.w);
  s3.x = fmaf(gG, s2.x, t2.x); s3.y = fmaf(gG, s2.y, t2.y);
  s3.z = fmaf(gG, s2.z, t2.z); s3.w = fmaf(gG, s2.w, t2.w);
  T[i + slab] = s2; T[i + 2 * slab] = s3;
}

// ---- pass C: inter-chunk output, full-dk state in regs, no atomics --------
__global__ __launch_bounds__(256) void retn_inter2(const float* __restrict__ q,
                                                   const float* __restrict__ k,
                                                   const float* __restrict__ v,
                                                   float* __restrict__ o,
                                                   const float* __restrict__ Sbuf) {
  // grid (16, 4, 8): x = b*4+h, y = g, z = dvt
  const int bh = blockIdx.x; const int b = bh >> 2, h = bh & 3;
  const int g = blockIdx.y;
  const int dvt = blockIdx.z;
  const int t = threadIdx.x;
  __shared__ float gpow[65];
  __shared__ __align__(16) float xS[64][68];  // shared q-block / k-block stage
  __shared__ __align__(16) float sS[64][68];  // state-block publish
  __shared__ __align__(16) float vS[64][68];  // v chunk
  if (t <= 64) gpow[t] = powf(1.0f - exp2f(-5.0f - (float)h), (float)t);
  __syncthreads();
  const float gC = gpow[64];
  const int rq = (t & 15) * 4;        // state rows within a dk-block
  const int c0 = (t >> 4) * 4;        // state cols (dv within tile)
  const int i0 = (t >> 4) * 4;        // o-tile rows
  const int v0 = (t & 15) * 4;        // o-tile cols
  const size_t baseQK = (size_t)(b * T_SEQ + g * 512) * KDIM + h * HK;
  const size_t baseV  = (size_t)(b * T_SEQ + g * 512) * VDIM + h * HV + (size_t)dvt * 64;

  // S accessed ONLY with compile-time indices; never address-taken.
  float S[4][4][4];                   // [dk-block][row][col], 64 regs
  if (g > 0) {
    const size_t sb = (((size_t)(g - 1) * 16 + bh) * 256) * 512 + (size_t)dvt * 64;
#pragma unroll
    for (int b4 = 0; b4 < 4; ++b4)
#pragma unroll
      for (int i = 0; i < 4; ++i) {
        float4 tmp = *(const float4*)&Sbuf[sb + (size_t)(b4 * 64 + rq + i) * 512 + c0];
        S[b4][i][0] = tmp.x; S[b4][i][1] = tmp.y; S[b4][i][2] = tmp.z; S[b4][i][3] = tmp.w;
      }
  } else {
#pragma unroll
    for (int b4 = 0; b4 < 4; ++b4)
#pragma unroll
      for (int i = 0; i < 4; ++i)
#pragma unroll
        for (int j = 0; j < 4; ++j) S[b4][i][j] = 0.f;
  }

  for (int c = 0; c < 8; ++c) {
    const int t0 = c * 64;
    // ---- o phase: oa = (q * cross_dec) @ S_incoming (skip when S == 0) ----
    if (g > 0 || c > 0) {
      float oa[4][4] = {};
#pragma unroll
      for (int b4 = 0; b4 < 4; ++b4) {
        __syncthreads();   // prev readers of sS/xS done
#pragma unroll
        for (int i = 0; i < 4; ++i)
          *(float4*)&sS[rq + i][c0] =
              make_float4(S[b4][i][0], S[b4][i][1], S[b4][i][2], S[b4][i][3]);
#pragma unroll
        for (int r = 0; r < 4; ++r) {
          int idx = t + 256 * r; int row = idx >> 4, c4 = (idx & 15) * 4;
          float4 qv = *(const float4*)&q[baseQK + (size_t)(t0 + row) * KDIM + b4 * 64 + c4];
          float gp = gpow[row + 1];
          qv.x *= gp; qv.y *= gp; qv.z *= gp; qv.w *= gp;
          *(float4*)&xS[row][c4] = qv;
        }
        __syncthreads();
        for (int d = 0; d < 64; d += 4) {
          float a_[4][4], s_[4][4];
#pragma unroll
          for (int ii = 0; ii < 4; ++ii)
            *(float4*)&a_[ii][0] = *(const float4*)&xS[i0 + ii][d];
#pragma unroll
          for (int dd = 0; dd < 4; ++dd)
            *(float4*)&s_[dd][0] = *(const float4*)&sS[d + dd][v0];
#pragma unroll
          for (int dd = 0; dd < 4; ++dd)
#pragma unroll
            for (int ii = 0; ii < 4; ++ii)
#pragma unroll
              for (int jj = 0; jj < 4; ++jj)
                oa[ii][jj] = fmaf(a_[ii][dd], s_[dd][jj], oa[ii][jj]);
        }
      }
      // o += oa : sole-writer read-modify-write, coalesced float4
#pragma unroll
      for (int ii = 0; ii < 4; ++ii) {
        size_t addr = baseV + (size_t)(t0 + i0 + ii) * VDIM + v0;
        float4 ov = *(const float4*)&o[addr];
        ov.x += oa[ii][0]; ov.y += oa[ii][1]; ov.z += oa[ii][2]; ov.w += oa[ii][3];
        *(float4*)&o[addr] = ov;
      }
    }
    // ---- update phase: S = gC*S + (k*k_dec)^T v ----
    __syncthreads();   // o-phase readers of xS done; prev chunk's vS readers done
#pragma unroll
    for (int r = 0; r < 4; ++r) {
      int idx = t + 256 * r; int row = idx >> 4, c4 = (idx & 15) * 4;
      *(float4*)&vS[row][c4] = *(const float4*)&v[baseV + (size_t)(t0 + row) * VDIM + c4];
    }
#pragma unroll
    for (int b4 = 0; b4 < 4; ++b4) {
      if (b4 > 0) __syncthreads();   // prev j-loop readers of xS done
#pragma unroll
      for (int r = 0; r < 4; ++r) {
        int idx = t + 256 * r; int row = idx >> 4, c4 = (idx & 15) * 4;
        float4 kv = *(const float4*)&k[baseQK + (size_t)(t0 + row) * KDIM + b4 * 64 + c4];
        float kd = gpow[63 - row];
        kv.x *= kd; kv.y *= kd; kv.z *= kd; kv.w *= kd;
        *(float4*)&xS[row][c4] = kv;
      }
      __syncthreads();
#pragma unroll
      for (int ii = 0; ii < 4; ++ii)
#pragma unroll
        for (int jj = 0; jj < 4; ++jj) S[b4][ii][jj] *= gC;
      for (int j = 0; j < 64; ++j) {
        float4 kv = *(const float4*)&xS[j][rq];
        float4 vv = *(const float4*)&vS[j][c0];
        S[b4][0][0] = fmaf(kv.x, vv.x, S[b4][0][0]); S[b4][0][1] = fmaf(kv.x, vv.y, S[b4][0][1]);
        S[b4][0][2] = fmaf(kv.x, vv.z, S[b4][0][2]); S[b4][0][3] = fmaf(kv.x, vv.w, S[b4][0][3]);
        S[b4][1][0] = fmaf(kv.y, vv.x, S[b4][1][0]); S[b4][1][1] = fmaf(kv.y, vv.y, S[b4][1][1]);
        S[b4][1][2] = fmaf(kv.y, vv.z, S[b4][1][2]); S[b4][1][3] = fmaf(kv.y, vv.w, S[b4][1][3]);
        S[b4][2][0] = fmaf(kv.z, vv.x, S[b4][2][0]); S[b4][2][1] = fmaf(kv.z, vv.y, S[b4][2][1]);
        S[b4][2][2] = fmaf(kv.z, vv.z, S[b4][2][2]); S[b4][2][3] = fmaf(kv.z, vv.w, S[b4][2][3]);
        S[b4][3][0] = fmaf(kv.w, vv.x, S[b4][3][0]); S[b4][3][1] = fmaf(kv.w, vv.y, S[b4][3][1]);
        S[b4][3][2] = fmaf(kv.w, vv.z, S[b4][3][2]); S[b4][3][3] = fmaf(kv.w, vv.w, S[b4][3][3]);
      }
    }
  }
}

// ---------------- RMS group-norm over HEAD_V + SiLU(g) gate (in-place) -------
__global__ __launch_bounds__(256) void norm_gate(float* __restrict__ o,
                                                 const float* __restrict__ g,
                                                 const float* __restrict__ gnw) {
  const int row = blockIdx.x;
  const size_t base = (size_t)row * 512;
  const int t = threadIdx.x;
  float x0 = o[base + t], x1 = o[base + t + 256];
  float ss = x0 * x0 + x1 * x1;
#pragma unroll
  for (int off = 32; off > 0; off >>= 1) ss += __shfl_down(ss, off, 64);
  __shared__ float wsum[4];
  if ((t & 63) == 0) wsum[t >> 6] = ss;
  __syncthreads();
  float tot = wsum[0] + wsum[1] + wsum[2] + wsum[3];
  float scale = rsqrtf(tot * (1.0f / 512.0f) + 1e-5f);
  float g0 = g[base + t], g1 = g[base + t + 256];
  o[base + t]       = x0 * scale * gnw[t]       * (g0 / (1.0f + expf(-g0)));
  o[base + t + 256] = x1 * scale * gnw[t + 256] * (g1 / (1.0f + expf(-g1)));
}

extern "C" void kernel_launch(void* const* d_in, const int* in_sizes, int n_in,
                              void* d_out, int out_size, void* d_ws, size_t ws_size,
                              hipStream_t stream) {
  const float* x   = (const float*)d_in[0];
  const float* Wq  = (const float*)d_in[1];
  const float* Wk  = (const float*)d_in[2];
  const float* Wv  = (const float*)d_in[3];
  const float* Wg  = (const float*)d_in[4];
  const float* Wo  = (const float*)d_in[5];
  const float* gnw = (const float*)d_in[6];
  float* out = (float*)d_out;

  // workspace = 256 MiB exactly:
  // [q 32][k 32][v 64][o 64][x-splits 32][W-splits 32]
  // o-splits (64) alias dead v; g (64) aliases dead q+k.
  // d_out (32 MiB) doubles as group-state scratch (24 MiB) until final GEMM.
  const size_t M8 = (size_t)8192;
  float* q  = (float*)d_ws;
  float* kk = q  + M8 * 1024;
  float* v  = kk + M8 * 1024;
  float* o  = v  + M8 * 2048;
  unsigned short* xh  = (unsigned short*)(o + M8 * 2048);
  unsigned short* xl  = xh  + M8 * 1024;
  unsigned short* wqh = xl  + M8 * 1024;
  unsigned short* wql = wqh + (size_t)1024 * 1024;
  unsigned short* wkh = wql + (size_t)1024 * 1024;
  unsigned short* wkl = wkh + (size_t)1024 * 1024;
  unsigned short* wvh = wkl + (size_t)1024 * 1024;
  unsigned short* wvl = wvh + (size_t)2048 * 1024;
  unsigned short* wgh = wvl + (size_t)2048 * 1024;
  unsigned short* wgl = wgh + (size_t)2048 * 1024;
  unsigned short* woh = wgl + (size_t)2048 * 1024;
  unsigned short* wol = woh + (size_t)2048 * 1024;
  unsigned short* oh  = (unsigned short*)v;
  unsigned short* ol  = oh + M8 * 2048;
  float* g = q;
  float* Tbuf = (float*)d_out;   // 24 MiB scratch, dead until final GEMM

  dim3 blk(256);
  cast_split<<<dim3(8192), blk, 0, stream>>>(x,  xh,  xl,  2097152);
  cast_split<<<dim3(1024), blk, 0, stream>>>(Wq, wqh, wql, 262144);
  cast_split<<<dim3(1024), blk, 0, stream>>>(Wk, wkh, wkl, 262144);
  cast_split<<<dim3(2048), blk, 0, stream>>>(Wv, wvh, wvl, 524288);
  cast_split<<<dim3(2048), blk, 0, stream>>>(Wg, wgh, wgl, 524288);
  cast_split<<<dim3(2048), blk, 0, stream>>>(Wo, woh, wol, 524288);

  gemm_bf16s<<<dim3(8, 64),  blk, 0, stream>>>(xh, xl, wqh, wql, q,  8192, 1024, 1024);
  gemm_bf16s<<<dim3(8, 64),  blk, 0, stream>>>(xh, xl, wkh, wkl, kk, 8192, 1024, 1024);
  gemm_bf16s<<<dim3(16, 64), blk, 0, stream>>>(xh, xl, wvh, wvl, v,  8192, 2048, 1024);
  rope_kernel<<<dim3(16384), blk, 0, stream>>>(q, kk);
  retn_gstate<<<dim3(16, 3, 32), blk, 0, stream>>>(kk, v, Tbuf);
  retn_scan<<<dim3(2048), blk, 0, stream>>>(Tbuf);
  retn_intra<<<dim3(32, 4, 4),  blk, 0, stream>>>(q, kk, v, o);
  retn_inter2<<<dim3(16, 4, 8), blk, 0, stream>>>(q, kk, v, o, Tbuf);
  gemm_bf16s<<<dim3(16, 64), blk, 0, stream>>>(xh, xl, wgh, wgl, g, 8192, 2048, 1024);
  norm_gate<<<dim3(32768), blk, 0, stream>>>(o, g, gnw);
  cast_split<<<dim3(16384), blk, 0, stream>>>(o, oh, ol, 4194304);
  gemm_bf16s<<<dim3(8, 64),  blk, 0, stream>>>(oh, ol, woh, wol, out, 8192, 1024, 2048);
}

// Round 3
// 4623.713 us; speedup vs baseline: 2.1772x; 2.1575x over previous
//
#include <hip/hip_runtime.h>
#include <cstdint>
#include <cstddef>

#define T_SEQ 2048
#define DM    1024
#define HK    256
#define HV    512
#define NH    4
#define KDIM  1024
#define VDIM  2048

typedef __attribute__((ext_vector_type(8))) short bf16x8;
typedef __attribute__((ext_vector_type(4))) float f32x4;
#define AS1 __attribute__((address_space(1)))
#define AS3 __attribute__((address_space(3)))

// ---------------- f32 -> (hi, lo) bf16 split (RNE), vectorized x4 ------------
static __device__ inline unsigned short f2bf(float f) {
  unsigned u = __float_as_uint(f);
  unsigned rnd = 0x7fffu + ((u >> 16) & 1u);
  return (unsigned short)((u + rnd) >> 16);
}
static __device__ inline float bf2f(unsigned short h) {
  unsigned u = ((unsigned)h) << 16;
  return __uint_as_float(u);
}

__global__ __launch_bounds__(256) void cast_split(const float* __restrict__ in,
                                                  unsigned short* __restrict__ hi,
                                                  unsigned short* __restrict__ lo,
                                                  int n4) {
  int i = blockIdx.x * 256 + threadIdx.x;
  if (i >= n4) return;
  float4 v = ((const float4*)in)[i];
  ushort4 h, l;
  h.x = f2bf(v.x); l.x = f2bf(v.x - bf2f(h.x));
  h.y = f2bf(v.y); l.y = f2bf(v.y - bf2f(h.y));
  h.z = f2bf(v.z); l.z = f2bf(v.z - bf2f(h.z));
  h.w = f2bf(v.w); l.w = f2bf(v.w - bf2f(h.w));
  ((ushort4*)hi)[i] = h;
  ((ushort4*)lo)[i] = l;
}

// -------- split-precision bf16 MFMA GEMM: C = A @ W^T, A=Ah+Al, W=Wh+Wl ------
// C ~= Ah*Wh + Ah*Wl + Al*Wh (f32 accumulate; lo*lo term ~2^-16 rel, dropped).
// 128x128 tile, BK=32, 4 waves 2x2, wave = 64x64 = 4x4 16x16x32 frags.
__global__ __launch_bounds__(256) void gemm_bf16s(const unsigned short* __restrict__ Ah,
                                                  const unsigned short* __restrict__ Al,
                                                  const unsigned short* __restrict__ Wh,
                                                  const unsigned short* __restrict__ Wl,
                                                  float* __restrict__ C,
                                                  int M, int N, int K) {
  __shared__ unsigned short AhS[128 * 32];
  __shared__ unsigned short AlS[128 * 32];
  __shared__ unsigned short WhS[128 * 32];
  __shared__ unsigned short WlS[128 * 32];
  const int t = threadIdx.x;
  const int l = t & 63;
  const int w = t >> 6;
  const int bm = blockIdx.y * 128;
  const int bn = blockIdx.x * 128;
  const int wm = (w >> 1) * 64;
  const int wn = (w & 1) * 64;

  f32x4 acc[4][4];
#pragma unroll
  for (int i = 0; i < 4; ++i)
#pragma unroll
    for (int j = 0; j < 4; ++j)
#pragma unroll
      for (int r = 0; r < 4; ++r) acc[i][j][r] = 0.f;

  const int srow = w * 32 + (l >> 2);
  const int scol = (l & 3) * 8;
  const size_t gOffA = (size_t)(bm + srow) * K + scol;
  const size_t gOffW = (size_t)(bn + srow) * K + scol;
  const size_t rowStep = (size_t)16 * K;
  unsigned short* lAh0 = &AhS[(w * 32) * 32];
  unsigned short* lAh1 = &AhS[(w * 32 + 16) * 32];
  unsigned short* lAl0 = &AlS[(w * 32) * 32];
  unsigned short* lAl1 = &AlS[(w * 32 + 16) * 32];
  unsigned short* lWh0 = &WhS[(w * 32) * 32];
  unsigned short* lWh1 = &WhS[(w * 32 + 16) * 32];
  unsigned short* lWl0 = &WlS[(w * 32) * 32];
  unsigned short* lWl1 = &WlS[(w * 32 + 16) * 32];

  for (int k0 = 0; k0 < K; k0 += 32) {
    __syncthreads();
    __builtin_amdgcn_global_load_lds((const AS1 void*)(Ah + gOffA + k0),           (AS3 void*)lAh0, 16, 0, 0);
    __builtin_amdgcn_global_load_lds((const AS1 void*)(Ah + gOffA + rowStep + k0), (AS3 void*)lAh1, 16, 0, 0);
    __builtin_amdgcn_global_load_lds((const AS1 void*)(Al + gOffA + k0),           (AS3 void*)lAl0, 16, 0, 0);
    __builtin_amdgcn_global_load_lds((const AS1 void*)(Al + gOffA + rowStep + k0), (AS3 void*)lAl1, 16, 0, 0);
    __builtin_amdgcn_global_load_lds((const AS1 void*)(Wh + gOffW + k0),           (AS3 void*)lWh0, 16, 0, 0);
    __builtin_amdgcn_global_load_lds((const AS1 void*)(Wh + gOffW + rowStep + k0), (AS3 void*)lWh1, 16, 0, 0);
    __builtin_amdgcn_global_load_lds((const AS1 void*)(Wl + gOffW + k0),           (AS3 void*)lWl0, 16, 0, 0);
    __builtin_amdgcn_global_load_lds((const AS1 void*)(Wl + gOffW + rowStep + k0), (AS3 void*)lWl1, 16, 0, 0);
    __syncthreads();

    bf16x8 ah[4], al[4], bh[4], bl[4];
#pragma unroll
    for (int i = 0; i < 4; ++i) {
      int aoff = (wm + i * 16 + (l & 15)) * 32 + (l >> 4) * 8;
      int boff = (wn + i * 16 + (l & 15)) * 32 + (l >> 4) * 8;
      ah[i] = *(const bf16x8*)&AhS[aoff];
      al[i] = *(const bf16x8*)&AlS[aoff];
      bh[i] = *(const bf16x8*)&WhS[boff];
      bl[i] = *(const bf16x8*)&WlS[boff];
    }
#pragma unroll
    for (int i = 0; i < 4; ++i)
#pragma unroll
      for (int j = 0; j < 4; ++j) {
        acc[i][j] = __builtin_amdgcn_mfma_f32_16x16x32_bf16(ah[i], bh[j], acc[i][j], 0, 0, 0);
        acc[i][j] = __builtin_amdgcn_mfma_f32_16x16x32_bf16(ah[i], bl[j], acc[i][j], 0, 0, 0);
        acc[i][j] = __builtin_amdgcn_mfma_f32_16x16x32_bf16(al[i], bh[j], acc[i][j], 0, 0, 0);
      }
  }

  const int cr = (l >> 4) * 4;
  const int cc = l & 15;
#pragma unroll
  for (int i = 0; i < 4; ++i)
#pragma unroll
    for (int j = 0; j < 4; ++j)
#pragma unroll
      for (int r = 0; r < 4; ++r)
        C[(size_t)(bm + wm + i * 16 + cr + r) * N + (bn + wn + j * 16 + cc)] = acc[i][j][r];
}

// ---------------- RoPE (in-place on q and k), q also scaled by HK^-0.5 -------
__global__ __launch_bounds__(256) void rope_kernel(float* __restrict__ q,
                                                   float* __restrict__ k) {
  int idx = blockIdx.x * 256 + threadIdx.x;     // over B*T*H*128 = 4,194,304
  int f  = idx & 127;
  int h  = (idx >> 7) & 3;
  int tt = (idx >> 9) & 2047;
  int b  = idx >> 20;
  size_t a0 = ((size_t)(b * T_SEQ + tt)) * KDIM + h * HK + f;
  size_t a1 = a0 + 128;
  float invf = powf(10000.0f, -(float)f * (1.0f / 128.0f));
  float ang  = (float)tt * invf;
  float s, c;
  sincosf(ang, &s, &c);
  float q1 = q[a0], q2 = q[a1];
  q[a0] = (q1 * c - q2 * s) * 0.0625f;
  q[a1] = (q2 * c + q1 * s) * 0.0625f;
  float k1 = k[a0], k2 = k[a1];
  k[a0] = k1 * c - k2 * s;
  k[a1] = k2 * c + k1 * s;
}

// ---------------- Retention pass 1: intra-chunk (fully parallel) -------------
__global__ __launch_bounds__(256) void retn_intra(const float* __restrict__ q,
                                                  const float* __restrict__ k,
                                                  const float* __restrict__ v,
                                                  float* __restrict__ o) {
  const int n = blockIdx.x, h = blockIdx.y, b = blockIdx.z;
  const int t = threadIdx.x;
  const int t0 = n * 64;
  __shared__ float gpow[65];
  __shared__ float qS[64][65];
  __shared__ float kS[64][65];
  __shared__ float attnS[64][65];
  if (t <= 64) {
    float gamma = 1.0f - exp2f(-5.0f - (float)h);
    gpow[t] = powf(gamma, (float)t);
  }
  const size_t baseQK = (size_t)(b * T_SEQ + t0) * KDIM + h * HK;
  const size_t baseV  = (size_t)(b * T_SEQ + t0) * VDIM + h * HV;
  const int i0 = (t >> 4) * 4;
  const int j0 = (t & 15) * 4;
  float acc[4][4] = {};
  for (int s = 0; s < 4; ++s) {              // dk slices of 64
    __syncthreads();
#pragma unroll
    for (int r = 0; r < 16; ++r) {
      int idx = t + 256 * r;
      int row = idx >> 6, col = idx & 63;
      qS[row][col] = q[baseQK + (size_t)row * KDIM + s * 64 + col];
      kS[row][col] = k[baseQK + (size_t)row * KDIM + s * 64 + col];
    }
    __syncthreads();
    for (int d = 0; d < 64; ++d) {
      float a0 = qS[i0][d], a1 = qS[i0 + 1][d], a2 = qS[i0 + 2][d], a3 = qS[i0 + 3][d];
#pragma unroll
      for (int jj = 0; jj < 4; ++jj) {
        float bv = kS[j0 + jj][d];
        acc[0][jj] = fmaf(a0, bv, acc[0][jj]);
        acc[1][jj] = fmaf(a1, bv, acc[1][jj]);
        acc[2][jj] = fmaf(a2, bv, acc[2][jj]);
        acc[3][jj] = fmaf(a3, bv, acc[3][jj]);
      }
    }
  }
  __syncthreads();
#pragma unroll
  for (int ii = 0; ii < 4; ++ii)
#pragma unroll
    for (int jj = 0; jj < 4; ++jj) {
      int i = i0 + ii, j = j0 + jj;
      attnS[i][j] = (i >= j) ? acc[ii][jj] * gpow[i - j] : 0.0f;
    }
  float (*vS)[65] = qS;
  for (int vb = 0; vb < 8; ++vb) {
    __syncthreads();
#pragma unroll
    for (int r = 0; r < 16; ++r) {
      int idx = t + 256 * r;
      int row = idx >> 6, col = idx & 63;
      vS[row][col] = v[baseV + (size_t)row * VDIM + vb * 64 + col];
    }
    __syncthreads();
    float oa[4][4] = {};
    for (int j = 0; j < 64; ++j) {
      float a0 = attnS[i0][j], a1 = attnS[i0 + 1][j], a2 = attnS[i0 + 2][j], a3 = attnS[i0 + 3][j];
#pragma unroll
      for (int jj = 0; jj < 4; ++jj) {
        float bv = vS[j][j0 + jj];
        oa[0][jj] = fmaf(a0, bv, oa[0][jj]);
        oa[1][jj] = fmaf(a1, bv, oa[1][jj]);
        oa[2][jj] = fmaf(a2, bv, oa[2][jj]);
        oa[3][jj] = fmaf(a3, bv, oa[3][jj]);
      }
    }
#pragma unroll
    for (int ii = 0; ii < 4; ++ii)
#pragma unroll
      for (int jj = 0; jj < 4; ++jj)
        o[baseV + (size_t)(i0 + ii) * VDIM + vb * 64 + j0 + jj] = oa[ii][jj];
  }
}

// =================== Retention inter-chunk: two-level scan ===================
//   A) retn_gstate: per (b,h,group of 8 chunks) local state sums T_g (g=0..2).
//   B) retn_scan: elementwise exclusive scan over groups: T_g -> S_in[g+1].
//   C) retn_inter2: per (b,h,g,dv-tile32) WG carries full dk=256 state in regs
//      (32/thread), seeded from S_in[g]; 8-chunk serial scan; o updated with
//      plain load+add+store (sole writer, NO atomics).
// ROUND-2 POST-MORTEM: with dv-tile=64, per-thread S was 64 regs; peak demand
// (S + oa + pipelined LDS staging) exceeded the 256-VGPR budget and the
// allocator spilled S wholesale to scratch: VGPR pinned at 256, FETCH 12GB
// (~11GB scratch reloads in the j-loop), VALUBusy 2%, 9.3ms, plus a 40ms
// scratch first-touch dispatch. Removing address-taking (round 1->2) changed
// nothing -- it's pure pressure. Fix: dv-tile=32 (grid z=16), S[4][4][2]=32
// regs, all operands explicit float4/float2 scalars, no local arrays.
// dv-siblings are 64 apart in linear block id (64%8==0 -> same XCD) for L2
// reuse of the shared q/k slabs.

// ---- pass A: group-local state sums --------------------------------------
__global__ __launch_bounds__(256) void retn_gstate(const float* __restrict__ k,
                                                   const float* __restrict__ v,
                                                   float* __restrict__ Tbuf) {
  // grid (16, 3, 32): x = b*4+h, y = g (0..2), z: dkt = z>>3, dvt = z&7
  const int bh = blockIdx.x; const int b = bh >> 2, h = bh & 3;
  const int g = blockIdx.y;
  const int dkt = blockIdx.z >> 3, dvt = blockIdx.z & 7;
  const int t = threadIdx.x;
  __shared__ float gpow[65];
  __shared__ __align__(16) float kS[64][68];
  __shared__ __align__(16) float vS[64][68];
  if (t <= 64) gpow[t] = powf(1.0f - exp2f(-5.0f - (float)h), (float)t);
  __syncthreads();
  const float gC = gpow[64];
  const size_t baseK = (size_t)(b * T_SEQ + g * 512) * KDIM + h * HK + dkt * 64;
  const size_t baseV = (size_t)(b * T_SEQ + g * 512) * VDIM + h * HV + dvt * 64;
  const int dk0 = (t & 15) * 4, c0 = (t >> 4) * 4;
  float S[4][4] = {};
  for (int c = 0; c < 8; ++c) {
    const int t0 = c * 64;
    __syncthreads();
#pragma unroll
    for (int r = 0; r < 4; ++r) {
      int idx = t + 256 * r; int row = idx >> 4, c4 = (idx & 15) * 4;
      float4 kv = *(const float4*)&k[baseK + (size_t)(t0 + row) * KDIM + c4];
      float kd = gpow[63 - row];
      kv.x *= kd; kv.y *= kd; kv.z *= kd; kv.w *= kd;
      *(float4*)&kS[row][c4] = kv;
      *(float4*)&vS[row][c4] = *(const float4*)&v[baseV + (size_t)(t0 + row) * VDIM + c4];
    }
    __syncthreads();
#pragma unroll
    for (int ii = 0; ii < 4; ++ii)
#pragma unroll
      for (int jj = 0; jj < 4; ++jj) S[ii][jj] *= gC;
    for (int j = 0; j < 64; ++j) {
      float4 kv = *(const float4*)&kS[j][dk0];
      float4 vv = *(const float4*)&vS[j][c0];
      S[0][0] = fmaf(kv.x, vv.x, S[0][0]); S[0][1] = fmaf(kv.x, vv.y, S[0][1]);
      S[0][2] = fmaf(kv.x, vv.z, S[0][2]); S[0][3] = fmaf(kv.x, vv.w, S[0][3]);
      S[1][0] = fmaf(kv.y, vv.x, S[1][0]); S[1][1] = fmaf(kv.y, vv.y, S[1][1]);
      S[1][2] = fmaf(kv.y, vv.z, S[1][2]); S[1][3] = fmaf(kv.y, vv.w, S[1][3]);
      S[2][0] = fmaf(kv.z, vv.x, S[2][0]); S[2][1] = fmaf(kv.z, vv.y, S[2][1]);
      S[2][2] = fmaf(kv.z, vv.z, S[2][2]); S[2][3] = fmaf(kv.z, vv.w, S[2][3]);
      S[3][0] = fmaf(kv.w, vv.x, S[3][0]); S[3][1] = fmaf(kv.w, vv.y, S[3][1]);
      S[3][2] = fmaf(kv.w, vv.z, S[3][2]); S[3][3] = fmaf(kv.w, vv.w, S[3][3]);
    }
  }
  const size_t tb = (((size_t)g * 16 + bh) * 256 + dkt * 64 + dk0) * 512 + (size_t)dvt * 64 + c0;
#pragma unroll
  for (int ii = 0; ii < 4; ++ii)
    *(float4*)&Tbuf[tb + (size_t)ii * 512] = make_float4(S[ii][0], S[ii][1], S[ii][2], S[ii][3]);
}

// ---- pass B: exclusive scan over the 4 groups (in-place) ------------------
// slot g holds T_g on entry; on exit slot g holds S_in[g+1]:
//   S_in[1]=T0 (slot0 unchanged), S_in[2]=gG*T0+T1, S_in[3]=gG*S_in[2]+T2.
__global__ __launch_bounds__(256) void retn_scan(float* __restrict__ Tbuf) {
  int i = blockIdx.x * 256 + threadIdx.x;   // float4 index within one g-slab
  int h = (i >> 15) & 3;                    // (i*4)>>17 & 3
  float gamma = 1.0f - exp2f(-5.0f - (float)h);
  float gG = powf(gamma, 512.0f);           // gC^8 = gamma^(64*8)
  float4* T = (float4*)Tbuf;
  const int slab = 524288;                  // 16*256*512/4
  float4 t0 = T[i], t1 = T[i + slab], t2 = T[i + 2 * slab];
  float4 s2, s3;
  s2.x = fmaf(gG, t0.x, t1.x); s2.y = fmaf(gG, t0.y, t1.y);
  s2.z = fmaf(gG, t0.z, t1.z); s2.w = fmaf(gG, t0.w, t1.w);
  s3.x = fmaf(gG, s2.x, t2.x); s3.y = fmaf(gG, s2.y, t2.y);
  s3.z = fmaf(gG, s2.z, t2.z); s3.w = fmaf(gG, s2.w, t2.w);
  T[i + slab] = s2; T[i + 2 * slab] = s3;
}

// ---- pass C: inter-chunk output, full-dk state in regs, no atomics --------
__global__ __launch_bounds__(256) void retn_inter2(const float* __restrict__ q,
                                                   const float* __restrict__ k,
                                                   const float* __restrict__ v,
                                                   float* __restrict__ o,
                                                   const float* __restrict__ Sbuf) {
  // grid (16, 4, 16): x = b*4+h, y = g, z = dvt (32-wide dv tiles)
  const int bh = blockIdx.x; const int b = bh >> 2, h = bh & 3;
  const int g = blockIdx.y;
  const int dvt = blockIdx.z;
  const int t = threadIdx.x;
  __shared__ float gpow[65];
  __shared__ __align__(16) float xS[64][68];  // q-block / k-block stage (64x64)
  __shared__ __align__(16) float sS[64][36];  // state-block publish (64x32)
  __shared__ __align__(16) float vS[64][36];  // v chunk (64x32)
  if (t <= 64) gpow[t] = powf(1.0f - exp2f(-5.0f - (float)h), (float)t);
  __syncthreads();
  const float gC = gpow[64];
  const int rq = (t & 15) * 4;        // state rows within a dk-block
  const int c0 = (t >> 4) * 2;        // state cols (dv within 32-tile)
  const int i0 = (t >> 4) * 4;        // o-tile rows
  const int v0 = (t & 15) * 2;        // o-tile cols
  const size_t baseQK = (size_t)(b * T_SEQ + g * 512) * KDIM + h * HK;
  const size_t baseV  = (size_t)(b * T_SEQ + g * 512) * VDIM + h * HV + (size_t)dvt * 32;

  // S: 32 regs/thread, compile-time indices only, never address-taken.
  float S[4][4][2];                   // [dk-block][row][col2]
  if (g > 0) {
    const size_t sb = (((size_t)(g - 1) * 16 + bh) * 256) * 512 + (size_t)dvt * 32;
#pragma unroll
    for (int b4 = 0; b4 < 4; ++b4)
#pragma unroll
      for (int i = 0; i < 4; ++i) {
        float2 tmp = *(const float2*)&Sbuf[sb + (size_t)(b4 * 64 + rq + i) * 512 + c0];
        S[b4][i][0] = tmp.x; S[b4][i][1] = tmp.y;
      }
  } else {
#pragma unroll
    for (int b4 = 0; b4 < 4; ++b4)
#pragma unroll
      for (int i = 0; i < 4; ++i) {
        S[b4][i][0] = 0.f; S[b4][i][1] = 0.f;
      }
  }

  for (int c = 0; c < 8; ++c) {
    const int t0 = c * 64;
    // ---- o phase: oa = (q * cross_dec) @ S_incoming (skip when S == 0) ----
    if (g > 0 || c > 0) {
      float oa[4][2] = {};
#pragma unroll
      for (int b4 = 0; b4 < 4; ++b4) {
        __syncthreads();   // prev readers of sS/xS done
#pragma unroll
        for (int i = 0; i < 4; ++i)
          *(float2*)&sS[rq + i][c0] = make_float2(S[b4][i][0], S[b4][i][1]);
#pragma unroll
        for (int r = 0; r < 4; ++r) {
          int idx = t + 256 * r; int row = idx >> 4, c4 = (idx & 15) * 4;
          float4 qv = *(const float4*)&q[baseQK + (size_t)(t0 + row) * KDIM + b4 * 64 + c4];
          float gp = gpow[row + 1];
          qv.x *= gp; qv.y *= gp; qv.z *= gp; qv.w *= gp;
          *(float4*)&xS[row][c4] = qv;
        }
        __syncthreads();
        for (int d = 0; d < 64; d += 4) {
          float4 a0 = *(const float4*)&xS[i0 + 0][d];
          float4 a1 = *(const float4*)&xS[i0 + 1][d];
          float4 a2 = *(const float4*)&xS[i0 + 2][d];
          float4 a3 = *(const float4*)&xS[i0 + 3][d];
          float2 s0 = *(const float2*)&sS[d + 0][v0];
          float2 s1 = *(const float2*)&sS[d + 1][v0];
          float2 s2 = *(const float2*)&sS[d + 2][v0];
          float2 s3 = *(const float2*)&sS[d + 3][v0];
          oa[0][0] = fmaf(a0.x, s0.x, oa[0][0]); oa[0][1] = fmaf(a0.x, s0.y, oa[0][1]);
          oa[0][0] = fmaf(a0.y, s1.x, oa[0][0]); oa[0][1] = fmaf(a0.y, s1.y, oa[0][1]);
          oa[0][0] = fmaf(a0.z, s2.x, oa[0][0]); oa[0][1] = fmaf(a0.z, s2.y, oa[0][1]);
          oa[0][0] = fmaf(a0.w, s3.x, oa[0][0]); oa[0][1] = fmaf(a0.w, s3.y, oa[0][1]);
          oa[1][0] = fmaf(a1.x, s0.x, oa[1][0]); oa[1][1] = fmaf(a1.x, s0.y, oa[1][1]);
          oa[1][0] = fmaf(a1.y, s1.x, oa[1][0]); oa[1][1] = fmaf(a1.y, s1.y, oa[1][1]);
          oa[1][0] = fmaf(a1.z, s2.x, oa[1][0]); oa[1][1] = fmaf(a1.z, s2.y, oa[1][1]);
          oa[1][0] = fmaf(a1.w, s3.x, oa[1][0]); oa[1][1] = fmaf(a1.w, s3.y, oa[1][1]);
          oa[2][0] = fmaf(a2.x, s0.x, oa[2][0]); oa[2][1] = fmaf(a2.x, s0.y, oa[2][1]);
          oa[2][0] = fmaf(a2.y, s1.x, oa[2][0]); oa[2][1] = fmaf(a2.y, s1.y, oa[2][1]);
          oa[2][0] = fmaf(a2.z, s2.x, oa[2][0]); oa[2][1] = fmaf(a2.z, s2.y, oa[2][1]);
          oa[2][0] = fmaf(a2.w, s3.x, oa[2][0]); oa[2][1] = fmaf(a2.w, s3.y, oa[2][1]);
          oa[3][0] = fmaf(a3.x, s0.x, oa[3][0]); oa[3][1] = fmaf(a3.x, s0.y, oa[3][1]);
          oa[3][0] = fmaf(a3.y, s1.x, oa[3][0]); oa[3][1] = fmaf(a3.y, s1.y, oa[3][1]);
          oa[3][0] = fmaf(a3.z, s2.x, oa[3][0]); oa[3][1] = fmaf(a3.z, s2.y, oa[3][1]);
          oa[3][0] = fmaf(a3.w, s3.x, oa[3][0]); oa[3][1] = fmaf(a3.w, s3.y, oa[3][1]);
        }
      }
      // o += oa : sole-writer read-modify-write, coalesced float2 (128B/row/wave)
#pragma unroll
      for (int ii = 0; ii < 4; ++ii) {
        size_t addr = baseV + (size_t)(t0 + i0 + ii) * VDIM + v0;
        float2 ov = *(const float2*)&o[addr];
        ov.x += oa[ii][0]; ov.y += oa[ii][1];
        *(float2*)&o[addr] = ov;
      }
    }
    // ---- update phase: S = gC*S + (k*k_dec)^T v ----
    __syncthreads();   // o-phase readers of xS done
#pragma unroll
    for (int r = 0; r < 2; ++r) {
      int idx = t + 256 * r; int row = idx >> 3, c4 = (idx & 7) * 4;
      *(float4*)&vS[row][c4] = *(const float4*)&v[baseV + (size_t)(t0 + row) * VDIM + c4];
    }
#pragma unroll
    for (int b4 = 0; b4 < 4; ++b4) {
      if (b4 > 0) __syncthreads();   // prev j-loop readers of xS done
#pragma unroll
      for (int r = 0; r < 4; ++r) {
        int idx = t + 256 * r; int row = idx >> 4, c4 = (idx & 15) * 4;
        float4 kv = *(const float4*)&k[baseQK + (size_t)(t0 + row) * KDIM + b4 * 64 + c4];
        float kd = gpow[63 - row];
        kv.x *= kd; kv.y *= kd; kv.z *= kd; kv.w *= kd;
        *(float4*)&xS[row][c4] = kv;
      }
      __syncthreads();
      S[b4][0][0] *= gC; S[b4][0][1] *= gC;
      S[b4][1][0] *= gC; S[b4][1][1] *= gC;
      S[b4][2][0] *= gC; S[b4][2][1] *= gC;
      S[b4][3][0] *= gC; S[b4][3][1] *= gC;
      for (int j = 0; j < 64; ++j) {
        float4 kv = *(const float4*)&xS[j][rq];
        float2 vv = *(const float2*)&vS[j][c0];
        S[b4][0][0] = fmaf(kv.x, vv.x, S[b4][0][0]); S[b4][0][1] = fmaf(kv.x, vv.y, S[b4][0][1]);
        S[b4][1][0] = fmaf(kv.y, vv.x, S[b4][1][0]); S[b4][1][1] = fmaf(kv.y, vv.y, S[b4][1][1]);
        S[b4][2][0] = fmaf(kv.z, vv.x, S[b4][2][0]); S[b4][2][1] = fmaf(kv.z, vv.y, S[b4][2][1]);
        S[b4][3][0] = fmaf(kv.w, vv.x, S[b4][3][0]); S[b4][3][1] = fmaf(kv.w, vv.y, S[b4][3][1]);
      }
    }
  }
}

// ---------------- RMS group-norm over HEAD_V + SiLU(g) gate (in-place) -------
__global__ __launch_bounds__(256) void norm_gate(float* __restrict__ o,
                                                 const float* __restrict__ g,
                                                 const float* __restrict__ gnw) {
  const int row = blockIdx.x;
  const size_t base = (size_t)row * 512;
  const int t = threadIdx.x;
  float x0 = o[base + t], x1 = o[base + t + 256];
  float ss = x0 * x0 + x1 * x1;
#pragma unroll
  for (int off = 32; off > 0; off >>= 1) ss += __shfl_down(ss, off, 64);
  __shared__ float wsum[4];
  if ((t & 63) == 0) wsum[t >> 6] = ss;
  __syncthreads();
  float tot = wsum[0] + wsum[1] + wsum[2] + wsum[3];
  float scale = rsqrtf(tot * (1.0f / 512.0f) + 1e-5f);
  float g0 = g[base + t], g1 = g[base + t + 256];
  o[base + t]       = x0 * scale * gnw[t]       * (g0 / (1.0f + expf(-g0)));
  o[base + t + 256] = x1 * scale * gnw[t + 256] * (g1 / (1.0f + expf(-g1)));
}

extern "C" void kernel_launch(void* const* d_in, const int* in_sizes, int n_in,
                              void* d_out, int out_size, void* d_ws, size_t ws_size,
                              hipStream_t stream) {
  const float* x   = (const float*)d_in[0];
  const float* Wq  = (const float*)d_in[1];
  const float* Wk  = (const float*)d_in[2];
  const float* Wv  = (const float*)d_in[3];
  const float* Wg  = (const float*)d_in[4];
  const float* Wo  = (const float*)d_in[5];
  const float* gnw = (const float*)d_in[6];
  float* out = (float*)d_out;

  // workspace = 256 MiB exactly:
  // [q 32][k 32][v 64][o 64][x-splits 32][W-splits 32]
  // o-splits (64) alias dead v; g (64) aliases dead q+k.
  // d_out (32 MiB) doubles as group-state scratch (24 MiB) until final GEMM.
  const size_t M8 = (size_t)8192;
  float* q  = (float*)d_ws;
  float* kk = q  + M8 * 1024;
  float* v  = kk + M8 * 1024;
  float* o  = v  + M8 * 2048;
  unsigned short* xh  = (unsigned short*)(o + M8 * 2048);
  unsigned short* xl  = xh  + M8 * 1024;
  unsigned short* wqh = xl  + M8 * 1024;
  unsigned short* wql = wqh + (size_t)1024 * 1024;
  unsigned short* wkh = wql + (size_t)1024 * 1024;
  unsigned short* wkl = wkh + (size_t)1024 * 1024;
  unsigned short* wvh = wkl + (size_t)1024 * 1024;
  unsigned short* wvl = wvh + (size_t)2048 * 1024;
  unsigned short* wgh = wvl + (size_t)2048 * 1024;
  unsigned short* wgl = wgh + (size_t)2048 * 1024;
  unsigned short* woh = wgl + (size_t)2048 * 1024;
  unsigned short* wol = woh + (size_t)2048 * 1024;
  unsigned short* oh  = (unsigned short*)v;
  unsigned short* ol  = oh + M8 * 2048;
  float* g = q;
  float* Tbuf = (float*)d_out;   // 24 MiB scratch, dead until final GEMM

  dim3 blk(256);
  cast_split<<<dim3(8192), blk, 0, stream>>>(x,  xh,  xl,  2097152);
  cast_split<<<dim3(1024), blk, 0, stream>>>(Wq, wqh, wql, 262144);
  cast_split<<<dim3(1024), blk, 0, stream>>>(Wk, wkh, wkl, 262144);
  cast_split<<<dim3(2048), blk, 0, stream>>>(Wv, wvh, wvl, 524288);
  cast_split<<<dim3(2048), blk, 0, stream>>>(Wg, wgh, wgl, 524288);
  cast_split<<<dim3(2048), blk, 0, stream>>>(Wo, woh, wol, 524288);

  gemm_bf16s<<<dim3(8, 64),  blk, 0, stream>>>(xh, xl, wqh, wql, q,  8192, 1024, 1024);
  gemm_bf16s<<<dim3(8, 64),  blk, 0, stream>>>(xh, xl, wkh, wkl, kk, 8192, 1024, 1024);
  gemm_bf16s<<<dim3(16, 64), blk, 0, stream>>>(xh, xl, wvh, wvl, v,  8192, 2048, 1024);
  rope_kernel<<<dim3(16384), blk, 0, stream>>>(q, kk);
  retn_gstate<<<dim3(16, 3, 32), blk, 0, stream>>>(kk, v, Tbuf);
  retn_scan<<<dim3(2048), blk, 0, stream>>>(Tbuf);
  retn_intra<<<dim3(32, 4, 4),  blk, 0, stream>>>(q, kk, v, o);
  retn_inter2<<<dim3(16, 4, 16), blk, 0, stream>>>(q, kk, v, o, Tbuf);
  gemm_bf16s<<<dim3(16, 64), blk, 0, stream>>>(xh, xl, wgh, wgl, g, 8192, 2048, 1024);
  norm_gate<<<dim3(32768), blk, 0, stream>>>(o, g, gnw);
  cast_split<<<dim3(16384), blk, 0, stream>>>(o, oh, ol, 4194304);
  gemm_bf16s<<<dim3(8, 64),  blk, 0, stream>>>(oh, ol, woh, wol, out, 8192, 1024, 2048);
}

// Round 4
// 1286.348 us; speedup vs baseline: 7.8259x; 3.5945x over previous
//
#include <hip/hip_runtime.h>
#include <cstdint>
#include <cstddef>

#define T_SEQ 2048
#define DM    1024
#define HK    256
#define HV    512
#define NH    4
#define KDIM  1024
#define VDIM  2048

typedef __attribute__((ext_vector_type(8))) short bf16x8;
typedef __attribute__((ext_vector_type(4))) float f32x4;
#define AS1 __attribute__((address_space(1)))
#define AS3 __attribute__((address_space(3)))

// ---------------- f32 -> (hi, lo) bf16 split (RNE), vectorized x4 ------------
static __device__ inline unsigned short f2bf(float f) {
  unsigned u = __float_as_uint(f);
  unsigned rnd = 0x7fffu + ((u >> 16) & 1u);
  return (unsigned short)((u + rnd) >> 16);
}
static __device__ inline float bf2f(unsigned short h) {
  unsigned u = ((unsigned)h) << 16;
  return __uint_as_float(u);
}

__global__ __launch_bounds__(256) void cast_split(const float* __restrict__ in,
                                                  unsigned short* __restrict__ hi,
                                                  unsigned short* __restrict__ lo,
                                                  int n4) {
  int i = blockIdx.x * 256 + threadIdx.x;
  if (i >= n4) return;
  float4 v = ((const float4*)in)[i];
  ushort4 h, l;
  h.x = f2bf(v.x); l.x = f2bf(v.x - bf2f(h.x));
  h.y = f2bf(v.y); l.y = f2bf(v.y - bf2f(h.y));
  h.z = f2bf(v.z); l.z = f2bf(v.z - bf2f(h.z));
  h.w = f2bf(v.w); l.w = f2bf(v.w - bf2f(h.w));
  ((ushort4*)hi)[i] = h;
  ((ushort4*)lo)[i] = l;
}

// -------- split-precision bf16 MFMA GEMM: C = A @ W^T, A=Ah+Al, W=Wh+Wl ------
// C ~= Ah*Wh + Ah*Wl + Al*Wh (f32 accumulate; lo*lo term ~2^-16 rel, dropped).
// 128x128 tile, BK=32, 4 waves 2x2, wave = 64x64 = 4x4 16x16x32 frags.
__global__ __launch_bounds__(256) void gemm_bf16s(const unsigned short* __restrict__ Ah,
                                                  const unsigned short* __restrict__ Al,
                                                  const unsigned short* __restrict__ Wh,
                                                  const unsigned short* __restrict__ Wl,
                                                  float* __restrict__ C,
                                                  int M, int N, int K) {
  __shared__ unsigned short AhS[128 * 32];
  __shared__ unsigned short AlS[128 * 32];
  __shared__ unsigned short WhS[128 * 32];
  __shared__ unsigned short WlS[128 * 32];
  const int t = threadIdx.x;
  const int l = t & 63;
  const int w = t >> 6;
  const int bm = blockIdx.y * 128;
  const int bn = blockIdx.x * 128;
  const int wm = (w >> 1) * 64;
  const int wn = (w & 1) * 64;

  f32x4 acc[4][4];
#pragma unroll
  for (int i = 0; i < 4; ++i)
#pragma unroll
    for (int j = 0; j < 4; ++j)
#pragma unroll
      for (int r = 0; r < 4; ++r) acc[i][j][r] = 0.f;

  const int srow = w * 32 + (l >> 2);
  const int scol = (l & 3) * 8;
  const size_t gOffA = (size_t)(bm + srow) * K + scol;
  const size_t gOffW = (size_t)(bn + srow) * K + scol;
  const size_t rowStep = (size_t)16 * K;
  unsigned short* lAh0 = &AhS[(w * 32) * 32];
  unsigned short* lAh1 = &AhS[(w * 32 + 16) * 32];
  unsigned short* lAl0 = &AlS[(w * 32) * 32];
  unsigned short* lAl1 = &AlS[(w * 32 + 16) * 32];
  unsigned short* lWh0 = &WhS[(w * 32) * 32];
  unsigned short* lWh1 = &WhS[(w * 32 + 16) * 32];
  unsigned short* lWl0 = &WlS[(w * 32) * 32];
  unsigned short* lWl1 = &WlS[(w * 32 + 16) * 32];

  for (int k0 = 0; k0 < K; k0 += 32) {
    __syncthreads();
    __builtin_amdgcn_global_load_lds((const AS1 void*)(Ah + gOffA + k0),           (AS3 void*)lAh0, 16, 0, 0);
    __builtin_amdgcn_global_load_lds((const AS1 void*)(Ah + gOffA + rowStep + k0), (AS3 void*)lAh1, 16, 0, 0);
    __builtin_amdgcn_global_load_lds((const AS1 void*)(Al + gOffA + k0),           (AS3 void*)lAl0, 16, 0, 0);
    __builtin_amdgcn_global_load_lds((const AS1 void*)(Al + gOffA + rowStep + k0), (AS3 void*)lAl1, 16, 0, 0);
    __builtin_amdgcn_global_load_lds((const AS1 void*)(Wh + gOffW + k0),           (AS3 void*)lWh0, 16, 0, 0);
    __builtin_amdgcn_global_load_lds((const AS1 void*)(Wh + gOffW + rowStep + k0), (AS3 void*)lWh1, 16, 0, 0);
    __builtin_amdgcn_global_load_lds((const AS1 void*)(Wl + gOffW + k0),           (AS3 void*)lWl0, 16, 0, 0);
    __builtin_amdgcn_global_load_lds((const AS1 void*)(Wl + gOffW + rowStep + k0), (AS3 void*)lWl1, 16, 0, 0);
    __syncthreads();

    bf16x8 ah[4], al[4], bh[4], bl[4];
#pragma unroll
    for (int i = 0; i < 4; ++i) {
      int aoff = (wm + i * 16 + (l & 15)) * 32 + (l >> 4) * 8;
      int boff = (wn + i * 16 + (l & 15)) * 32 + (l >> 4) * 8;
      ah[i] = *(const bf16x8*)&AhS[aoff];
      al[i] = *(const bf16x8*)&AlS[aoff];
      bh[i] = *(const bf16x8*)&WhS[boff];
      bl[i] = *(const bf16x8*)&WlS[boff];
    }
#pragma unroll
    for (int i = 0; i < 4; ++i)
#pragma unroll
      for (int j = 0; j < 4; ++j) {
        acc[i][j] = __builtin_amdgcn_mfma_f32_16x16x32_bf16(ah[i], bh[j], acc[i][j], 0, 0, 0);
        acc[i][j] = __builtin_amdgcn_mfma_f32_16x16x32_bf16(ah[i], bl[j], acc[i][j], 0, 0, 0);
        acc[i][j] = __builtin_amdgcn_mfma_f32_16x16x32_bf16(al[i], bh[j], acc[i][j], 0, 0, 0);
      }
  }

  const int cr = (l >> 4) * 4;
  const int cc = l & 15;
#pragma unroll
  for (int i = 0; i < 4; ++i)
#pragma unroll
    for (int j = 0; j < 4; ++j)
#pragma unroll
      for (int r = 0; r < 4; ++r)
        C[(size_t)(bm + wm + i * 16 + cr + r) * N + (bn + wn + j * 16 + cc)] = acc[i][j][r];
}

// ---------------- RoPE (in-place on q and k), q also scaled by HK^-0.5 -------
__global__ __launch_bounds__(256) void rope_kernel(float* __restrict__ q,
                                                   float* __restrict__ k) {
  int idx = blockIdx.x * 256 + threadIdx.x;     // over B*T*H*128 = 4,194,304
  int f  = idx & 127;
  int h  = (idx >> 7) & 3;
  int tt = (idx >> 9) & 2047;
  int b  = idx >> 20;
  size_t a0 = ((size_t)(b * T_SEQ + tt)) * KDIM + h * HK + f;
  size_t a1 = a0 + 128;
  float invf = powf(10000.0f, -(float)f * (1.0f / 128.0f));
  float ang  = (float)tt * invf;
  float s, c;
  sincosf(ang, &s, &c);
  float q1 = q[a0], q2 = q[a1];
  q[a0] = (q1 * c - q2 * s) * 0.0625f;
  q[a1] = (q2 * c + q1 * s) * 0.0625f;
  float k1 = k[a0], k2 = k[a1];
  k[a0] = k1 * c - k2 * s;
  k[a1] = k2 * c + k1 * s;
}

// ---------------- Retention pass 1: intra-chunk (fully parallel) -------------
__global__ __launch_bounds__(256) void retn_intra(const float* __restrict__ q,
                                                  const float* __restrict__ k,
                                                  const float* __restrict__ v,
                                                  float* __restrict__ o) {
  const int n = blockIdx.x, h = blockIdx.y, b = blockIdx.z;
  const int t = threadIdx.x;
  const int t0 = n * 64;
  __shared__ float gpow[65];
  __shared__ float qS[64][65];
  __shared__ float kS[64][65];
  __shared__ float attnS[64][65];
  if (t <= 64) {
    float gamma = 1.0f - exp2f(-5.0f - (float)h);
    gpow[t] = powf(gamma, (float)t);
  }
  const size_t baseQK = (size_t)(b * T_SEQ + t0) * KDIM + h * HK;
  const size_t baseV  = (size_t)(b * T_SEQ + t0) * VDIM + h * HV;
  const int i0 = (t >> 4) * 4;
  const int j0 = (t & 15) * 4;
  float acc[4][4] = {};
  for (int s = 0; s < 4; ++s) {              // dk slices of 64
    __syncthreads();
#pragma unroll
    for (int r = 0; r < 16; ++r) {
      int idx = t + 256 * r;
      int row = idx >> 6, col = idx & 63;
      qS[row][col] = q[baseQK + (size_t)row * KDIM + s * 64 + col];
      kS[row][col] = k[baseQK + (size_t)row * KDIM + s * 64 + col];
    }
    __syncthreads();
    for (int d = 0; d < 64; ++d) {
      float a0 = qS[i0][d], a1 = qS[i0 + 1][d], a2 = qS[i0 + 2][d], a3 = qS[i0 + 3][d];
#pragma unroll
      for (int jj = 0; jj < 4; ++jj) {
        float bv = kS[j0 + jj][d];
        acc[0][jj] = fmaf(a0, bv, acc[0][jj]);
        acc[1][jj] = fmaf(a1, bv, acc[1][jj]);
        acc[2][jj] = fmaf(a2, bv, acc[2][jj]);
        acc[3][jj] = fmaf(a3, bv, acc[3][jj]);
      }
    }
  }
  __syncthreads();
#pragma unroll
  for (int ii = 0; ii < 4; ++ii)
#pragma unroll
    for (int jj = 0; jj < 4; ++jj) {
      int i = i0 + ii, j = j0 + jj;
      attnS[i][j] = (i >= j) ? acc[ii][jj] * gpow[i - j] : 0.0f;
    }
  float (*vS)[65] = qS;
  for (int vb = 0; vb < 8; ++vb) {
    __syncthreads();
#pragma unroll
    for (int r = 0; r < 16; ++r) {
      int idx = t + 256 * r;
      int row = idx >> 6, col = idx & 63;
      vS[row][col] = v[baseV + (size_t)row * VDIM + vb * 64 + col];
    }
    __syncthreads();
    float oa[4][4] = {};
    for (int j = 0; j < 64; ++j) {
      float a0 = attnS[i0][j], a1 = attnS[i0 + 1][j], a2 = attnS[i0 + 2][j], a3 = attnS[i0 + 3][j];
#pragma unroll
      for (int jj = 0; jj < 4; ++jj) {
        float bv = vS[j][j0 + jj];
        oa[0][jj] = fmaf(a0, bv, oa[0][jj]);
        oa[1][jj] = fmaf(a1, bv, oa[1][jj]);
        oa[2][jj] = fmaf(a2, bv, oa[2][jj]);
        oa[3][jj] = fmaf(a3, bv, oa[3][jj]);
      }
    }
#pragma unroll
    for (int ii = 0; ii < 4; ++ii)
#pragma unroll
      for (int jj = 0; jj < 4; ++jj)
        o[baseV + (size_t)(i0 + ii) * VDIM + vb * 64 + j0 + jj] = oa[ii][jj];
  }
}

// =================== Retention inter-chunk: two-level scan ===================
//   A) retn_gstate: per (b,h,group of 8 chunks) local state sums T_g (g=0..2).
//   B) retn_scan: elementwise exclusive scan over groups: T_g -> S_in[g+1].
//   C) retn_inter2: per (b,h,g,dv-tile16) WG carries full dk=256 state in regs
//      (16/thread), seeded from S_in[g]; 8-chunk serial scan; o updated with
//      plain load+add+store (sole writer, NO atomics).
// ROUND-3 POST-MORTEM: halving S (64->32 regs) changed nothing: still VGPR=256
// + scratch (WRITE ~6.4GB of spill stores, 35ms first-touch). The pressure is
// NOT S -- it's the fully-unrolled b4 loop forming one straight-line region
// per chunk, letting the scheduler hoist later iterations' global q/k staging
// loads (up to 4 iters x 8 float4 = 128 VGPRs in flight) across barriers.
// v4 returns to the pressure profile of the PROVEN 88-VGPR round-0 kernel:
// S[4][4]=16 regs (dv-tile=16, col c0=t>>4), ONE 64x64 q-block + ONE 64x64
// k-block staged per b4 phase and consumed immediately, and a
// sched_barrier(0) after every __syncthreads to firewall scheduling regions.
// o RMW adds exact 0 for g==0,c==0 (S==0) -> no guard, uniform barriers.
// dvt siblings are 64 apart in linear block id (64%8==0 -> same XCD L2).

// ---- pass A: group-local state sums --------------------------------------
__global__ __launch_bounds__(256) void retn_gstate(const float* __restrict__ k,
                                                   const float* __restrict__ v,
                                                   float* __restrict__ Tbuf) {
  // grid (16, 3, 32): x = b*4+h, y = g (0..2), z: dkt = z>>3, dvt = z&7
  const int bh = blockIdx.x; const int b = bh >> 2, h = bh & 3;
  const int g = blockIdx.y;
  const int dkt = blockIdx.z >> 3, dvt = blockIdx.z & 7;
  const int t = threadIdx.x;
  __shared__ float gpow[65];
  __shared__ __align__(16) float kS[64][68];
  __shared__ __align__(16) float vS[64][68];
  if (t <= 64) gpow[t] = powf(1.0f - exp2f(-5.0f - (float)h), (float)t);
  __syncthreads();
  const float gC = gpow[64];
  const size_t baseK = (size_t)(b * T_SEQ + g * 512) * KDIM + h * HK + dkt * 64;
  const size_t baseV = (size_t)(b * T_SEQ + g * 512) * VDIM + h * HV + dvt * 64;
  const int dk0 = (t & 15) * 4, c0 = (t >> 4) * 4;
  float S[4][4] = {};
  for (int c = 0; c < 8; ++c) {
    const int t0 = c * 64;
    __syncthreads();
    __builtin_amdgcn_sched_barrier(0);
#pragma unroll
    for (int r = 0; r < 4; ++r) {
      int idx = t + 256 * r; int row = idx >> 4, c4 = (idx & 15) * 4;
      float4 kv = *(const float4*)&k[baseK + (size_t)(t0 + row) * KDIM + c4];
      float kd = gpow[63 - row];
      kv.x *= kd; kv.y *= kd; kv.z *= kd; kv.w *= kd;
      *(float4*)&kS[row][c4] = kv;
      *(float4*)&vS[row][c4] = *(const float4*)&v[baseV + (size_t)(t0 + row) * VDIM + c4];
    }
    __syncthreads();
    __builtin_amdgcn_sched_barrier(0);
#pragma unroll
    for (int ii = 0; ii < 4; ++ii)
#pragma unroll
      for (int jj = 0; jj < 4; ++jj) S[ii][jj] *= gC;
    for (int j = 0; j < 64; ++j) {
      float4 kv = *(const float4*)&kS[j][dk0];
      float4 vv = *(const float4*)&vS[j][c0];
      S[0][0] = fmaf(kv.x, vv.x, S[0][0]); S[0][1] = fmaf(kv.x, vv.y, S[0][1]);
      S[0][2] = fmaf(kv.x, vv.z, S[0][2]); S[0][3] = fmaf(kv.x, vv.w, S[0][3]);
      S[1][0] = fmaf(kv.y, vv.x, S[1][0]); S[1][1] = fmaf(kv.y, vv.y, S[1][1]);
      S[1][2] = fmaf(kv.y, vv.z, S[1][2]); S[1][3] = fmaf(kv.y, vv.w, S[1][3]);
      S[2][0] = fmaf(kv.z, vv.x, S[2][0]); S[2][1] = fmaf(kv.z, vv.y, S[2][1]);
      S[2][2] = fmaf(kv.z, vv.z, S[2][2]); S[2][3] = fmaf(kv.z, vv.w, S[2][3]);
      S[3][0] = fmaf(kv.w, vv.x, S[3][0]); S[3][1] = fmaf(kv.w, vv.y, S[3][1]);
      S[3][2] = fmaf(kv.w, vv.z, S[3][2]); S[3][3] = fmaf(kv.w, vv.w, S[3][3]);
    }
  }
  const size_t tb = (((size_t)g * 16 + bh) * 256 + dkt * 64 + dk0) * 512 + (size_t)dvt * 64 + c0;
#pragma unroll
  for (int ii = 0; ii < 4; ++ii)
    *(float4*)&Tbuf[tb + (size_t)ii * 512] = make_float4(S[ii][0], S[ii][1], S[ii][2], S[ii][3]);
}

// ---- pass B: exclusive scan over the 4 groups (in-place) ------------------
// slot g holds T_g on entry; on exit slot g holds S_in[g+1]:
//   S_in[1]=T0 (slot0 unchanged), S_in[2]=gG*T0+T1, S_in[3]=gG*S_in[2]+T2.
__global__ __launch_bounds__(256) void retn_scan(float* __restrict__ Tbuf) {
  int i = blockIdx.x * 256 + threadIdx.x;   // float4 index within one g-slab
  int h = (i >> 15) & 3;                    // (i*4)>>17 & 3
  float gamma = 1.0f - exp2f(-5.0f - (float)h);
  float gG = powf(gamma, 512.0f);           // gC^8 = gamma^(64*8)
  float4* T = (float4*)Tbuf;
  const int slab = 524288;                  // 16*256*512/4
  float4 t0 = T[i], t1 = T[i + slab], t2 = T[i + 2 * slab];
  float4 s2, s3;
  s2.x = fmaf(gG, t0.x, t1.x); s2.y = fmaf(gG, t0.y, t1.y);
  s2.z = fmaf(gG, t0.z, t1.z); s2.w = fmaf(gG, t0.w, t1.w);
  s3.x = fmaf(gG, s2.x, t2.x); s3.y = fmaf(gG, s2.y, t2.y);
  s3.z = fmaf(gG, s2.z, t2.z); s3.w = fmaf(gG, s2.w, t2.w);
  T[i + slab] = s2; T[i + 2 * slab] = s3;
}

// ---- pass C: inter-chunk output, full-dk state in regs, no atomics --------
__global__ __launch_bounds__(256) void retn_inter2(const float* __restrict__ q,
                                                   const float* __restrict__ k,
                                                   const float* __restrict__ v,
                                                   float* __restrict__ o,
                                                   const float* __restrict__ Sbuf) {
  // grid (16, 4, 32): x = b*4+h, y = g, z = dvt (16-wide dv tiles)
  const int bh = blockIdx.x; const int b = bh >> 2, h = bh & 3;
  const int g = blockIdx.y;
  const int dvt = blockIdx.z;
  const int t = threadIdx.x;
  __shared__ float gpow[65];
  __shared__ __align__(16) float qS[64][68];  // q~ block (64x64)
  __shared__ __align__(16) float kS[64][68];  // k~ block (64x64)
  __shared__            float sS[64][21];     // state-block publish (scalar only)
  __shared__ __align__(16) float vS[64][20];  // v chunk (64x16)
  if (t <= 64) gpow[t] = powf(1.0f - exp2f(-5.0f - (float)h), (float)t);
  __syncthreads();
  const float gC = gpow[64];
  const int rq = (t & 15) * 4;   // state rows within a dk-block (publish/j-loop)
  const int c0 = t >> 4;         // state col (0..15)
  const int i0 = (t >> 4) * 4;   // o-tile rows
  const int v0 = t & 15;         // o-tile col
  const size_t baseQK = (size_t)(b * T_SEQ + g * 512) * KDIM + h * HK;
  const size_t baseV  = (size_t)(b * T_SEQ + g * 512) * VDIM + h * HV + (size_t)dvt * 16;

  // S: 16 regs/thread, compile-time indices only (proven 88-VGPR profile).
  float S[4][4];                 // [dk-block][row]; this thread's col = c0
  if (g > 0) {
    const size_t sb = (((size_t)(g - 1) * 16 + bh) * 256) * 512 + (size_t)dvt * 16 + c0;
#pragma unroll
    for (int b4 = 0; b4 < 4; ++b4)
#pragma unroll
      for (int i = 0; i < 4; ++i)
        S[b4][i] = Sbuf[sb + (size_t)(b4 * 64 + rq + i) * 512];
  } else {
#pragma unroll
    for (int b4 = 0; b4 < 4; ++b4)
#pragma unroll
      for (int i = 0; i < 4; ++i) S[b4][i] = 0.f;
  }

  for (int c = 0; c < 8; ++c) {
    const int t0 = c * 64;
    __syncthreads();                       // prev chunk's vS readers done
    __builtin_amdgcn_sched_barrier(0);
    {  // stage v chunk 64x16 (one float4 per thread)
      int row = t >> 2, c4 = (t & 3) * 4;
      *(float4*)&vS[row][c4] = *(const float4*)&v[baseV + (size_t)(t0 + row) * VDIM + c4];
    }
    float oa0 = 0.f, oa1 = 0.f, oa2 = 0.f, oa3 = 0.f;
#pragma unroll
    for (int b4 = 0; b4 < 4; ++b4) {
      __syncthreads();                     // prev b4's qS/kS/sS readers done (covers vS write at b4=0)
      __builtin_amdgcn_sched_barrier(0);
      // publish this dk-block of S (OLD state) for the o-phase
#pragma unroll
      for (int i = 0; i < 4; ++i)
        sS[rq + i][c0] = S[b4][i];
      // stage q~ block (64x64), scaled by cross_dec
#pragma unroll
      for (int r = 0; r < 4; ++r) {
        int idx = t + 256 * r; int row = idx >> 4, c4 = (idx & 15) * 4;
        float4 qv = *(const float4*)&q[baseQK + (size_t)(t0 + row) * KDIM + b4 * 64 + c4];
        float gp = gpow[row + 1];
        qv.x *= gp; qv.y *= gp; qv.z *= gp; qv.w *= gp;
        *(float4*)&qS[row][c4] = qv;
      }
      // stage k~ block (64x64), scaled by k_dec
#pragma unroll
      for (int r = 0; r < 4; ++r) {
        int idx = t + 256 * r; int row = idx >> 4, c4 = (idx & 15) * 4;
        float4 kv = *(const float4*)&k[baseQK + (size_t)(t0 + row) * KDIM + b4 * 64 + c4];
        float kd = gpow[63 - row];
        kv.x *= kd; kv.y *= kd; kv.z *= kd; kv.w *= kd;
        *(float4*)&kS[row][c4] = kv;
      }
      __syncthreads();
      __builtin_amdgcn_sched_barrier(0);
      // o-phase: oa += q~S(64x64) @ sS(64x16), this thread: 4 rows x col v0
      for (int d = 0; d < 64; d += 4) {
        float4 a0 = *(const float4*)&qS[i0 + 0][d];
        float4 a1 = *(const float4*)&qS[i0 + 1][d];
        float4 a2 = *(const float4*)&qS[i0 + 2][d];
        float4 a3 = *(const float4*)&qS[i0 + 3][d];
        float s0 = sS[d + 0][v0];
        float s1 = sS[d + 1][v0];
        float s2 = sS[d + 2][v0];
        float s3 = sS[d + 3][v0];
        oa0 = fmaf(a0.x, s0, oa0); oa0 = fmaf(a0.y, s1, oa0);
        oa0 = fmaf(a0.z, s2, oa0); oa0 = fmaf(a0.w, s3, oa0);
        oa1 = fmaf(a1.x, s0, oa1); oa1 = fmaf(a1.y, s1, oa1);
        oa1 = fmaf(a1.z, s2, oa1); oa1 = fmaf(a1.w, s3, oa1);
        oa2 = fmaf(a2.x, s0, oa2); oa2 = fmaf(a2.y, s1, oa2);
        oa2 = fmaf(a2.z, s2, oa2); oa2 = fmaf(a2.w, s3, oa2);
        oa3 = fmaf(a3.x, s0, oa3); oa3 = fmaf(a3.y, s1, oa3);
        oa3 = fmaf(a3.z, s2, oa3); oa3 = fmaf(a3.w, s3, oa3);
      }
      // update: S[b4] = gC*S[b4] + k~^T v (rows rq..rq+3, col c0)
      S[b4][0] *= gC; S[b4][1] *= gC; S[b4][2] *= gC; S[b4][3] *= gC;
      for (int j = 0; j < 64; ++j) {
        float4 kv = *(const float4*)&kS[j][rq];
        float vv = vS[j][c0];
        S[b4][0] = fmaf(kv.x, vv, S[b4][0]);
        S[b4][1] = fmaf(kv.y, vv, S[b4][1]);
        S[b4][2] = fmaf(kv.z, vv, S[b4][2]);
        S[b4][3] = fmaf(kv.w, vv, S[b4][3]);
      }
    }
    // o += oa (adds exact 0.0 when g==0 && c==0 since S==0 -> no guard)
    {
      size_t a0 = baseV + (size_t)(t0 + i0 + 0) * VDIM + v0;
      size_t a1 = baseV + (size_t)(t0 + i0 + 1) * VDIM + v0;
      size_t a2 = baseV + (size_t)(t0 + i0 + 2) * VDIM + v0;
      size_t a3 = baseV + (size_t)(t0 + i0 + 3) * VDIM + v0;
      o[a0] += oa0; o[a1] += oa1; o[a2] += oa2; o[a3] += oa3;
    }
  }
}

// ---------------- RMS group-norm over HEAD_V + SiLU(g) gate (in-place) -------
__global__ __launch_bounds__(256) void norm_gate(float* __restrict__ o,
                                                 const float* __restrict__ g,
                                                 const float* __restrict__ gnw) {
  const int row = blockIdx.x;
  const size_t base = (size_t)row * 512;
  const int t = threadIdx.x;
  float x0 = o[base + t], x1 = o[base + t + 256];
  float ss = x0 * x0 + x1 * x1;
#pragma unroll
  for (int off = 32; off > 0; off >>= 1) ss += __shfl_down(ss, off, 64);
  __shared__ float wsum[4];
  if ((t & 63) == 0) wsum[t >> 6] = ss;
  __syncthreads();
  float tot = wsum[0] + wsum[1] + wsum[2] + wsum[3];
  float scale = rsqrtf(tot * (1.0f / 512.0f) + 1e-5f);
  float g0 = g[base + t], g1 = g[base + t + 256];
  o[base + t]       = x0 * scale * gnw[t]       * (g0 / (1.0f + expf(-g0)));
  o[base + t + 256] = x1 * scale * gnw[t + 256] * (g1 / (1.0f + expf(-g1)));
}

extern "C" void kernel_launch(void* const* d_in, const int* in_sizes, int n_in,
                              void* d_out, int out_size, void* d_ws, size_t ws_size,
                              hipStream_t stream) {
  const float* x   = (const float*)d_in[0];
  const float* Wq  = (const float*)d_in[1];
  const float* Wk  = (const float*)d_in[2];
  const float* Wv  = (const float*)d_in[3];
  const float* Wg  = (const float*)d_in[4];
  const float* Wo  = (const float*)d_in[5];
  const float* gnw = (const float*)d_in[6];
  float* out = (float*)d_out;

  // workspace = 256 MiB exactly:
  // [q 32][k 32][v 64][o 64][x-splits 32][W-splits 32]
  // o-splits (64) alias dead v; g (64) aliases dead q+k.
  // d_out (32 MiB) doubles as group-state scratch (24 MiB) until final GEMM.
  const size_t M8 = (size_t)8192;
  float* q  = (float*)d_ws;
  float* kk = q  + M8 * 1024;
  float* v  = kk + M8 * 1024;
  float* o  = v  + M8 * 2048;
  unsigned short* xh  = (unsigned short*)(o + M8 * 2048);
  unsigned short* xl  = xh  + M8 * 1024;
  unsigned short* wqh = xl  + M8 * 1024;
  unsigned short* wql = wqh + (size_t)1024 * 1024;
  unsigned short* wkh = wql + (size_t)1024 * 1024;
  unsigned short* wkl = wkh + (size_t)1024 * 1024;
  unsigned short* wvh = wkl + (size_t)1024 * 1024;
  unsigned short* wvl = wvh + (size_t)2048 * 1024;
  unsigned short* wgh = wvl + (size_t)2048 * 1024;
  unsigned short* wgl = wgh + (size_t)2048 * 1024;
  unsigned short* woh = wgl + (size_t)2048 * 1024;
  unsigned short* wol = woh + (size_t)2048 * 1024;
  unsigned short* oh  = (unsigned short*)v;
  unsigned short* ol  = oh + M8 * 2048;
  float* g = q;
  float* Tbuf = (float*)d_out;   // 24 MiB scratch, dead until final GEMM

  dim3 blk(256);
  cast_split<<<dim3(8192), blk, 0, stream>>>(x,  xh,  xl,  2097152);
  cast_split<<<dim3(1024), blk, 0, stream>>>(Wq, wqh, wql, 262144);
  cast_split<<<dim3(1024), blk, 0, stream>>>(Wk, wkh, wkl, 262144);
  cast_split<<<dim3(2048), blk, 0, stream>>>(Wv, wvh, wvl, 524288);
  cast_split<<<dim3(2048), blk, 0, stream>>>(Wg, wgh, wgl, 524288);
  cast_split<<<dim3(2048), blk, 0, stream>>>(Wo, woh, wol, 524288);

  gemm_bf16s<<<dim3(8, 64),  blk, 0, stream>>>(xh, xl, wqh, wql, q,  8192, 1024, 1024);
  gemm_bf16s<<<dim3(8, 64),  blk, 0, stream>>>(xh, xl, wkh, wkl, kk, 8192, 1024, 1024);
  gemm_bf16s<<<dim3(16, 64), blk, 0, stream>>>(xh, xl, wvh, wvl, v,  8192, 2048, 1024);
  rope_kernel<<<dim3(16384), blk, 0, stream>>>(q, kk);
  retn_gstate<<<dim3(16, 3, 32), blk, 0, stream>>>(kk, v, Tbuf);
  retn_scan<<<dim3(2048), blk, 0, stream>>>(Tbuf);
  retn_intra<<<dim3(32, 4, 4),  blk, 0, stream>>>(q, kk, v, o);
  retn_inter2<<<dim3(16, 4, 32), blk, 0, stream>>>(q, kk, v, o, Tbuf);
  gemm_bf16s<<<dim3(16, 64), blk, 0, stream>>>(xh, xl, wgh, wgl, g, 8192, 2048, 1024);
  norm_gate<<<dim3(32768), blk, 0, stream>>>(o, g, gnw);
  cast_split<<<dim3(16384), blk, 0, stream>>>(o, oh, ol, 4194304);
  gemm_bf16s<<<dim3(8, 64),  blk, 0, stream>>>(oh, ol, woh, wol, out, 8192, 1024, 2048);
}

// Round 5
// 1152.789 us; speedup vs baseline: 8.7326x; 1.1159x over previous
//
#include <hip/hip_runtime.h>
#include <cstdint>
#include <cstddef>

#define T_SEQ 2048
#define DM    1024
#define HK    256
#define HV    512
#define NH    4
#define KDIM  1024
#define VDIM  2048

typedef __attribute__((ext_vector_type(8))) short bf16x8;
typedef __attribute__((ext_vector_type(4))) float f32x4;
#define AS1 __attribute__((address_space(1)))
#define AS3 __attribute__((address_space(3)))

// ---------------- f32 -> (hi, lo) bf16 split (RNE), vectorized x4 ------------
static __device__ inline unsigned short f2bf(float f) {
  unsigned u = __float_as_uint(f);
  unsigned rnd = 0x7fffu + ((u >> 16) & 1u);
  return (unsigned short)((u + rnd) >> 16);
}
static __device__ inline float bf2f(unsigned short h) {
  unsigned u = ((unsigned)h) << 16;
  return __uint_as_float(u);
}

__global__ __launch_bounds__(256) void cast_split(const float* __restrict__ in,
                                                  unsigned short* __restrict__ hi,
                                                  unsigned short* __restrict__ lo,
                                                  int n4) {
  int i = blockIdx.x * 256 + threadIdx.x;
  if (i >= n4) return;
  float4 v = ((const float4*)in)[i];
  ushort4 h, l;
  h.x = f2bf(v.x); l.x = f2bf(v.x - bf2f(h.x));
  h.y = f2bf(v.y); l.y = f2bf(v.y - bf2f(h.y));
  h.z = f2bf(v.z); l.z = f2bf(v.z - bf2f(h.z));
  h.w = f2bf(v.w); l.w = f2bf(v.w - bf2f(h.w));
  ((ushort4*)hi)[i] = h;
  ((ushort4*)lo)[i] = l;
}

// -------- split-precision bf16 MFMA GEMM: C = A @ W^T, A=Ah+Al, W=Wh+Wl ------
// C ~= Ah*Wh + Ah*Wl + Al*Wh (f32 accumulate; lo*lo term ~2^-16 rel, dropped).
// 128x128 tile, BK=32, 4 waves 2x2, wave = 64x64 = 4x4 16x16x32 frags.
__global__ __launch_bounds__(256) void gemm_bf16s(const unsigned short* __restrict__ Ah,
                                                  const unsigned short* __restrict__ Al,
                                                  const unsigned short* __restrict__ Wh,
                                                  const unsigned short* __restrict__ Wl,
                                                  float* __restrict__ C,
                                                  int M, int N, int K) {
  __shared__ unsigned short AhS[128 * 32];
  __shared__ unsigned short AlS[128 * 32];
  __shared__ unsigned short WhS[128 * 32];
  __shared__ unsigned short WlS[128 * 32];
  const int t = threadIdx.x;
  const int l = t & 63;
  const int w = t >> 6;
  const int bm = blockIdx.y * 128;
  const int bn = blockIdx.x * 128;
  const int wm = (w >> 1) * 64;
  const int wn = (w & 1) * 64;

  f32x4 acc[4][4];
#pragma unroll
  for (int i = 0; i < 4; ++i)
#pragma unroll
    for (int j = 0; j < 4; ++j)
#pragma unroll
      for (int r = 0; r < 4; ++r) acc[i][j][r] = 0.f;

  const int srow = w * 32 + (l >> 2);
  const int scol = (l & 3) * 8;
  const size_t gOffA = (size_t)(bm + srow) * K + scol;
  const size_t gOffW = (size_t)(bn + srow) * K + scol;
  const size_t rowStep = (size_t)16 * K;
  unsigned short* lAh0 = &AhS[(w * 32) * 32];
  unsigned short* lAh1 = &AhS[(w * 32 + 16) * 32];
  unsigned short* lAl0 = &AlS[(w * 32) * 32];
  unsigned short* lAl1 = &AlS[(w * 32 + 16) * 32];
  unsigned short* lWh0 = &WhS[(w * 32) * 32];
  unsigned short* lWh1 = &WhS[(w * 32 + 16) * 32];
  unsigned short* lWl0 = &WlS[(w * 32) * 32];
  unsigned short* lWl1 = &WlS[(w * 32 + 16) * 32];

  for (int k0 = 0; k0 < K; k0 += 32) {
    __syncthreads();
    __builtin_amdgcn_global_load_lds((const AS1 void*)(Ah + gOffA + k0),           (AS3 void*)lAh0, 16, 0, 0);
    __builtin_amdgcn_global_load_lds((const AS1 void*)(Ah + gOffA + rowStep + k0), (AS3 void*)lAh1, 16, 0, 0);
    __builtin_amdgcn_global_load_lds((const AS1 void*)(Al + gOffA + k0),           (AS3 void*)lAl0, 16, 0, 0);
    __builtin_amdgcn_global_load_lds((const AS1 void*)(Al + gOffA + rowStep + k0), (AS3 void*)lAl1, 16, 0, 0);
    __builtin_amdgcn_global_load_lds((const AS1 void*)(Wh + gOffW + k0),           (AS3 void*)lWh0, 16, 0, 0);
    __builtin_amdgcn_global_load_lds((const AS1 void*)(Wh + gOffW + rowStep + k0), (AS3 void*)lWh1, 16, 0, 0);
    __builtin_amdgcn_global_load_lds((const AS1 void*)(Wl + gOffW + k0),           (AS3 void*)lWl0, 16, 0, 0);
    __builtin_amdgcn_global_load_lds((const AS1 void*)(Wl + gOffW + rowStep + k0), (AS3 void*)lWl1, 16, 0, 0);
    __syncthreads();

    bf16x8 ah[4], al[4], bh[4], bl[4];
#pragma unroll
    for (int i = 0; i < 4; ++i) {
      int aoff = (wm + i * 16 + (l & 15)) * 32 + (l >> 4) * 8;
      int boff = (wn + i * 16 + (l & 15)) * 32 + (l >> 4) * 8;
      ah[i] = *(const bf16x8*)&AhS[aoff];
      al[i] = *(const bf16x8*)&AlS[aoff];
      bh[i] = *(const bf16x8*)&WhS[boff];
      bl[i] = *(const bf16x8*)&WlS[boff];
    }
#pragma unroll
    for (int i = 0; i < 4; ++i)
#pragma unroll
      for (int j = 0; j < 4; ++j) {
        acc[i][j] = __builtin_amdgcn_mfma_f32_16x16x32_bf16(ah[i], bh[j], acc[i][j], 0, 0, 0);
        acc[i][j] = __builtin_amdgcn_mfma_f32_16x16x32_bf16(ah[i], bl[j], acc[i][j], 0, 0, 0);
        acc[i][j] = __builtin_amdgcn_mfma_f32_16x16x32_bf16(al[i], bh[j], acc[i][j], 0, 0, 0);
      }
  }

  const int cr = (l >> 4) * 4;
  const int cc = l & 15;
#pragma unroll
  for (int i = 0; i < 4; ++i)
#pragma unroll
    for (int j = 0; j < 4; ++j)
#pragma unroll
      for (int r = 0; r < 4; ++r)
        C[(size_t)(bm + wm + i * 16 + cr + r) * N + (bn + wn + j * 16 + cc)] = acc[i][j][r];
}

// ---------------- RoPE (in-place on q and k), q also scaled by HK^-0.5 -------
__global__ __launch_bounds__(256) void rope_kernel(float* __restrict__ q,
                                                   float* __restrict__ k) {
  int idx = blockIdx.x * 256 + threadIdx.x;     // over B*T*H*128 = 4,194,304
  int f  = idx & 127;
  int h  = (idx >> 7) & 3;
  int tt = (idx >> 9) & 2047;
  int b  = idx >> 20;
  size_t a0 = ((size_t)(b * T_SEQ + tt)) * KDIM + h * HK + f;
  size_t a1 = a0 + 128;
  float invf = powf(10000.0f, -(float)f * (1.0f / 128.0f));
  float ang  = (float)tt * invf;
  float s, c;
  sincosf(ang, &s, &c);
  float q1 = q[a0], q2 = q[a1];
  q[a0] = (q1 * c - q2 * s) * 0.0625f;
  q[a1] = (q2 * c + q1 * s) * 0.0625f;
  float k1 = k[a0], k2 = k[a1];
  k[a0] = k1 * c - k2 * s;
  k[a1] = k2 * c + k1 * s;
}

// ---------------- Retention pass 1: intra-chunk (fully parallel) -------------
// Round-5: float4-blocked LDS reads (pad 65->68 for 16B row alignment).
// Same accumulation order as the scalar version (d and j sequential) ->
// bitwise-identical results; ~4x fewer LDS instructions.
__global__ __launch_bounds__(256) void retn_intra(const float* __restrict__ q,
                                                  const float* __restrict__ k,
                                                  const float* __restrict__ v,
                                                  float* __restrict__ o) {
  const int n = blockIdx.x, h = blockIdx.y, b = blockIdx.z;
  const int t = threadIdx.x;
  const int t0 = n * 64;
  __shared__ float gpow[65];
  __shared__ __align__(16) float qS[64][68];
  __shared__ __align__(16) float kS[64][68];
  __shared__ __align__(16) float attnS[64][68];
  if (t <= 64) {
    float gamma = 1.0f - exp2f(-5.0f - (float)h);
    gpow[t] = powf(gamma, (float)t);
  }
  const size_t baseQK = (size_t)(b * T_SEQ + t0) * KDIM + h * HK;
  const size_t baseV  = (size_t)(b * T_SEQ + t0) * VDIM + h * HV;
  const int i0 = (t >> 4) * 4;
  const int j0 = (t & 15) * 4;
  float acc[4][4] = {};
  for (int s = 0; s < 4; ++s) {              // dk slices of 64
    __syncthreads();
    __builtin_amdgcn_sched_barrier(0);
#pragma unroll
    for (int r = 0; r < 4; ++r) {            // stage 64x64 as float4
      int idx = t + 256 * r;
      int row = idx >> 4, c4 = (idx & 15) * 4;
      *(float4*)&qS[row][c4] = *(const float4*)&q[baseQK + (size_t)row * KDIM + s * 64 + c4];
      *(float4*)&kS[row][c4] = *(const float4*)&k[baseQK + (size_t)row * KDIM + s * 64 + c4];
    }
    __syncthreads();
    __builtin_amdgcn_sched_barrier(0);
    for (int d = 0; d < 64; d += 4) {
      float4 a0 = *(const float4*)&qS[i0 + 0][d];
      float4 a1 = *(const float4*)&qS[i0 + 1][d];
      float4 a2 = *(const float4*)&qS[i0 + 2][d];
      float4 a3 = *(const float4*)&qS[i0 + 3][d];
      float4 b0 = *(const float4*)&kS[j0 + 0][d];
      float4 b1 = *(const float4*)&kS[j0 + 1][d];
      float4 b2 = *(const float4*)&kS[j0 + 2][d];
      float4 b3 = *(const float4*)&kS[j0 + 3][d];
      acc[0][0]=fmaf(a0.x,b0.x,acc[0][0]); acc[0][0]=fmaf(a0.y,b0.y,acc[0][0]); acc[0][0]=fmaf(a0.z,b0.z,acc[0][0]); acc[0][0]=fmaf(a0.w,b0.w,acc[0][0]);
      acc[0][1]=fmaf(a0.x,b1.x,acc[0][1]); acc[0][1]=fmaf(a0.y,b1.y,acc[0][1]); acc[0][1]=fmaf(a0.z,b1.z,acc[0][1]); acc[0][1]=fmaf(a0.w,b1.w,acc[0][1]);
      acc[0][2]=fmaf(a0.x,b2.x,acc[0][2]); acc[0][2]=fmaf(a0.y,b2.y,acc[0][2]); acc[0][2]=fmaf(a0.z,b2.z,acc[0][2]); acc[0][2]=fmaf(a0.w,b2.w,acc[0][2]);
      acc[0][3]=fmaf(a0.x,b3.x,acc[0][3]); acc[0][3]=fmaf(a0.y,b3.y,acc[0][3]); acc[0][3]=fmaf(a0.z,b3.z,acc[0][3]); acc[0][3]=fmaf(a0.w,b3.w,acc[0][3]);
      acc[1][0]=fmaf(a1.x,b0.x,acc[1][0]); acc[1][0]=fmaf(a1.y,b0.y,acc[1][0]); acc[1][0]=fmaf(a1.z,b0.z,acc[1][0]); acc[1][0]=fmaf(a1.w,b0.w,acc[1][0]);
      acc[1][1]=fmaf(a1.x,b1.x,acc[1][1]); acc[1][1]=fmaf(a1.y,b1.y,acc[1][1]); acc[1][1]=fmaf(a1.z,b1.z,acc[1][1]); acc[1][1]=fmaf(a1.w,b1.w,acc[1][1]);
      acc[1][2]=fmaf(a1.x,b2.x,acc[1][2]); acc[1][2]=fmaf(a1.y,b2.y,acc[1][2]); acc[1][2]=fmaf(a1.z,b2.z,acc[1][2]); acc[1][2]=fmaf(a1.w,b2.w,acc[1][2]);
      acc[1][3]=fmaf(a1.x,b3.x,acc[1][3]); acc[1][3]=fmaf(a1.y,b3.y,acc[1][3]); acc[1][3]=fmaf(a1.z,b3.z,acc[1][3]); acc[1][3]=fmaf(a1.w,b3.w,acc[1][3]);
      acc[2][0]=fmaf(a2.x,b0.x,acc[2][0]); acc[2][0]=fmaf(a2.y,b0.y,acc[2][0]); acc[2][0]=fmaf(a2.z,b0.z,acc[2][0]); acc[2][0]=fmaf(a2.w,b0.w,acc[2][0]);
      acc[2][1]=fmaf(a2.x,b1.x,acc[2][1]); acc[2][1]=fmaf(a2.y,b1.y,acc[2][1]); acc[2][1]=fmaf(a2.z,b1.z,acc[2][1]); acc[2][1]=fmaf(a2.w,b1.w,acc[2][1]);
      acc[2][2]=fmaf(a2.x,b2.x,acc[2][2]); acc[2][2]=fmaf(a2.y,b2.y,acc[2][2]); acc[2][2]=fmaf(a2.z,b2.z,acc[2][2]); acc[2][2]=fmaf(a2.w,b2.w,acc[2][2]);
      acc[2][3]=fmaf(a2.x,b3.x,acc[2][3]); acc[2][3]=fmaf(a2.y,b3.y,acc[2][3]); acc[2][3]=fmaf(a2.z,b3.z,acc[2][3]); acc[2][3]=fmaf(a2.w,b3.w,acc[2][3]);
      acc[3][0]=fmaf(a3.x,b0.x,acc[3][0]); acc[3][0]=fmaf(a3.y,b0.y,acc[3][0]); acc[3][0]=fmaf(a3.z,b0.z,acc[3][0]); acc[3][0]=fmaf(a3.w,b0.w,acc[3][0]);
      acc[3][1]=fmaf(a3.x,b1.x,acc[3][1]); acc[3][1]=fmaf(a3.y,b1.y,acc[3][1]); acc[3][1]=fmaf(a3.z,b1.z,acc[3][1]); acc[3][1]=fmaf(a3.w,b1.w,acc[3][1]);
      acc[3][2]=fmaf(a3.x,b2.x,acc[3][2]); acc[3][2]=fmaf(a3.y,b2.y,acc[3][2]); acc[3][2]=fmaf(a3.z,b2.z,acc[3][2]); acc[3][2]=fmaf(a3.w,b2.w,acc[3][2]);
      acc[3][3]=fmaf(a3.x,b3.x,acc[3][3]); acc[3][3]=fmaf(a3.y,b3.y,acc[3][3]); acc[3][3]=fmaf(a3.z,b3.z,acc[3][3]); acc[3][3]=fmaf(a3.w,b3.w,acc[3][3]);
    }
  }
  __syncthreads();
#pragma unroll
  for (int ii = 0; ii < 4; ++ii)
#pragma unroll
    for (int jj = 0; jj < 4; ++jj) {
      int i = i0 + ii, j = j0 + jj;
      attnS[i][j] = (i >= j) ? acc[ii][jj] * gpow[i - j] : 0.0f;
    }
  float (*vS)[68] = qS;
  for (int vb = 0; vb < 8; ++vb) {
    __syncthreads();
    __builtin_amdgcn_sched_barrier(0);
#pragma unroll
    for (int r = 0; r < 4; ++r) {
      int idx = t + 256 * r;
      int row = idx >> 4, c4 = (idx & 15) * 4;
      *(float4*)&vS[row][c4] = *(const float4*)&v[baseV + (size_t)row * VDIM + vb * 64 + c4];
    }
    __syncthreads();
    __builtin_amdgcn_sched_barrier(0);
    float oa[4][4] = {};
    for (int j = 0; j < 64; j += 4) {
      float4 p0 = *(const float4*)&attnS[i0 + 0][j];
      float4 p1 = *(const float4*)&attnS[i0 + 1][j];
      float4 p2 = *(const float4*)&attnS[i0 + 2][j];
      float4 p3 = *(const float4*)&attnS[i0 + 3][j];
      float4 v0 = *(const float4*)&vS[j + 0][j0];
      float4 v1 = *(const float4*)&vS[j + 1][j0];
      float4 v2 = *(const float4*)&vS[j + 2][j0];
      float4 v3 = *(const float4*)&vS[j + 3][j0];
      oa[0][0]=fmaf(p0.x,v0.x,oa[0][0]); oa[0][0]=fmaf(p0.y,v1.x,oa[0][0]); oa[0][0]=fmaf(p0.z,v2.x,oa[0][0]); oa[0][0]=fmaf(p0.w,v3.x,oa[0][0]);
      oa[0][1]=fmaf(p0.x,v0.y,oa[0][1]); oa[0][1]=fmaf(p0.y,v1.y,oa[0][1]); oa[0][1]=fmaf(p0.z,v2.y,oa[0][1]); oa[0][1]=fmaf(p0.w,v3.y,oa[0][1]);
      oa[0][2]=fmaf(p0.x,v0.z,oa[0][2]); oa[0][2]=fmaf(p0.y,v1.z,oa[0][2]); oa[0][2]=fmaf(p0.z,v2.z,oa[0][2]); oa[0][2]=fmaf(p0.w,v3.z,oa[0][2]);
      oa[0][3]=fmaf(p0.x,v0.w,oa[0][3]); oa[0][3]=fmaf(p0.y,v1.w,oa[0][3]); oa[0][3]=fmaf(p0.z,v2.w,oa[0][3]); oa[0][3]=fmaf(p0.w,v3.w,oa[0][3]);
      oa[1][0]=fmaf(p1.x,v0.x,oa[1][0]); oa[1][0]=fmaf(p1.y,v1.x,oa[1][0]); oa[1][0]=fmaf(p1.z,v2.x,oa[1][0]); oa[1][0]=fmaf(p1.w,v3.x,oa[1][0]);
      oa[1][1]=fmaf(p1.x,v0.y,oa[1][1]); oa[1][1]=fmaf(p1.y,v1.y,oa[1][1]); oa[1][1]=fmaf(p1.z,v2.y,oa[1][1]); oa[1][1]=fmaf(p1.w,v3.y,oa[1][1]);
      oa[1][2]=fmaf(p1.x,v0.z,oa[1][2]); oa[1][2]=fmaf(p1.y,v1.z,oa[1][2]); oa[1][2]=fmaf(p1.z,v2.z,oa[1][2]); oa[1][2]=fmaf(p1.w,v3.z,oa[1][2]);
      oa[1][3]=fmaf(p1.x,v0.w,oa[1][3]); oa[1][3]=fmaf(p1.y,v1.w,oa[1][3]); oa[1][3]=fmaf(p1.z,v2.w,oa[1][3]); oa[1][3]=fmaf(p1.w,v3.w,oa[1][3]);
      oa[2][0]=fmaf(p2.x,v0.x,oa[2][0]); oa[2][0]=fmaf(p2.y,v1.x,oa[2][0]); oa[2][0]=fmaf(p2.z,v2.x,oa[2][0]); oa[2][0]=fmaf(p2.w,v3.x,oa[2][0]);
      oa[2][1]=fmaf(p2.x,v0.y,oa[2][1]); oa[2][1]=fmaf(p2.y,v1.y,oa[2][1]); oa[2][1]=fmaf(p2.z,v2.y,oa[2][1]); oa[2][1]=fmaf(p2.w,v3.y,oa[2][1]);
      oa[2][2]=fmaf(p2.x,v0.z,oa[2][2]); oa[2][2]=fmaf(p2.y,v1.z,oa[2][2]); oa[2][2]=fmaf(p2.z,v2.z,oa[2][2]); oa[2][2]=fmaf(p2.w,v3.z,oa[2][2]);
      oa[2][3]=fmaf(p2.x,v0.w,oa[2][3]); oa[2][3]=fmaf(p2.y,v1.w,oa[2][3]); oa[2][3]=fmaf(p2.z,v2.w,oa[2][3]); oa[2][3]=fmaf(p2.w,v3.w,oa[2][3]);
      oa[3][0]=fmaf(p3.x,v0.x,oa[3][0]); oa[3][0]=fmaf(p3.y,v1.x,oa[3][0]); oa[3][0]=fmaf(p3.z,v2.x,oa[3][0]); oa[3][0]=fmaf(p3.w,v3.x,oa[3][0]);
      oa[3][1]=fmaf(p3.x,v0.y,oa[3][1]); oa[3][1]=fmaf(p3.y,v1.y,oa[3][1]); oa[3][1]=fmaf(p3.z,v2.y,oa[3][1]); oa[3][1]=fmaf(p3.w,v3.y,oa[3][1]);
      oa[3][2]=fmaf(p3.x,v0.z,oa[3][2]); oa[3][2]=fmaf(p3.y,v1.z,oa[3][2]); oa[3][2]=fmaf(p3.z,v2.z,oa[3][2]); oa[3][2]=fmaf(p3.w,v3.z,oa[3][2]);
      oa[3][3]=fmaf(p3.x,v0.w,oa[3][3]); oa[3][3]=fmaf(p3.y,v1.w,oa[3][3]); oa[3][3]=fmaf(p3.z,v2.w,oa[3][3]); oa[3][3]=fmaf(p3.w,v3.w,oa[3][3]);
    }
#pragma unroll
    for (int ii = 0; ii < 4; ++ii)
      *(float4*)&o[baseV + (size_t)(i0 + ii) * VDIM + vb * 64 + j0] =
          make_float4(oa[ii][0], oa[ii][1], oa[ii][2], oa[ii][3]);
  }
}

// =================== Retention inter-chunk: two-level scan ===================
//   A) retn_gstate: per (b,h,group of 8 chunks) local state sums T_g (g=0..2).
//   B) retn_scan: elementwise exclusive scan over groups: T_g -> S_in[g+1].
//   C) retn_inter2: per (b,h,g,dv-tile32) WG carries full dk=256 state in regs
//      (32/thread), seeded from S_in[g]; 8-chunk serial scan; o updated with
//      plain load+add+store (sole writer, NO atomics).
// ROUND-4 POST-MORTEM (spill fixed): one-staging-block-per-phase, consumed
// immediately, with sched_barrier(0) after every __syncthreads => VGPR 76,
// zero scratch, 530us. That kernel was LDS-issue-bound (VALUBusy 40%,
// ~1 FMA per LDS float read). ROUND-5: dv-tile 16->32 (S[4][4][2]=32 regs,
// oa[4][2], sS/vS reads widen b32->b64): same per-thread LDS instruction
// count, HALF the threads => total LDS traffic halves, FLOPs unchanged.
// Skeleton (phases/barriers/fences) kept identical to the proven v4.
// dvt siblings are 64 apart in linear block id (64%8==0 -> same XCD L2).

// ---- pass A: group-local state sums --------------------------------------
__global__ __launch_bounds__(256) void retn_gstate(const float* __restrict__ k,
                                                   const float* __restrict__ v,
                                                   float* __restrict__ Tbuf) {
  // grid (16, 3, 32): x = b*4+h, y = g (0..2), z: dkt = z>>3, dvt = z&7
  const int bh = blockIdx.x; const int b = bh >> 2, h = bh & 3;
  const int g = blockIdx.y;
  const int dkt = blockIdx.z >> 3, dvt = blockIdx.z & 7;
  const int t = threadIdx.x;
  __shared__ float gpow[65];
  __shared__ __align__(16) float kS[64][68];
  __shared__ __align__(16) float vS[64][68];
  if (t <= 64) gpow[t] = powf(1.0f - exp2f(-5.0f - (float)h), (float)t);
  __syncthreads();
  const float gC = gpow[64];
  const size_t baseK = (size_t)(b * T_SEQ + g * 512) * KDIM + h * HK + dkt * 64;
  const size_t baseV = (size_t)(b * T_SEQ + g * 512) * VDIM + h * HV + dvt * 64;
  const int dk0 = (t & 15) * 4, c0 = (t >> 4) * 4;
  float S[4][4] = {};
  for (int c = 0; c < 8; ++c) {
    const int t0 = c * 64;
    __syncthreads();
    __builtin_amdgcn_sched_barrier(0);
#pragma unroll
    for (int r = 0; r < 4; ++r) {
      int idx = t + 256 * r; int row = idx >> 4, c4 = (idx & 15) * 4;
      float4 kv = *(const float4*)&k[baseK + (size_t)(t0 + row) * KDIM + c4];
      float kd = gpow[63 - row];
      kv.x *= kd; kv.y *= kd; kv.z *= kd; kv.w *= kd;
      *(float4*)&kS[row][c4] = kv;
      *(float4*)&vS[row][c4] = *(const float4*)&v[baseV + (size_t)(t0 + row) * VDIM + c4];
    }
    __syncthreads();
    __builtin_amdgcn_sched_barrier(0);
#pragma unroll
    for (int ii = 0; ii < 4; ++ii)
#pragma unroll
      for (int jj = 0; jj < 4; ++jj) S[ii][jj] *= gC;
    for (int j = 0; j < 64; ++j) {
      float4 kv = *(const float4*)&kS[j][dk0];
      float4 vv = *(const float4*)&vS[j][c0];
      S[0][0] = fmaf(kv.x, vv.x, S[0][0]); S[0][1] = fmaf(kv.x, vv.y, S[0][1]);
      S[0][2] = fmaf(kv.x, vv.z, S[0][2]); S[0][3] = fmaf(kv.x, vv.w, S[0][3]);
      S[1][0] = fmaf(kv.y, vv.x, S[1][0]); S[1][1] = fmaf(kv.y, vv.y, S[1][1]);
      S[1][2] = fmaf(kv.y, vv.z, S[1][2]); S[1][3] = fmaf(kv.y, vv.w, S[1][3]);
      S[2][0] = fmaf(kv.z, vv.x, S[2][0]); S[2][1] = fmaf(kv.z, vv.y, S[2][1]);
      S[2][2] = fmaf(kv.z, vv.z, S[2][2]); S[2][3] = fmaf(kv.z, vv.w, S[2][3]);
      S[3][0] = fmaf(kv.w, vv.x, S[3][0]); S[3][1] = fmaf(kv.w, vv.y, S[3][1]);
      S[3][2] = fmaf(kv.w, vv.z, S[3][2]); S[3][3] = fmaf(kv.w, vv.w, S[3][3]);
    }
  }
  const size_t tb = (((size_t)g * 16 + bh) * 256 + dkt * 64 + dk0) * 512 + (size_t)dvt * 64 + c0;
#pragma unroll
  for (int ii = 0; ii < 4; ++ii)
    *(float4*)&Tbuf[tb + (size_t)ii * 512] = make_float4(S[ii][0], S[ii][1], S[ii][2], S[ii][3]);
}

// ---- pass B: exclusive scan over the 4 groups (in-place) ------------------
// slot g holds T_g on entry; on exit slot g holds S_in[g+1]:
//   S_in[1]=T0 (slot0 unchanged), S_in[2]=gG*T0+T1, S_in[3]=gG*S_in[2]+T2.
__global__ __launch_bounds__(256) void retn_scan(float* __restrict__ Tbuf) {
  int i = blockIdx.x * 256 + threadIdx.x;   // float4 index within one g-slab
  int h = (i >> 15) & 3;                    // (i*4)>>17 & 3
  float gamma = 1.0f - exp2f(-5.0f - (float)h);
  float gG = powf(gamma, 512.0f);           // gC^8 = gamma^(64*8)
  float4* T = (float4*)Tbuf;
  const int slab = 524288;                  // 16*256*512/4
  float4 t0 = T[i], t1 = T[i + slab], t2 = T[i + 2 * slab];
  float4 s2, s3;
  s2.x = fmaf(gG, t0.x, t1.x); s2.y = fmaf(gG, t0.y, t1.y);
  s2.z = fmaf(gG, t0.z, t1.z); s2.w = fmaf(gG, t0.w, t1.w);
  s3.x = fmaf(gG, s2.x, t2.x); s3.y = fmaf(gG, s2.y, t2.y);
  s3.z = fmaf(gG, s2.z, t2.z); s3.w = fmaf(gG, s2.w, t2.w);
  T[i + slab] = s2; T[i + 2 * slab] = s3;
}

// ---- pass C: inter-chunk output, full-dk state in regs, no atomics --------
__global__ __launch_bounds__(256) void retn_inter2(const float* __restrict__ q,
                                                   const float* __restrict__ k,
                                                   const float* __restrict__ v,
                                                   float* __restrict__ o,
                                                   const float* __restrict__ Sbuf) {
  // grid (16, 4, 16): x = b*4+h, y = g, z = dvt (32-wide dv tiles)
  const int bh = blockIdx.x; const int b = bh >> 2, h = bh & 3;
  const int g = blockIdx.y;
  const int dvt = blockIdx.z;
  const int t = threadIdx.x;
  __shared__ float gpow[65];
  __shared__ __align__(16) float qS[64][68];  // q~ block (64x64)
  __shared__ __align__(16) float kS[64][68];  // k~ block (64x64)
  __shared__ __align__(16) float sS[64][34];  // state-block publish (64x32)
  __shared__ __align__(16) float vS[64][36];  // v chunk (64x32)
  if (t <= 64) gpow[t] = powf(1.0f - exp2f(-5.0f - (float)h), (float)t);
  __syncthreads();
  const float gC = gpow[64];
  const int rq  = (t & 15) * 4;  // state rows within a dk-block (publish/j-loop)
  const int c0v = (t >> 4) * 2;  // state col pair (0,2,..,30)
  const int i0  = (t >> 4) * 4;  // o-tile rows
  const int v0c = (t & 15) * 2;  // o-tile col pair
  const size_t baseQK = (size_t)(b * T_SEQ + g * 512) * KDIM + h * HK;
  const size_t baseV  = (size_t)(b * T_SEQ + g * 512) * VDIM + h * HV + (size_t)dvt * 32;

  // S: 32 regs/thread, compile-time indices only, never address-taken.
  float S[4][4][2];              // [dk-block][row][colpair]; cols c0v,c0v+1
  if (g > 0) {
    const size_t sb = (((size_t)(g - 1) * 16 + bh) * 256) * 512 + (size_t)dvt * 32 + c0v;
#pragma unroll
    for (int b4 = 0; b4 < 4; ++b4)
#pragma unroll
      for (int i = 0; i < 4; ++i) {
        float2 tmp = *(const float2*)&Sbuf[sb + (size_t)(b4 * 64 + rq + i) * 512];
        S[b4][i][0] = tmp.x; S[b4][i][1] = tmp.y;
      }
  } else {
#pragma unroll
    for (int b4 = 0; b4 < 4; ++b4)
#pragma unroll
      for (int i = 0; i < 4; ++i) { S[b4][i][0] = 0.f; S[b4][i][1] = 0.f; }
  }

  for (int c = 0; c < 8; ++c) {
    const int t0 = c * 64;
    __syncthreads();                       // prev chunk's vS readers done
    __builtin_amdgcn_sched_barrier(0);
#pragma unroll
    for (int r = 0; r < 2; ++r) {          // stage v chunk 64x32
      int idx = t + 256 * r; int row = idx >> 3, c4 = (idx & 7) * 4;
      *(float4*)&vS[row][c4] = *(const float4*)&v[baseV + (size_t)(t0 + row) * VDIM + c4];
    }
    float oa00 = 0.f, oa01 = 0.f, oa10 = 0.f, oa11 = 0.f;
    float oa20 = 0.f, oa21 = 0.f, oa30 = 0.f, oa31 = 0.f;
#pragma unroll
    for (int b4 = 0; b4 < 4; ++b4) {
      __syncthreads();                     // prev b4's qS/kS/sS readers done (covers vS write at b4=0)
      __builtin_amdgcn_sched_barrier(0);
      // publish this dk-block of S (OLD state) for the o-phase
#pragma unroll
      for (int i = 0; i < 4; ++i)
        *(float2*)&sS[rq + i][c0v] = make_float2(S[b4][i][0], S[b4][i][1]);
      // stage q~ block (64x64), scaled by cross_dec
#pragma unroll
      for (int r = 0; r < 4; ++r) {
        int idx = t + 256 * r; int row = idx >> 4, c4 = (idx & 15) * 4;
        float4 qv = *(const float4*)&q[baseQK + (size_t)(t0 + row) * KDIM + b4 * 64 + c4];
        float gp = gpow[row + 1];
        qv.x *= gp; qv.y *= gp; qv.z *= gp; qv.w *= gp;
        *(float4*)&qS[row][c4] = qv;
      }
      // stage k~ block (64x64), scaled by k_dec
#pragma unroll
      for (int r = 0; r < 4; ++r) {
        int idx = t + 256 * r; int row = idx >> 4, c4 = (idx & 15) * 4;
        float4 kv = *(const float4*)&k[baseQK + (size_t)(t0 + row) * KDIM + b4 * 64 + c4];
        float kd = gpow[63 - row];
        kv.x *= kd; kv.y *= kd; kv.z *= kd; kv.w *= kd;
        *(float4*)&kS[row][c4] = kv;
      }
      __syncthreads();
      __builtin_amdgcn_sched_barrier(0);
      // o-phase: oa += q~S(64x64) @ sS(64x32), this thread: 4 rows x 2 cols
      for (int d = 0; d < 64; d += 4) {
        float4 a0 = *(const float4*)&qS[i0 + 0][d];
        float4 a1 = *(const float4*)&qS[i0 + 1][d];
        float4 a2 = *(const float4*)&qS[i0 + 2][d];
        float4 a3 = *(const float4*)&qS[i0 + 3][d];
        float2 s0 = *(const float2*)&sS[d + 0][v0c];
        float2 s1 = *(const float2*)&sS[d + 1][v0c];
        float2 s2 = *(const float2*)&sS[d + 2][v0c];
        float2 s3 = *(const float2*)&sS[d + 3][v0c];
        oa00 = fmaf(a0.x, s0.x, oa00); oa00 = fmaf(a0.y, s1.x, oa00);
        oa00 = fmaf(a0.z, s2.x, oa00); oa00 = fmaf(a0.w, s3.x, oa00);
        oa01 = fmaf(a0.x, s0.y, oa01); oa01 = fmaf(a0.y, s1.y, oa01);
        oa01 = fmaf(a0.z, s2.y, oa01); oa01 = fmaf(a0.w, s3.y, oa01);
        oa10 = fmaf(a1.x, s0.x, oa10); oa10 = fmaf(a1.y, s1.x, oa10);
        oa10 = fmaf(a1.z, s2.x, oa10); oa10 = fmaf(a1.w, s3.x, oa10);
        oa11 = fmaf(a1.x, s0.y, oa11); oa11 = fmaf(a1.y, s1.y, oa11);
        oa11 = fmaf(a1.z, s2.y, oa11); oa11 = fmaf(a1.w, s3.y, oa11);
        oa20 = fmaf(a2.x, s0.x, oa20); oa20 = fmaf(a2.y, s1.x, oa20);
        oa20 = fmaf(a2.z, s2.x, oa20); oa20 = fmaf(a2.w, s3.x, oa20);
        oa21 = fmaf(a2.x, s0.y, oa21); oa21 = fmaf(a2.y, s1.y, oa21);
        oa21 = fmaf(a2.z, s2.y, oa21); oa21 = fmaf(a2.w, s3.y, oa21);
        oa30 = fmaf(a3.x, s0.x, oa30); oa30 = fmaf(a3.y, s1.x, oa30);
        oa30 = fmaf(a3.z, s2.x, oa30); oa30 = fmaf(a3.w, s3.x, oa30);
        oa31 = fmaf(a3.x, s0.y, oa31); oa31 = fmaf(a3.y, s1.y, oa31);
        oa31 = fmaf(a3.z, s2.y, oa31); oa31 = fmaf(a3.w, s3.y, oa31);
      }
      // update: S[b4] = gC*S[b4] + k~^T v (rows rq..rq+3, cols c0v..c0v+1)
      S[b4][0][0] *= gC; S[b4][0][1] *= gC;
      S[b4][1][0] *= gC; S[b4][1][1] *= gC;
      S[b4][2][0] *= gC; S[b4][2][1] *= gC;
      S[b4][3][0] *= gC; S[b4][3][1] *= gC;
      for (int j = 0; j < 64; ++j) {
        float4 kv = *(const float4*)&kS[j][rq];
        float2 vv = *(const float2*)&vS[j][c0v];
        S[b4][0][0] = fmaf(kv.x, vv.x, S[b4][0][0]); S[b4][0][1] = fmaf(kv.x, vv.y, S[b4][0][1]);
        S[b4][1][0] = fmaf(kv.y, vv.x, S[b4][1][0]); S[b4][1][1] = fmaf(kv.y, vv.y, S[b4][1][1]);
        S[b4][2][0] = fmaf(kv.z, vv.x, S[b4][2][0]); S[b4][2][1] = fmaf(kv.z, vv.y, S[b4][2][1]);
        S[b4][3][0] = fmaf(kv.w, vv.x, S[b4][3][0]); S[b4][3][1] = fmaf(kv.w, vv.y, S[b4][3][1]);
      }
    }
    // o += oa (adds exact 0.0 when g==0 && c==0 since S==0 -> no guard)
#pragma unroll
    for (int ii = 0; ii < 4; ++ii) {
      size_t addr = baseV + (size_t)(t0 + i0 + ii) * VDIM + v0c;
      float2 ov = *(const float2*)&o[addr];
      float a = (ii == 0) ? oa00 : (ii == 1) ? oa10 : (ii == 2) ? oa20 : oa30;
      float bqq = (ii == 0) ? oa01 : (ii == 1) ? oa11 : (ii == 2) ? oa21 : oa31;
      ov.x += a; ov.y += bqq;
      *(float2*)&o[addr] = ov;
    }
  }
}

// ---------------- RMS group-norm over HEAD_V + SiLU(g) gate (in-place) -------
__global__ __launch_bounds__(256) void norm_gate(float* __restrict__ o,
                                                 const float* __restrict__ g,
                                                 const float* __restrict__ gnw) {
  const int row = blockIdx.x;
  const size_t base = (size_t)row * 512;
  const int t = threadIdx.x;
  float x0 = o[base + t], x1 = o[base + t + 256];
  float ss = x0 * x0 + x1 * x1;
#pragma unroll
  for (int off = 32; off > 0; off >>= 1) ss += __shfl_down(ss, off, 64);
  __shared__ float wsum[4];
  if ((t & 63) == 0) wsum[t >> 6] = ss;
  __syncthreads();
  float tot = wsum[0] + wsum[1] + wsum[2] + wsum[3];
  float scale = rsqrtf(tot * (1.0f / 512.0f) + 1e-5f);
  float g0 = g[base + t], g1 = g[base + t + 256];
  o[base + t]       = x0 * scale * gnw[t]       * (g0 / (1.0f + expf(-g0)));
  o[base + t + 256] = x1 * scale * gnw[t + 256] * (g1 / (1.0f + expf(-g1)));
}

extern "C" void kernel_launch(void* const* d_in, const int* in_sizes, int n_in,
                              void* d_out, int out_size, void* d_ws, size_t ws_size,
                              hipStream_t stream) {
  const float* x   = (const float*)d_in[0];
  const float* Wq  = (const float*)d_in[1];
  const float* Wk  = (const float*)d_in[2];
  const float* Wv  = (const float*)d_in[3];
  const float* Wg  = (const float*)d_in[4];
  const float* Wo  = (const float*)d_in[5];
  const float* gnw = (const float*)d_in[6];
  float* out = (float*)d_out;

  // workspace = 256 MiB exactly:
  // [q 32][k 32][v 64][o 64][x-splits 32][W-splits 32]
  // o-splits (64) alias dead v; g (64) aliases dead q+k.
  // d_out (32 MiB) doubles as group-state scratch (24 MiB) until final GEMM.
  const size_t M8 = (size_t)8192;
  float* q  = (float*)d_ws;
  float* kk = q  + M8 * 1024;
  float* v  = kk + M8 * 1024;
  float* o  = v  + M8 * 2048;
  unsigned short* xh  = (unsigned short*)(o + M8 * 2048);
  unsigned short* xl  = xh  + M8 * 1024;
  unsigned short* wqh = xl  + M8 * 1024;
  unsigned short* wql = wqh + (size_t)1024 * 1024;
  unsigned short* wkh = wql + (size_t)1024 * 1024;
  unsigned short* wkl = wkh + (size_t)1024 * 1024;
  unsigned short* wvh = wkl + (size_t)1024 * 1024;
  unsigned short* wvl = wvh + (size_t)2048 * 1024;
  unsigned short* wgh = wvl + (size_t)2048 * 1024;
  unsigned short* wgl = wgh + (size_t)2048 * 1024;
  unsigned short* woh = wgl + (size_t)2048 * 1024;
  unsigned short* wol = woh + (size_t)2048 * 1024;
  unsigned short* oh  = (unsigned short*)v;
  unsigned short* ol  = oh + M8 * 2048;
  float* g = q;
  float* Tbuf = (float*)d_out;   // 24 MiB scratch, dead until final GEMM

  dim3 blk(256);
  cast_split<<<dim3(8192), blk, 0, stream>>>(x,  xh,  xl,  2097152);
  cast_split<<<dim3(1024), blk, 0, stream>>>(Wq, wqh, wql, 262144);
  cast_split<<<dim3(1024), blk, 0, stream>>>(Wk, wkh, wkl, 262144);
  cast_split<<<dim3(2048), blk, 0, stream>>>(Wv, wvh, wvl, 524288);
  cast_split<<<dim3(2048), blk, 0, stream>>>(Wg, wgh, wgl, 524288);
  cast_split<<<dim3(2048), blk, 0, stream>>>(Wo, woh, wol, 524288);

  gemm_bf16s<<<dim3(8, 64),  blk, 0, stream>>>(xh, xl, wqh, wql, q,  8192, 1024, 1024);
  gemm_bf16s<<<dim3(8, 64),  blk, 0, stream>>>(xh, xl, wkh, wkl, kk, 8192, 1024, 1024);
  gemm_bf16s<<<dim3(16, 64), blk, 0, stream>>>(xh, xl, wvh, wvl, v,  8192, 2048, 1024);
  rope_kernel<<<dim3(16384), blk, 0, stream>>>(q, kk);
  retn_gstate<<<dim3(16, 3, 32), blk, 0, stream>>>(kk, v, Tbuf);
  retn_scan<<<dim3(2048), blk, 0, stream>>>(Tbuf);
  retn_intra<<<dim3(32, 4, 4),  blk, 0, stream>>>(q, kk, v, o);
  retn_inter2<<<dim3(16, 4, 16), blk, 0, stream>>>(q, kk, v, o, Tbuf);
  gemm_bf16s<<<dim3(16, 64), blk, 0, stream>>>(xh, xl, wgh, wgl, g, 8192, 2048, 1024);
  norm_gate<<<dim3(32768), blk, 0, stream>>>(o, g, gnw);
  cast_split<<<dim3(16384), blk, 0, stream>>>(o, oh, ol, 4194304);
  gemm_bf16s<<<dim3(8, 64),  blk, 0, stream>>>(oh, ol, woh, wol, out, 8192, 1024, 2048);
}

// Round 6
// 1025.593 us; speedup vs baseline: 9.8156x; 1.1240x over previous
//
#include <hip/hip_runtime.h>
#include <cstdint>
#include <cstddef>

#define T_SEQ 2048
#define DM    1024
#define HK    256
#define HV    512
#define NH    4
#define KDIM  1024
#define VDIM  2048

typedef __attribute__((ext_vector_type(8))) short bf16x8;
typedef __attribute__((ext_vector_type(4))) float f32x4;
#define AS1 __attribute__((address_space(1)))
#define AS3 __attribute__((address_space(3)))

// ---------------- f32 -> (hi, lo) bf16 split (RNE), vectorized x4 ------------
static __device__ inline unsigned short f2bf(float f) {
  unsigned u = __float_as_uint(f);
  unsigned rnd = 0x7fffu + ((u >> 16) & 1u);
  return (unsigned short)((u + rnd) >> 16);
}
static __device__ inline float bf2f(unsigned short h) {
  unsigned u = ((unsigned)h) << 16;
  return __uint_as_float(u);
}

__global__ __launch_bounds__(256) void cast_split(const float* __restrict__ in,
                                                  unsigned short* __restrict__ hi,
                                                  unsigned short* __restrict__ lo,
                                                  int n4) {
  int i = blockIdx.x * 256 + threadIdx.x;
  if (i >= n4) return;
  float4 v = ((const float4*)in)[i];
  ushort4 h, l;
  h.x = f2bf(v.x); l.x = f2bf(v.x - bf2f(h.x));
  h.y = f2bf(v.y); l.y = f2bf(v.y - bf2f(h.y));
  h.z = f2bf(v.z); l.z = f2bf(v.z - bf2f(h.z));
  h.w = f2bf(v.w); l.w = f2bf(v.w - bf2f(h.w));
  ((ushort4*)hi)[i] = h;
  ((ushort4*)lo)[i] = l;
}

// -------- split-precision bf16 MFMA GEMM: C = A @ W^T, A=Ah+Al, W=Wh+Wl ------
// C ~= Ah*Wh + Ah*Wl + Al*Wh (f32 accumulate; lo*lo term ~2^-16 rel, dropped).
// 128x128 tile, BK=32, 4 waves 2x2, wave = 64x64 = 4x4 16x16x32 frags.
__global__ __launch_bounds__(256) void gemm_bf16s(const unsigned short* __restrict__ Ah,
                                                  const unsigned short* __restrict__ Al,
                                                  const unsigned short* __restrict__ Wh,
                                                  const unsigned short* __restrict__ Wl,
                                                  float* __restrict__ C,
                                                  int M, int N, int K) {
  __shared__ unsigned short AhS[128 * 32];
  __shared__ unsigned short AlS[128 * 32];
  __shared__ unsigned short WhS[128 * 32];
  __shared__ unsigned short WlS[128 * 32];
  const int t = threadIdx.x;
  const int l = t & 63;
  const int w = t >> 6;
  const int bm = blockIdx.y * 128;
  const int bn = blockIdx.x * 128;
  const int wm = (w >> 1) * 64;
  const int wn = (w & 1) * 64;

  f32x4 acc[4][4];
#pragma unroll
  for (int i = 0; i < 4; ++i)
#pragma unroll
    for (int j = 0; j < 4; ++j)
#pragma unroll
      for (int r = 0; r < 4; ++r) acc[i][j][r] = 0.f;

  const int srow = w * 32 + (l >> 2);
  const int scol = (l & 3) * 8;
  const size_t gOffA = (size_t)(bm + srow) * K + scol;
  const size_t gOffW = (size_t)(bn + srow) * K + scol;
  const size_t rowStep = (size_t)16 * K;
  unsigned short* lAh0 = &AhS[(w * 32) * 32];
  unsigned short* lAh1 = &AhS[(w * 32 + 16) * 32];
  unsigned short* lAl0 = &AlS[(w * 32) * 32];
  unsigned short* lAl1 = &AlS[(w * 32 + 16) * 32];
  unsigned short* lWh0 = &WhS[(w * 32) * 32];
  unsigned short* lWh1 = &WhS[(w * 32 + 16) * 32];
  unsigned short* lWl0 = &WlS[(w * 32) * 32];
  unsigned short* lWl1 = &WlS[(w * 32 + 16) * 32];

  for (int k0 = 0; k0 < K; k0 += 32) {
    __syncthreads();
    __builtin_amdgcn_global_load_lds((const AS1 void*)(Ah + gOffA + k0),           (AS3 void*)lAh0, 16, 0, 0);
    __builtin_amdgcn_global_load_lds((const AS1 void*)(Ah + gOffA + rowStep + k0), (AS3 void*)lAh1, 16, 0, 0);
    __builtin_amdgcn_global_load_lds((const AS1 void*)(Al + gOffA + k0),           (AS3 void*)lAl0, 16, 0, 0);
    __builtin_amdgcn_global_load_lds((const AS1 void*)(Al + gOffA + rowStep + k0), (AS3 void*)lAl1, 16, 0, 0);
    __builtin_amdgcn_global_load_lds((const AS1 void*)(Wh + gOffW + k0),           (AS3 void*)lWh0, 16, 0, 0);
    __builtin_amdgcn_global_load_lds((const AS1 void*)(Wh + gOffW + rowStep + k0), (AS3 void*)lWh1, 16, 0, 0);
    __builtin_amdgcn_global_load_lds((const AS1 void*)(Wl + gOffW + k0),           (AS3 void*)lWl0, 16, 0, 0);
    __builtin_amdgcn_global_load_lds((const AS1 void*)(Wl + gOffW + rowStep + k0), (AS3 void*)lWl1, 16, 0, 0);
    __syncthreads();

    bf16x8 ah[4], al[4], bh[4], bl[4];
#pragma unroll
    for (int i = 0; i < 4; ++i) {
      int aoff = (wm + i * 16 + (l & 15)) * 32 + (l >> 4) * 8;
      int boff = (wn + i * 16 + (l & 15)) * 32 + (l >> 4) * 8;
      ah[i] = *(const bf16x8*)&AhS[aoff];
      al[i] = *(const bf16x8*)&AlS[aoff];
      bh[i] = *(const bf16x8*)&WhS[boff];
      bl[i] = *(const bf16x8*)&WlS[boff];
    }
#pragma unroll
    for (int i = 0; i < 4; ++i)
#pragma unroll
      for (int j = 0; j < 4; ++j) {
        acc[i][j] = __builtin_amdgcn_mfma_f32_16x16x32_bf16(ah[i], bh[j], acc[i][j], 0, 0, 0);
        acc[i][j] = __builtin_amdgcn_mfma_f32_16x16x32_bf16(ah[i], bl[j], acc[i][j], 0, 0, 0);
        acc[i][j] = __builtin_amdgcn_mfma_f32_16x16x32_bf16(al[i], bh[j], acc[i][j], 0, 0, 0);
      }
  }

  const int cr = (l >> 4) * 4;
  const int cc = l & 15;
#pragma unroll
  for (int i = 0; i < 4; ++i)
#pragma unroll
    for (int j = 0; j < 4; ++j)
#pragma unroll
      for (int r = 0; r < 4; ++r)
        C[(size_t)(bm + wm + i * 16 + cr + r) * N + (bn + wn + j * 16 + cc)] = acc[i][j][r];
}

// ---------------- RoPE (in-place on q and k), q also scaled by HK^-0.5 -------
__global__ __launch_bounds__(256) void rope_kernel(float* __restrict__ q,
                                                   float* __restrict__ k) {
  int idx = blockIdx.x * 256 + threadIdx.x;     // over B*T*H*128 = 4,194,304
  int f  = idx & 127;
  int h  = (idx >> 7) & 3;
  int tt = (idx >> 9) & 2047;
  int b  = idx >> 20;
  size_t a0 = ((size_t)(b * T_SEQ + tt)) * KDIM + h * HK + f;
  size_t a1 = a0 + 128;
  float invf = powf(10000.0f, -(float)f * (1.0f / 128.0f));
  float ang  = (float)tt * invf;
  float s, c;
  sincosf(ang, &s, &c);
  float q1 = q[a0], q2 = q[a1];
  q[a0] = (q1 * c - q2 * s) * 0.0625f;
  q[a1] = (q2 * c + q1 * s) * 0.0625f;
  float k1 = k[a0], k2 = k[a1];
  k[a0] = k1 * c - k2 * s;
  k[a1] = k2 * c + k1 * s;
}

// ---------------- Retention pass 1: intra-chunk (fully parallel) -------------
// Round-5: float4-blocked LDS reads (pad 65->68 for 16B row alignment).
// Same accumulation order as the scalar version (d and j sequential) ->
// bitwise-identical results; ~4x fewer LDS instructions.
__global__ __launch_bounds__(256) void retn_intra(const float* __restrict__ q,
                                                  const float* __restrict__ k,
                                                  const float* __restrict__ v,
                                                  float* __restrict__ o) {
  const int n = blockIdx.x, h = blockIdx.y, b = blockIdx.z;
  const int t = threadIdx.x;
  const int t0 = n * 64;
  __shared__ float gpow[65];
  __shared__ __align__(16) float qS[64][68];
  __shared__ __align__(16) float kS[64][68];
  __shared__ __align__(16) float attnS[64][68];
  if (t <= 64) {
    float gamma = 1.0f - exp2f(-5.0f - (float)h);
    gpow[t] = powf(gamma, (float)t);
  }
  const size_t baseQK = (size_t)(b * T_SEQ + t0) * KDIM + h * HK;
  const size_t baseV  = (size_t)(b * T_SEQ + t0) * VDIM + h * HV;
  const int i0 = (t >> 4) * 4;
  const int j0 = (t & 15) * 4;
  float acc[4][4] = {};
  for (int s = 0; s < 4; ++s) {              // dk slices of 64
    __syncthreads();
    __builtin_amdgcn_sched_barrier(0);
#pragma unroll
    for (int r = 0; r < 4; ++r) {            // stage 64x64 as float4
      int idx = t + 256 * r;
      int row = idx >> 4, c4 = (idx & 15) * 4;
      *(float4*)&qS[row][c4] = *(const float4*)&q[baseQK + (size_t)row * KDIM + s * 64 + c4];
      *(float4*)&kS[row][c4] = *(const float4*)&k[baseQK + (size_t)row * KDIM + s * 64 + c4];
    }
    __syncthreads();
    __builtin_amdgcn_sched_barrier(0);
    for (int d = 0; d < 64; d += 4) {
      float4 a0 = *(const float4*)&qS[i0 + 0][d];
      float4 a1 = *(const float4*)&qS[i0 + 1][d];
      float4 a2 = *(const float4*)&qS[i0 + 2][d];
      float4 a3 = *(const float4*)&qS[i0 + 3][d];
      float4 b0 = *(const float4*)&kS[j0 + 0][d];
      float4 b1 = *(const float4*)&kS[j0 + 1][d];
      float4 b2 = *(const float4*)&kS[j0 + 2][d];
      float4 b3 = *(const float4*)&kS[j0 + 3][d];
      acc[0][0]=fmaf(a0.x,b0.x,acc[0][0]); acc[0][0]=fmaf(a0.y,b0.y,acc[0][0]); acc[0][0]=fmaf(a0.z,b0.z,acc[0][0]); acc[0][0]=fmaf(a0.w,b0.w,acc[0][0]);
      acc[0][1]=fmaf(a0.x,b1.x,acc[0][1]); acc[0][1]=fmaf(a0.y,b1.y,acc[0][1]); acc[0][1]=fmaf(a0.z,b1.z,acc[0][1]); acc[0][1]=fmaf(a0.w,b1.w,acc[0][1]);
      acc[0][2]=fmaf(a0.x,b2.x,acc[0][2]); acc[0][2]=fmaf(a0.y,b2.y,acc[0][2]); acc[0][2]=fmaf(a0.z,b2.z,acc[0][2]); acc[0][2]=fmaf(a0.w,b2.w,acc[0][2]);
      acc[0][3]=fmaf(a0.x,b3.x,acc[0][3]); acc[0][3]=fmaf(a0.y,b3.y,acc[0][3]); acc[0][3]=fmaf(a0.z,b3.z,acc[0][3]); acc[0][3]=fmaf(a0.w,b3.w,acc[0][3]);
      acc[1][0]=fmaf(a1.x,b0.x,acc[1][0]); acc[1][0]=fmaf(a1.y,b0.y,acc[1][0]); acc[1][0]=fmaf(a1.z,b0.z,acc[1][0]); acc[1][0]=fmaf(a1.w,b0.w,acc[1][0]);
      acc[1][1]=fmaf(a1.x,b1.x,acc[1][1]); acc[1][1]=fmaf(a1.y,b1.y,acc[1][1]); acc[1][1]=fmaf(a1.z,b1.z,acc[1][1]); acc[1][1]=fmaf(a1.w,b1.w,acc[1][1]);
      acc[1][2]=fmaf(a1.x,b2.x,acc[1][2]); acc[1][2]=fmaf(a1.y,b2.y,acc[1][2]); acc[1][2]=fmaf(a1.z,b2.z,acc[1][2]); acc[1][2]=fmaf(a1.w,b2.w,acc[1][2]);
      acc[1][3]=fmaf(a1.x,b3.x,acc[1][3]); acc[1][3]=fmaf(a1.y,b3.y,acc[1][3]); acc[1][3]=fmaf(a1.z,b3.z,acc[1][3]); acc[1][3]=fmaf(a1.w,b3.w,acc[1][3]);
      acc[2][0]=fmaf(a2.x,b0.x,acc[2][0]); acc[2][0]=fmaf(a2.y,b0.y,acc[2][0]); acc[2][0]=fmaf(a2.z,b0.z,acc[2][0]); acc[2][0]=fmaf(a2.w,b0.w,acc[2][0]);
      acc[2][1]=fmaf(a2.x,b1.x,acc[2][1]); acc[2][1]=fmaf(a2.y,b1.y,acc[2][1]); acc[2][1]=fmaf(a2.z,b1.z,acc[2][1]); acc[2][1]=fmaf(a2.w,b1.w,acc[2][1]);
      acc[2][2]=fmaf(a2.x,b2.x,acc[2][2]); acc[2][2]=fmaf(a2.y,b2.y,acc[2][2]); acc[2][2]=fmaf(a2.z,b2.z,acc[2][2]); acc[2][2]=fmaf(a2.w,b2.w,acc[2][2]);
      acc[2][3]=fmaf(a2.x,b3.x,acc[2][3]); acc[2][3]=fmaf(a2.y,b3.y,acc[2][3]); acc[2][3]=fmaf(a2.z,b3.z,acc[2][3]); acc[2][3]=fmaf(a2.w,b3.w,acc[2][3]);
      acc[3][0]=fmaf(a3.x,b0.x,acc[3][0]); acc[3][0]=fmaf(a3.y,b0.y,acc[3][0]); acc[3][0]=fmaf(a3.z,b0.z,acc[3][0]); acc[3][0]=fmaf(a3.w,b0.w,acc[3][0]);
      acc[3][1]=fmaf(a3.x,b1.x,acc[3][1]); acc[3][1]=fmaf(a3.y,b1.y,acc[3][1]); acc[3][1]=fmaf(a3.z,b1.z,acc[3][1]); acc[3][1]=fmaf(a3.w,b1.w,acc[3][1]);
      acc[3][2]=fmaf(a3.x,b2.x,acc[3][2]); acc[3][2]=fmaf(a3.y,b2.y,acc[3][2]); acc[3][2]=fmaf(a3.z,b2.z,acc[3][2]); acc[3][2]=fmaf(a3.w,b2.w,acc[3][2]);
      acc[3][3]=fmaf(a3.x,b3.x,acc[3][3]); acc[3][3]=fmaf(a3.y,b3.y,acc[3][3]); acc[3][3]=fmaf(a3.z,b3.z,acc[3][3]); acc[3][3]=fmaf(a3.w,b3.w,acc[3][3]);
    }
  }
  __syncthreads();
#pragma unroll
  for (int ii = 0; ii < 4; ++ii)
#pragma unroll
    for (int jj = 0; jj < 4; ++jj) {
      int i = i0 + ii, j = j0 + jj;
      attnS[i][j] = (i >= j) ? acc[ii][jj] * gpow[i - j] : 0.0f;
    }
  float (*vS)[68] = qS;
  for (int vb = 0; vb < 8; ++vb) {
    __syncthreads();
    __builtin_amdgcn_sched_barrier(0);
#pragma unroll
    for (int r = 0; r < 4; ++r) {
      int idx = t + 256 * r;
      int row = idx >> 4, c4 = (idx & 15) * 4;
      *(float4*)&vS[row][c4] = *(const float4*)&v[baseV + (size_t)row * VDIM + vb * 64 + c4];
    }
    __syncthreads();
    __builtin_amdgcn_sched_barrier(0);
    float oa[4][4] = {};
    for (int j = 0; j < 64; j += 4) {
      float4 p0 = *(const float4*)&attnS[i0 + 0][j];
      float4 p1 = *(const float4*)&attnS[i0 + 1][j];
      float4 p2 = *(const float4*)&attnS[i0 + 2][j];
      float4 p3 = *(const float4*)&attnS[i0 + 3][j];
      float4 v0 = *(const float4*)&vS[j + 0][j0];
      float4 v1 = *(const float4*)&vS[j + 1][j0];
      float4 v2 = *(const float4*)&vS[j + 2][j0];
      float4 v3 = *(const float4*)&vS[j + 3][j0];
      oa[0][0]=fmaf(p0.x,v0.x,oa[0][0]); oa[0][0]=fmaf(p0.y,v1.x,oa[0][0]); oa[0][0]=fmaf(p0.z,v2.x,oa[0][0]); oa[0][0]=fmaf(p0.w,v3.x,oa[0][0]);
      oa[0][1]=fmaf(p0.x,v0.y,oa[0][1]); oa[0][1]=fmaf(p0.y,v1.y,oa[0][1]); oa[0][1]=fmaf(p0.z,v2.y,oa[0][1]); oa[0][1]=fmaf(p0.w,v3.y,oa[0][1]);
      oa[0][2]=fmaf(p0.x,v0.z,oa[0][2]); oa[0][2]=fmaf(p0.y,v1.z,oa[0][2]); oa[0][2]=fmaf(p0.z,v2.z,oa[0][2]); oa[0][2]=fmaf(p0.w,v3.z,oa[0][2]);
      oa[0][3]=fmaf(p0.x,v0.w,oa[0][3]); oa[0][3]=fmaf(p0.y,v1.w,oa[0][3]); oa[0][3]=fmaf(p0.z,v2.w,oa[0][3]); oa[0][3]=fmaf(p0.w,v3.w,oa[0][3]);
      oa[1][0]=fmaf(p1.x,v0.x,oa[1][0]); oa[1][0]=fmaf(p1.y,v1.x,oa[1][0]); oa[1][0]=fmaf(p1.z,v2.x,oa[1][0]); oa[1][0]=fmaf(p1.w,v3.x,oa[1][0]);
      oa[1][1]=fmaf(p1.x,v0.y,oa[1][1]); oa[1][1]=fmaf(p1.y,v1.y,oa[1][1]); oa[1][1]=fmaf(p1.z,v2.y,oa[1][1]); oa[1][1]=fmaf(p1.w,v3.y,oa[1][1]);
      oa[1][2]=fmaf(p1.x,v0.z,oa[1][2]); oa[1][2]=fmaf(p1.y,v1.z,oa[1][2]); oa[1][2]=fmaf(p1.z,v2.z,oa[1][2]); oa[1][2]=fmaf(p1.w,v3.z,oa[1][2]);
      oa[1][3]=fmaf(p1.x,v0.w,oa[1][3]); oa[1][3]=fmaf(p1.y,v1.w,oa[1][3]); oa[1][3]=fmaf(p1.z,v2.w,oa[1][3]); oa[1][3]=fmaf(p1.w,v3.w,oa[1][3]);
      oa[2][0]=fmaf(p2.x,v0.x,oa[2][0]); oa[2][0]=fmaf(p2.y,v1.x,oa[2][0]); oa[2][0]=fmaf(p2.z,v2.x,oa[2][0]); oa[2][0]=fmaf(p2.w,v3.x,oa[2][0]);
      oa[2][1]=fmaf(p2.x,v0.y,oa[2][1]); oa[2][1]=fmaf(p2.y,v1.y,oa[2][1]); oa[2][1]=fmaf(p2.z,v2.y,oa[2][1]); oa[2][1]=fmaf(p2.w,v3.y,oa[2][1]);
      oa[2][2]=fmaf(p2.x,v0.z,oa[2][2]); oa[2][2]=fmaf(p2.y,v1.z,oa[2][2]); oa[2][2]=fmaf(p2.z,v2.z,oa[2][2]); oa[2][2]=fmaf(p2.w,v3.z,oa[2][2]);
      oa[2][3]=fmaf(p2.x,v0.w,oa[2][3]); oa[2][3]=fmaf(p2.y,v1.w,oa[2][3]); oa[2][3]=fmaf(p2.z,v2.w,oa[2][3]); oa[2][3]=fmaf(p2.w,v3.w,oa[2][3]);
      oa[3][0]=fmaf(p3.x,v0.x,oa[3][0]); oa[3][0]=fmaf(p3.y,v1.x,oa[3][0]); oa[3][0]=fmaf(p3.z,v2.x,oa[3][0]); oa[3][0]=fmaf(p3.w,v3.x,oa[3][0]);
      oa[3][1]=fmaf(p3.x,v0.y,oa[3][1]); oa[3][1]=fmaf(p3.y,v1.y,oa[3][1]); oa[3][1]=fmaf(p3.z,v2.y,oa[3][1]); oa[3][1]=fmaf(p3.w,v3.y,oa[3][1]);
      oa[3][2]=fmaf(p3.x,v0.z,oa[3][2]); oa[3][2]=fmaf(p3.y,v1.z,oa[3][2]); oa[3][2]=fmaf(p3.z,v2.z,oa[3][2]); oa[3][2]=fmaf(p3.w,v3.z,oa[3][2]);
      oa[3][3]=fmaf(p3.x,v0.w,oa[3][3]); oa[3][3]=fmaf(p3.y,v1.w,oa[3][3]); oa[3][3]=fmaf(p3.z,v2.w,oa[3][3]); oa[3][3]=fmaf(p3.w,v3.w,oa[3][3]);
    }
#pragma unroll
    for (int ii = 0; ii < 4; ++ii)
      *(float4*)&o[baseV + (size_t)(i0 + ii) * VDIM + vb * 64 + j0] =
          make_float4(oa[ii][0], oa[ii][1], oa[ii][2], oa[ii][3]);
  }
}

// =================== Retention inter-chunk: two-level scan ===================
//   A) retn_gstate: per (b,h,group of 8 chunks) local state sums T_g (g=0..2).
//   B) retn_scan: elementwise exclusive scan over groups: T_g -> S_in[g+1].
//   C) retn_inter2: per (b,h,g,dv-tile64) WG carries full dk=256 state in regs
//      (64/thread), seeded from S_in[g]; 8-chunk serial scan; o updated with
//      plain load+add+store (sole writer, NO atomics).
// ROUND-5 POST-MORTEM: v5 (dv32) hit 457us, VGPR 116, no spill -- kernel is
// LDS-INSTRUCTION-ISSUE-bound: 33.5M wave LDS reads x ~10-12cyc matches the
// measured time; bank conflicts are negligible (0.2cyc/instr). ROUND-6:
// dv-tile 32->64 (round-2 geometry) but WITH the proven v4/v5 anti-spill
// skeleton (one staging block per phase consumed immediately, sched_barrier(0)
// after every __syncthreads, compile-time-indexed S). Per-thread S[4][4][4]=64
// regs + oa[4][4]; ALL LDS reads b128 at 8 FMA/instr (2x v5); same per-thread
// instr count, HALF the waves => LDS issue ~halves. LDS 70KB -> 2 WG/CU =
// exactly the 512-WG grid. Per-element FP order identical to v5.
// dvt siblings are 64 apart in linear block id (64%8==0 -> same XCD L2).

// ---- pass A: group-local state sums --------------------------------------
__global__ __launch_bounds__(256) void retn_gstate(const float* __restrict__ k,
                                                   const float* __restrict__ v,
                                                   float* __restrict__ Tbuf) {
  // grid (16, 3, 32): x = b*4+h, y = g (0..2), z: dkt = z>>3, dvt = z&7
  const int bh = blockIdx.x; const int b = bh >> 2, h = bh & 3;
  const int g = blockIdx.y;
  const int dkt = blockIdx.z >> 3, dvt = blockIdx.z & 7;
  const int t = threadIdx.x;
  __shared__ float gpow[65];
  __shared__ __align__(16) float kS[64][68];
  __shared__ __align__(16) float vS[64][68];
  if (t <= 64) gpow[t] = powf(1.0f - exp2f(-5.0f - (float)h), (float)t);
  __syncthreads();
  const float gC = gpow[64];
  const size_t baseK = (size_t)(b * T_SEQ + g * 512) * KDIM + h * HK + dkt * 64;
  const size_t baseV = (size_t)(b * T_SEQ + g * 512) * VDIM + h * HV + dvt * 64;
  const int dk0 = (t & 15) * 4, c0 = (t >> 4) * 4;
  float S[4][4] = {};
  for (int c = 0; c < 8; ++c) {
    const int t0 = c * 64;
    __syncthreads();
    __builtin_amdgcn_sched_barrier(0);
#pragma unroll
    for (int r = 0; r < 4; ++r) {
      int idx = t + 256 * r; int row = idx >> 4, c4 = (idx & 15) * 4;
      float4 kv = *(const float4*)&k[baseK + (size_t)(t0 + row) * KDIM + c4];
      float kd = gpow[63 - row];
      kv.x *= kd; kv.y *= kd; kv.z *= kd; kv.w *= kd;
      *(float4*)&kS[row][c4] = kv;
      *(float4*)&vS[row][c4] = *(const float4*)&v[baseV + (size_t)(t0 + row) * VDIM + c4];
    }
    __syncthreads();
    __builtin_amdgcn_sched_barrier(0);
#pragma unroll
    for (int ii = 0; ii < 4; ++ii)
#pragma unroll
      for (int jj = 0; jj < 4; ++jj) S[ii][jj] *= gC;
    for (int j = 0; j < 64; ++j) {
      float4 kv = *(const float4*)&kS[j][dk0];
      float4 vv = *(const float4*)&vS[j][c0];
      S[0][0] = fmaf(kv.x, vv.x, S[0][0]); S[0][1] = fmaf(kv.x, vv.y, S[0][1]);
      S[0][2] = fmaf(kv.x, vv.z, S[0][2]); S[0][3] = fmaf(kv.x, vv.w, S[0][3]);
      S[1][0] = fmaf(kv.y, vv.x, S[1][0]); S[1][1] = fmaf(kv.y, vv.y, S[1][1]);
      S[1][2] = fmaf(kv.y, vv.z, S[1][2]); S[1][3] = fmaf(kv.y, vv.w, S[1][3]);
      S[2][0] = fmaf(kv.z, vv.x, S[2][0]); S[2][1] = fmaf(kv.z, vv.y, S[2][1]);
      S[2][2] = fmaf(kv.z, vv.z, S[2][2]); S[2][3] = fmaf(kv.z, vv.w, S[2][3]);
      S[3][0] = fmaf(kv.w, vv.x, S[3][0]); S[3][1] = fmaf(kv.w, vv.y, S[3][1]);
      S[3][2] = fmaf(kv.w, vv.z, S[3][2]); S[3][3] = fmaf(kv.w, vv.w, S[3][3]);
    }
  }
  const size_t tb = (((size_t)g * 16 + bh) * 256 + dkt * 64 + dk0) * 512 + (size_t)dvt * 64 + c0;
#pragma unroll
  for (int ii = 0; ii < 4; ++ii)
    *(float4*)&Tbuf[tb + (size_t)ii * 512] = make_float4(S[ii][0], S[ii][1], S[ii][2], S[ii][3]);
}

// ---- pass B: exclusive scan over the 4 groups (in-place) ------------------
// slot g holds T_g on entry; on exit slot g holds S_in[g+1]:
//   S_in[1]=T0 (slot0 unchanged), S_in[2]=gG*T0+T1, S_in[3]=gG*S_in[2]+T2.
__global__ __launch_bounds__(256) void retn_scan(float* __restrict__ Tbuf) {
  int i = blockIdx.x * 256 + threadIdx.x;   // float4 index within one g-slab
  int h = (i >> 15) & 3;                    // (i*4)>>17 & 3
  float gamma = 1.0f - exp2f(-5.0f - (float)h);
  float gG = powf(gamma, 512.0f);           // gC^8 = gamma^(64*8)
  float4* T = (float4*)Tbuf;
  const int slab = 524288;                  // 16*256*512/4
  float4 t0 = T[i], t1 = T[i + slab], t2 = T[i + 2 * slab];
  float4 s2, s3;
  s2.x = fmaf(gG, t0.x, t1.x); s2.y = fmaf(gG, t0.y, t1.y);
  s2.z = fmaf(gG, t0.z, t1.z); s2.w = fmaf(gG, t0.w, t1.w);
  s3.x = fmaf(gG, s2.x, t2.x); s3.y = fmaf(gG, s2.y, t2.y);
  s3.z = fmaf(gG, s2.z, t2.z); s3.w = fmaf(gG, s2.w, t2.w);
  T[i + slab] = s2; T[i + 2 * slab] = s3;
}

// ---- pass C: inter-chunk output, full-dk state in regs, no atomics --------
__global__ __launch_bounds__(256) void retn_inter2(const float* __restrict__ q,
                                                   const float* __restrict__ k,
                                                   const float* __restrict__ v,
                                                   float* __restrict__ o,
                                                   const float* __restrict__ Sbuf) {
  // grid (16, 4, 8): x = b*4+h, y = g, z = dvt (64-wide dv tiles)
  const int bh = blockIdx.x; const int b = bh >> 2, h = bh & 3;
  const int g = blockIdx.y;
  const int dvt = blockIdx.z;
  const int t = threadIdx.x;
  __shared__ float gpow[65];
  __shared__ __align__(16) float qS[64][68];  // q~ block (64x64)
  __shared__ __align__(16) float kS[64][68];  // k~ block (64x64)
  __shared__ __align__(16) float sS[64][68];  // state-block publish (64x64)
  __shared__ __align__(16) float vS[64][68];  // v chunk (64x64)
  if (t <= 64) gpow[t] = powf(1.0f - exp2f(-5.0f - (float)h), (float)t);
  __syncthreads();
  const float gC = gpow[64];
  const int rq = (t & 15) * 4;   // state rows within a dk-block (publish/j-loop)
  const int c0 = (t >> 4) * 4;   // state cols (0,4,..,60)
  const int i0 = (t >> 4) * 4;   // o-tile rows
  const int v0 = (t & 15) * 4;   // o-tile cols
  const size_t baseQK = (size_t)(b * T_SEQ + g * 512) * KDIM + h * HK;
  const size_t baseV  = (size_t)(b * T_SEQ + g * 512) * VDIM + h * HV + (size_t)dvt * 64;

  // S: 64 regs/thread, compile-time indices only, never address-taken.
  float S[4][4][4];              // [dk-block][row][col]; cols c0..c0+3
  if (g > 0) {
    const size_t sb = (((size_t)(g - 1) * 16 + bh) * 256) * 512 + (size_t)dvt * 64 + c0;
#pragma unroll
    for (int b4 = 0; b4 < 4; ++b4)
#pragma unroll
      for (int i = 0; i < 4; ++i) {
        float4 tmp = *(const float4*)&Sbuf[sb + (size_t)(b4 * 64 + rq + i) * 512];
        S[b4][i][0] = tmp.x; S[b4][i][1] = tmp.y; S[b4][i][2] = tmp.z; S[b4][i][3] = tmp.w;
      }
  } else {
#pragma unroll
    for (int b4 = 0; b4 < 4; ++b4)
#pragma unroll
      for (int i = 0; i < 4; ++i) {
        S[b4][i][0] = 0.f; S[b4][i][1] = 0.f; S[b4][i][2] = 0.f; S[b4][i][3] = 0.f;
      }
  }

  for (int c = 0; c < 8; ++c) {
    const int t0 = c * 64;
    __syncthreads();                       // prev chunk's vS readers done
    __builtin_amdgcn_sched_barrier(0);
#pragma unroll
    for (int r = 0; r < 4; ++r) {          // stage v chunk 64x64
      int idx = t + 256 * r; int row = idx >> 4, c4 = (idx & 15) * 4;
      *(float4*)&vS[row][c4] = *(const float4*)&v[baseV + (size_t)(t0 + row) * VDIM + c4];
    }
    float oa[4][4] = {};
#pragma unroll
    for (int b4 = 0; b4 < 4; ++b4) {
      __syncthreads();                     // prev b4's qS/kS/sS readers done (covers vS write at b4=0)
      __builtin_amdgcn_sched_barrier(0);
      // publish this dk-block of S (OLD state) for the o-phase
#pragma unroll
      for (int i = 0; i < 4; ++i)
        *(float4*)&sS[rq + i][c0] =
            make_float4(S[b4][i][0], S[b4][i][1], S[b4][i][2], S[b4][i][3]);
      // stage q~ block (64x64), scaled by cross_dec
#pragma unroll
      for (int r = 0; r < 4; ++r) {
        int idx = t + 256 * r; int row = idx >> 4, c4 = (idx & 15) * 4;
        float4 qv = *(const float4*)&q[baseQK + (size_t)(t0 + row) * KDIM + b4 * 64 + c4];
        float gp = gpow[row + 1];
        qv.x *= gp; qv.y *= gp; qv.z *= gp; qv.w *= gp;
        *(float4*)&qS[row][c4] = qv;
      }
      // stage k~ block (64x64), scaled by k_dec
#pragma unroll
      for (int r = 0; r < 4; ++r) {
        int idx = t + 256 * r; int row = idx >> 4, c4 = (idx & 15) * 4;
        float4 kv = *(const float4*)&k[baseQK + (size_t)(t0 + row) * KDIM + b4 * 64 + c4];
        float kd = gpow[63 - row];
        kv.x *= kd; kv.y *= kd; kv.z *= kd; kv.w *= kd;
        *(float4*)&kS[row][c4] = kv;
      }
      __syncthreads();
      __builtin_amdgcn_sched_barrier(0);
      // o-phase: oa += q~S(64x64) @ sS(64x64), this thread: 4 rows x 4 cols
      for (int d = 0; d < 64; d += 4) {
        float4 a0 = *(const float4*)&qS[i0 + 0][d];
        float4 a1 = *(const float4*)&qS[i0 + 1][d];
        float4 a2 = *(const float4*)&qS[i0 + 2][d];
        float4 a3 = *(const float4*)&qS[i0 + 3][d];
        float4 s0 = *(const float4*)&sS[d + 0][v0];
        float4 s1 = *(const float4*)&sS[d + 1][v0];
        float4 s2 = *(const float4*)&sS[d + 2][v0];
        float4 s3 = *(const float4*)&sS[d + 3][v0];
        oa[0][0]=fmaf(a0.x,s0.x,oa[0][0]); oa[0][0]=fmaf(a0.y,s1.x,oa[0][0]); oa[0][0]=fmaf(a0.z,s2.x,oa[0][0]); oa[0][0]=fmaf(a0.w,s3.x,oa[0][0]);
        oa[0][1]=fmaf(a0.x,s0.y,oa[0][1]); oa[0][1]=fmaf(a0.y,s1.y,oa[0][1]); oa[0][1]=fmaf(a0.z,s2.y,oa[0][1]); oa[0][1]=fmaf(a0.w,s3.y,oa[0][1]);
        oa[0][2]=fmaf(a0.x,s0.z,oa[0][2]); oa[0][2]=fmaf(a0.y,s1.z,oa[0][2]); oa[0][2]=fmaf(a0.z,s2.z,oa[0][2]); oa[0][2]=fmaf(a0.w,s3.z,oa[0][2]);
        oa[0][3]=fmaf(a0.x,s0.w,oa[0][3]); oa[0][3]=fmaf(a0.y,s1.w,oa[0][3]); oa[0][3]=fmaf(a0.z,s2.w,oa[0][3]); oa[0][3]=fmaf(a0.w,s3.w,oa[0][3]);
        oa[1][0]=fmaf(a1.x,s0.x,oa[1][0]); oa[1][0]=fmaf(a1.y,s1.x,oa[1][0]); oa[1][0]=fmaf(a1.z,s2.x,oa[1][0]); oa[1][0]=fmaf(a1.w,s3.x,oa[1][0]);
        oa[1][1]=fmaf(a1.x,s0.y,oa[1][1]); oa[1][1]=fmaf(a1.y,s1.y,oa[1][1]); oa[1][1]=fmaf(a1.z,s2.y,oa[1][1]); oa[1][1]=fmaf(a1.w,s3.y,oa[1][1]);
        oa[1][2]=fmaf(a1.x,s0.z,oa[1][2]); oa[1][2]=fmaf(a1.y,s1.z,oa[1][2]); oa[1][2]=fmaf(a1.z,s2.z,oa[1][2]); oa[1][2]=fmaf(a1.w,s3.z,oa[1][2]);
        oa[1][3]=fmaf(a1.x,s0.w,oa[1][3]); oa[1][3]=fmaf(a1.y,s1.w,oa[1][3]); oa[1][3]=fmaf(a1.z,s2.w,oa[1][3]); oa[1][3]=fmaf(a1.w,s3.w,oa[1][3]);
        oa[2][0]=fmaf(a2.x,s0.x,oa[2][0]); oa[2][0]=fmaf(a2.y,s1.x,oa[2][0]); oa[2][0]=fmaf(a2.z,s2.x,oa[2][0]); oa[2][0]=fmaf(a2.w,s3.x,oa[2][0]);
        oa[2][1]=fmaf(a2.x,s0.y,oa[2][1]); oa[2][1]=fmaf(a2.y,s1.y,oa[2][1]); oa[2][1]=fmaf(a2.z,s2.y,oa[2][1]); oa[2][1]=fmaf(a2.w,s3.y,oa[2][1]);
        oa[2][2]=fmaf(a2.x,s0.z,oa[2][2]); oa[2][2]=fmaf(a2.y,s1.z,oa[2][2]); oa[2][2]=fmaf(a2.z,s2.z,oa[2][2]); oa[2][2]=fmaf(a2.w,s3.z,oa[2][2]);
        oa[2][3]=fmaf(a2.x,s0.w,oa[2][3]); oa[2][3]=fmaf(a2.y,s1.w,oa[2][3]); oa[2][3]=fmaf(a2.z,s2.w,oa[2][3]); oa[2][3]=fmaf(a2.w,s3.w,oa[2][3]);
        oa[3][0]=fmaf(a3.x,s0.x,oa[3][0]); oa[3][0]=fmaf(a3.y,s1.x,oa[3][0]); oa[3][0]=fmaf(a3.z,s2.x,oa[3][0]); oa[3][0]=fmaf(a3.w,s3.x,oa[3][0]);
        oa[3][1]=fmaf(a3.x,s0.y,oa[3][1]); oa[3][1]=fmaf(a3.y,s1.y,oa[3][1]); oa[3][1]=fmaf(a3.z,s2.y,oa[3][1]); oa[3][1]=fmaf(a3.w,s3.y,oa[3][1]);
        oa[3][2]=fmaf(a3.x,s0.z,oa[3][2]); oa[3][2]=fmaf(a3.y,s1.z,oa[3][2]); oa[3][2]=fmaf(a3.z,s2.z,oa[3][2]); oa[3][2]=fmaf(a3.w,s3.z,oa[3][2]);
        oa[3][3]=fmaf(a3.x,s0.w,oa[3][3]); oa[3][3]=fmaf(a3.y,s1.w,oa[3][3]); oa[3][3]=fmaf(a3.z,s2.w,oa[3][3]); oa[3][3]=fmaf(a3.w,s3.w,oa[3][3]);
      }
      // update: S[b4] = gC*S[b4] + k~^T v (rows rq..rq+3, cols c0..c0+3)
#pragma unroll
      for (int ii = 0; ii < 4; ++ii) {
        S[b4][ii][0] *= gC; S[b4][ii][1] *= gC; S[b4][ii][2] *= gC; S[b4][ii][3] *= gC;
      }
      for (int j = 0; j < 64; ++j) {
        float4 kv = *(const float4*)&kS[j][rq];
        float4 vv = *(const float4*)&vS[j][c0];
        S[b4][0][0] = fmaf(kv.x, vv.x, S[b4][0][0]); S[b4][0][1] = fmaf(kv.x, vv.y, S[b4][0][1]);
        S[b4][0][2] = fmaf(kv.x, vv.z, S[b4][0][2]); S[b4][0][3] = fmaf(kv.x, vv.w, S[b4][0][3]);
        S[b4][1][0] = fmaf(kv.y, vv.x, S[b4][1][0]); S[b4][1][1] = fmaf(kv.y, vv.y, S[b4][1][1]);
        S[b4][1][2] = fmaf(kv.y, vv.z, S[b4][1][2]); S[b4][1][3] = fmaf(kv.y, vv.w, S[b4][1][3]);
        S[b4][2][0] = fmaf(kv.z, vv.x, S[b4][2][0]); S[b4][2][1] = fmaf(kv.z, vv.y, S[b4][2][1]);
        S[b4][2][2] = fmaf(kv.z, vv.z, S[b4][2][2]); S[b4][2][3] = fmaf(kv.z, vv.w, S[b4][2][3]);
        S[b4][3][0] = fmaf(kv.w, vv.x, S[b4][3][0]); S[b4][3][1] = fmaf(kv.w, vv.y, S[b4][3][1]);
        S[b4][3][2] = fmaf(kv.w, vv.z, S[b4][3][2]); S[b4][3][3] = fmaf(kv.w, vv.w, S[b4][3][3]);
      }
    }
    // o += oa (adds exact 0.0 when g==0 && c==0 since S==0 -> no guard)
#pragma unroll
    for (int ii = 0; ii < 4; ++ii) {
      size_t addr = baseV + (size_t)(t0 + i0 + ii) * VDIM + v0;
      float4 ov = *(const float4*)&o[addr];
      ov.x += oa[ii][0]; ov.y += oa[ii][1]; ov.z += oa[ii][2]; ov.w += oa[ii][3];
      *(float4*)&o[addr] = ov;
    }
  }
}

// ---------------- RMS group-norm over HEAD_V + SiLU(g) gate (in-place) -------
__global__ __launch_bounds__(256) void norm_gate(float* __restrict__ o,
                                                 const float* __restrict__ g,
                                                 const float* __restrict__ gnw) {
  const int row = blockIdx.x;
  const size_t base = (size_t)row * 512;
  const int t = threadIdx.x;
  float x0 = o[base + t], x1 = o[base + t + 256];
  float ss = x0 * x0 + x1 * x1;
#pragma unroll
  for (int off = 32; off > 0; off >>= 1) ss += __shfl_down(ss, off, 64);
  __shared__ float wsum[4];
  if ((t & 63) == 0) wsum[t >> 6] = ss;
  __syncthreads();
  float tot = wsum[0] + wsum[1] + wsum[2] + wsum[3];
  float scale = rsqrtf(tot * (1.0f / 512.0f) + 1e-5f);
  float g0 = g[base + t], g1 = g[base + t + 256];
  o[base + t]       = x0 * scale * gnw[t]       * (g0 / (1.0f + expf(-g0)));
  o[base + t + 256] = x1 * scale * gnw[t + 256] * (g1 / (1.0f + expf(-g1)));
}

extern "C" void kernel_launch(void* const* d_in, const int* in_sizes, int n_in,
                              void* d_out, int out_size, void* d_ws, size_t ws_size,
                              hipStream_t stream) {
  const float* x   = (const float*)d_in[0];
  const float* Wq  = (const float*)d_in[1];
  const float* Wk  = (const float*)d_in[2];
  const float* Wv  = (const float*)d_in[3];
  const float* Wg  = (const float*)d_in[4];
  const float* Wo  = (const float*)d_in[5];
  const float* gnw = (const float*)d_in[6];
  float* out = (float*)d_out;

  // workspace = 256 MiB exactly:
  // [q 32][k 32][v 64][o 64][x-splits 32][W-splits 32]
  // o-splits (64) alias dead v; g (64) aliases dead q+k.
  // d_out (32 MiB) doubles as group-state scratch (24 MiB) until final GEMM.
  const size_t M8 = (size_t)8192;
  float* q  = (float*)d_ws;
  float* kk = q  + M8 * 1024;
  float* v  = kk + M8 * 1024;
  float* o  = v  + M8 * 2048;
  unsigned short* xh  = (unsigned short*)(o + M8 * 2048);
  unsigned short* xl  = xh  + M8 * 1024;
  unsigned short* wqh = xl  + M8 * 1024;
  unsigned short* wql = wqh + (size_t)1024 * 1024;
  unsigned short* wkh = wql + (size_t)1024 * 1024;
  unsigned short* wkl = wkh + (size_t)1024 * 1024;
  unsigned short* wvh = wkl + (size_t)1024 * 1024;
  unsigned short* wvl = wvh + (size_t)2048 * 1024;
  unsigned short* wgh = wvl + (size_t)2048 * 1024;
  unsigned short* wgl = wgh + (size_t)2048 * 1024;
  unsigned short* woh = wgl + (size_t)2048 * 1024;
  unsigned short* wol = woh + (size_t)2048 * 1024;
  unsigned short* oh  = (unsigned short*)v;
  unsigned short* ol  = oh + M8 * 2048;
  float* g = q;
  float* Tbuf = (float*)d_out;   // 24 MiB scratch, dead until final GEMM

  dim3 blk(256);
  cast_split<<<dim3(8192), blk, 0, stream>>>(x,  xh,  xl,  2097152);
  cast_split<<<dim3(1024), blk, 0, stream>>>(Wq, wqh, wql, 262144);
  cast_split<<<dim3(1024), blk, 0, stream>>>(Wk, wkh, wkl, 262144);
  cast_split<<<dim3(2048), blk, 0, stream>>>(Wv, wvh, wvl, 524288);
  cast_split<<<dim3(2048), blk, 0, stream>>>(Wg, wgh, wgl, 524288);
  cast_split<<<dim3(2048), blk, 0, stream>>>(Wo, woh, wol, 524288);

  gemm_bf16s<<<dim3(8, 64),  blk, 0, stream>>>(xh, xl, wqh, wql, q,  8192, 1024, 1024);
  gemm_bf16s<<<dim3(8, 64),  blk, 0, stream>>>(xh, xl, wkh, wkl, kk, 8192, 1024, 1024);
  gemm_bf16s<<<dim3(16, 64), blk, 0, stream>>>(xh, xl, wvh, wvl, v,  8192, 2048, 1024);
  rope_kernel<<<dim3(16384), blk, 0, stream>>>(q, kk);
  retn_gstate<<<dim3(16, 3, 32), blk, 0, stream>>>(kk, v, Tbuf);
  retn_scan<<<dim3(2048), blk, 0, stream>>>(Tbuf);
  retn_intra<<<dim3(32, 4, 4),  blk, 0, stream>>>(q, kk, v, o);
  retn_inter2<<<dim3(16, 4, 8), blk, 0, stream>>>(q, kk, v, o, Tbuf);
  gemm_bf16s<<<dim3(16, 64), blk, 0, stream>>>(xh, xl, wgh, wgl, g, 8192, 2048, 1024);
  norm_gate<<<dim3(32768), blk, 0, stream>>>(o, g, gnw);
  cast_split<<<dim3(16384), blk, 0, stream>>>(o, oh, ol, 4194304);
  gemm_bf16s<<<dim3(8, 64),  blk, 0, stream>>>(oh, ol, woh, wol, out, 8192, 1024, 2048);
}

// Round 7
// 1011.111 us; speedup vs baseline: 9.9562x; 1.0143x over previous
//
#include <hip/hip_runtime.h>
#include <cstdint>
#include <cstddef>

#define T_SEQ 2048
#define DM    1024
#define HK    256
#define HV    512
#define NH    4
#define KDIM  1024
#define VDIM  2048

typedef __attribute__((ext_vector_type(8))) short bf16x8;
typedef __attribute__((ext_vector_type(4))) float f32x4;
#define AS1 __attribute__((address_space(1)))
#define AS3 __attribute__((address_space(3)))

// ---------------- f32 -> (hi, lo) bf16 split (RNE), vectorized x4 ------------
static __device__ inline unsigned short f2bf(float f) {
  unsigned u = __float_as_uint(f);
  unsigned rnd = 0x7fffu + ((u >> 16) & 1u);
  return (unsigned short)((u + rnd) >> 16);
}
static __device__ inline float bf2f(unsigned short h) {
  unsigned u = ((unsigned)h) << 16;
  return __uint_as_float(u);
}

__global__ __launch_bounds__(256) void cast_split(const float* __restrict__ in,
                                                  unsigned short* __restrict__ hi,
                                                  unsigned short* __restrict__ lo,
                                                  int n4) {
  int i = blockIdx.x * 256 + threadIdx.x;
  if (i >= n4) return;
  float4 v = ((const float4*)in)[i];
  ushort4 h, l;
  h.x = f2bf(v.x); l.x = f2bf(v.x - bf2f(h.x));
  h.y = f2bf(v.y); l.y = f2bf(v.y - bf2f(h.y));
  h.z = f2bf(v.z); l.z = f2bf(v.z - bf2f(h.z));
  h.w = f2bf(v.w); l.w = f2bf(v.w - bf2f(h.w));
  ((ushort4*)hi)[i] = h;
  ((ushort4*)lo)[i] = l;
}

// -------- split-precision bf16 MFMA GEMM: C = A @ W^T, A=Ah+Al, W=Wh+Wl ------
// C ~= Ah*Wh + Ah*Wl + Al*Wh (f32 accumulate; lo*lo term ~2^-16 rel, dropped).
// 128x128 tile, BK=32, 4 waves 2x2, wave = 64x64 = 4x4 16x16x32 frags.
__global__ __launch_bounds__(256) void gemm_bf16s(const unsigned short* __restrict__ Ah,
                                                  const unsigned short* __restrict__ Al,
                                                  const unsigned short* __restrict__ Wh,
                                                  const unsigned short* __restrict__ Wl,
                                                  float* __restrict__ C,
                                                  int M, int N, int K) {
  __shared__ unsigned short AhS[128 * 32];
  __shared__ unsigned short AlS[128 * 32];
  __shared__ unsigned short WhS[128 * 32];
  __shared__ unsigned short WlS[128 * 32];
  const int t = threadIdx.x;
  const int l = t & 63;
  const int w = t >> 6;
  const int bm = blockIdx.y * 128;
  const int bn = blockIdx.x * 128;
  const int wm = (w >> 1) * 64;
  const int wn = (w & 1) * 64;

  f32x4 acc[4][4];
#pragma unroll
  for (int i = 0; i < 4; ++i)
#pragma unroll
    for (int j = 0; j < 4; ++j)
#pragma unroll
      for (int r = 0; r < 4; ++r) acc[i][j][r] = 0.f;

  const int srow = w * 32 + (l >> 2);
  const int scol = (l & 3) * 8;
  const size_t gOffA = (size_t)(bm + srow) * K + scol;
  const size_t gOffW = (size_t)(bn + srow) * K + scol;
  const size_t rowStep = (size_t)16 * K;
  unsigned short* lAh0 = &AhS[(w * 32) * 32];
  unsigned short* lAh1 = &AhS[(w * 32 + 16) * 32];
  unsigned short* lAl0 = &AlS[(w * 32) * 32];
  unsigned short* lAl1 = &AlS[(w * 32 + 16) * 32];
  unsigned short* lWh0 = &WhS[(w * 32) * 32];
  unsigned short* lWh1 = &WhS[(w * 32 + 16) * 32];
  unsigned short* lWl0 = &WlS[(w * 32) * 32];
  unsigned short* lWl1 = &WlS[(w * 32 + 16) * 32];

  for (int k0 = 0; k0 < K; k0 += 32) {
    __syncthreads();
    __builtin_amdgcn_global_load_lds((const AS1 void*)(Ah + gOffA + k0),           (AS3 void*)lAh0, 16, 0, 0);
    __builtin_amdgcn_global_load_lds((const AS1 void*)(Ah + gOffA + rowStep + k0), (AS3 void*)lAh1, 16, 0, 0);
    __builtin_amdgcn_global_load_lds((const AS1 void*)(Al + gOffA + k0),           (AS3 void*)lAl0, 16, 0, 0);
    __builtin_amdgcn_global_load_lds((const AS1 void*)(Al + gOffA + rowStep + k0), (AS3 void*)lAl1, 16, 0, 0);
    __builtin_amdgcn_global_load_lds((const AS1 void*)(Wh + gOffW + k0),           (AS3 void*)lWh0, 16, 0, 0);
    __builtin_amdgcn_global_load_lds((const AS1 void*)(Wh + gOffW + rowStep + k0), (AS3 void*)lWh1, 16, 0, 0);
    __builtin_amdgcn_global_load_lds((const AS1 void*)(Wl + gOffW + k0),           (AS3 void*)lWl0, 16, 0, 0);
    __builtin_amdgcn_global_load_lds((const AS1 void*)(Wl + gOffW + rowStep + k0), (AS3 void*)lWl1, 16, 0, 0);
    __syncthreads();

    bf16x8 ah[4], al[4], bh[4], bl[4];
#pragma unroll
    for (int i = 0; i < 4; ++i) {
      int aoff = (wm + i * 16 + (l & 15)) * 32 + (l >> 4) * 8;
      int boff = (wn + i * 16 + (l & 15)) * 32 + (l >> 4) * 8;
      ah[i] = *(const bf16x8*)&AhS[aoff];
      al[i] = *(const bf16x8*)&AlS[aoff];
      bh[i] = *(const bf16x8*)&WhS[boff];
      bl[i] = *(const bf16x8*)&WlS[boff];
    }
#pragma unroll
    for (int i = 0; i < 4; ++i)
#pragma unroll
      for (int j = 0; j < 4; ++j) {
        acc[i][j] = __builtin_amdgcn_mfma_f32_16x16x32_bf16(ah[i], bh[j], acc[i][j], 0, 0, 0);
        acc[i][j] = __builtin_amdgcn_mfma_f32_16x16x32_bf16(ah[i], bl[j], acc[i][j], 0, 0, 0);
        acc[i][j] = __builtin_amdgcn_mfma_f32_16x16x32_bf16(al[i], bh[j], acc[i][j], 0, 0, 0);
      }
  }

  const int cr = (l >> 4) * 4;
  const int cc = l & 15;
#pragma unroll
  for (int i = 0; i < 4; ++i)
#pragma unroll
    for (int j = 0; j < 4; ++j)
#pragma unroll
      for (int r = 0; r < 4; ++r)
        C[(size_t)(bm + wm + i * 16 + cr + r) * N + (bn + wn + j * 16 + cc)] = acc[i][j][r];
}

// -------- merged q/k/v projection GEMM (one launch, routed by blockIdx.x) ----
// grid (32, 64): bx<8 -> q (N=1024), bx<16 -> k (N=1024), else -> v (N=2048).
// Routing is block-uniform (SGPR branch). Body identical to gemm_bf16s with
// M=8192, K=1024. Merging fills the machine (2048 WGs vs 3 underfilled
// launches) and reuses the A slab across all three projections.
__global__ __launch_bounds__(256) void gemm_qkv(const unsigned short* __restrict__ Ah,
                                                const unsigned short* __restrict__ Al,
                                                const unsigned short* __restrict__ wqh,
                                                const unsigned short* __restrict__ wql,
                                                const unsigned short* __restrict__ wkh,
                                                const unsigned short* __restrict__ wkl,
                                                const unsigned short* __restrict__ wvh,
                                                const unsigned short* __restrict__ wvl,
                                                float* __restrict__ q,
                                                float* __restrict__ kk,
                                                float* __restrict__ v) {
  const int K = 1024;
  const int bx = blockIdx.x;
  const unsigned short* Wh; const unsigned short* Wl; float* C; int N; int bn;
  if (bx < 8)       { Wh = wqh; Wl = wql; C = q;  N = 1024; bn = bx * 128; }
  else if (bx < 16) { Wh = wkh; Wl = wkl; C = kk; N = 1024; bn = (bx - 8) * 128; }
  else              { Wh = wvh; Wl = wvl; C = v;  N = 2048; bn = (bx - 16) * 128; }

  __shared__ unsigned short AhS[128 * 32];
  __shared__ unsigned short AlS[128 * 32];
  __shared__ unsigned short WhS[128 * 32];
  __shared__ unsigned short WlS[128 * 32];
  const int t = threadIdx.x;
  const int l = t & 63;
  const int w = t >> 6;
  const int bm = blockIdx.y * 128;
  const int wm = (w >> 1) * 64;
  const int wn = (w & 1) * 64;

  f32x4 acc[4][4];
#pragma unroll
  for (int i = 0; i < 4; ++i)
#pragma unroll
    for (int j = 0; j < 4; ++j)
#pragma unroll
      for (int r = 0; r < 4; ++r) acc[i][j][r] = 0.f;

  const int srow = w * 32 + (l >> 2);
  const int scol = (l & 3) * 8;
  const size_t gOffA = (size_t)(bm + srow) * K + scol;
  const size_t gOffW = (size_t)(bn + srow) * K + scol;
  const size_t rowStep = (size_t)16 * K;
  unsigned short* lAh0 = &AhS[(w * 32) * 32];
  unsigned short* lAh1 = &AhS[(w * 32 + 16) * 32];
  unsigned short* lAl0 = &AlS[(w * 32) * 32];
  unsigned short* lAl1 = &AlS[(w * 32 + 16) * 32];
  unsigned short* lWh0 = &WhS[(w * 32) * 32];
  unsigned short* lWh1 = &WhS[(w * 32 + 16) * 32];
  unsigned short* lWl0 = &WlS[(w * 32) * 32];
  unsigned short* lWl1 = &WlS[(w * 32 + 16) * 32];

  for (int k0 = 0; k0 < K; k0 += 32) {
    __syncthreads();
    __builtin_amdgcn_global_load_lds((const AS1 void*)(Ah + gOffA + k0),           (AS3 void*)lAh0, 16, 0, 0);
    __builtin_amdgcn_global_load_lds((const AS1 void*)(Ah + gOffA + rowStep + k0), (AS3 void*)lAh1, 16, 0, 0);
    __builtin_amdgcn_global_load_lds((const AS1 void*)(Al + gOffA + k0),           (AS3 void*)lAl0, 16, 0, 0);
    __builtin_amdgcn_global_load_lds((const AS1 void*)(Al + gOffA + rowStep + k0), (AS3 void*)lAl1, 16, 0, 0);
    __builtin_amdgcn_global_load_lds((const AS1 void*)(Wh + gOffW + k0),           (AS3 void*)lWh0, 16, 0, 0);
    __builtin_amdgcn_global_load_lds((const AS1 void*)(Wh + gOffW + rowStep + k0), (AS3 void*)lWh1, 16, 0, 0);
    __builtin_amdgcn_global_load_lds((const AS1 void*)(Wl + gOffW + k0),           (AS3 void*)lWl0, 16, 0, 0);
    __builtin_amdgcn_global_load_lds((const AS1 void*)(Wl + gOffW + rowStep + k0), (AS3 void*)lWl1, 16, 0, 0);
    __syncthreads();

    bf16x8 ah[4], al[4], bh[4], bl[4];
#pragma unroll
    for (int i = 0; i < 4; ++i) {
      int aoff = (wm + i * 16 + (l & 15)) * 32 + (l >> 4) * 8;
      int boff = (wn + i * 16 + (l & 15)) * 32 + (l >> 4) * 8;
      ah[i] = *(const bf16x8*)&AhS[aoff];
      al[i] = *(const bf16x8*)&AlS[aoff];
      bh[i] = *(const bf16x8*)&WhS[boff];
      bl[i] = *(const bf16x8*)&WlS[boff];
    }
#pragma unroll
    for (int i = 0; i < 4; ++i)
#pragma unroll
      for (int j = 0; j < 4; ++j) {
        acc[i][j] = __builtin_amdgcn_mfma_f32_16x16x32_bf16(ah[i], bh[j], acc[i][j], 0, 0, 0);
        acc[i][j] = __builtin_amdgcn_mfma_f32_16x16x32_bf16(ah[i], bl[j], acc[i][j], 0, 0, 0);
        acc[i][j] = __builtin_amdgcn_mfma_f32_16x16x32_bf16(al[i], bh[j], acc[i][j], 0, 0, 0);
      }
  }

  const int cr = (l >> 4) * 4;
  const int cc = l & 15;
#pragma unroll
  for (int i = 0; i < 4; ++i)
#pragma unroll
    for (int j = 0; j < 4; ++j)
#pragma unroll
      for (int r = 0; r < 4; ++r)
        C[(size_t)(bm + wm + i * 16 + cr + r) * N + (bn + wn + j * 16 + cc)] = acc[i][j][r];
}

// ---------------- RoPE (in-place on q and k), q also scaled by HK^-0.5 -------
__global__ __launch_bounds__(256) void rope_kernel(float* __restrict__ q,
                                                   float* __restrict__ k) {
  int idx = blockIdx.x * 256 + threadIdx.x;     // over B*T*H*128 = 4,194,304
  int f  = idx & 127;
  int h  = (idx >> 7) & 3;
  int tt = (idx >> 9) & 2047;
  int b  = idx >> 20;
  size_t a0 = ((size_t)(b * T_SEQ + tt)) * KDIM + h * HK + f;
  size_t a1 = a0 + 128;
  float invf = powf(10000.0f, -(float)f * (1.0f / 128.0f));
  float ang  = (float)tt * invf;
  float s, c;
  sincosf(ang, &s, &c);
  float q1 = q[a0], q2 = q[a1];
  q[a0] = (q1 * c - q2 * s) * 0.0625f;
  q[a1] = (q2 * c + q1 * s) * 0.0625f;
  float k1 = k[a0], k2 = k[a1];
  k[a0] = k1 * c - k2 * s;
  k[a1] = k2 * c + k1 * s;
}

// ---------------- Retention pass 1: intra-chunk (fully parallel) -------------
// Round-5: float4-blocked LDS reads (pad 65->68 for 16B row alignment).
__global__ __launch_bounds__(256) void retn_intra(const float* __restrict__ q,
                                                  const float* __restrict__ k,
                                                  const float* __restrict__ v,
                                                  float* __restrict__ o) {
  const int n = blockIdx.x, h = blockIdx.y, b = blockIdx.z;
  const int t = threadIdx.x;
  const int t0 = n * 64;
  __shared__ float gpow[65];
  __shared__ __align__(16) float qS[64][68];
  __shared__ __align__(16) float kS[64][68];
  __shared__ __align__(16) float attnS[64][68];
  if (t <= 64) {
    float gamma = 1.0f - exp2f(-5.0f - (float)h);
    gpow[t] = powf(gamma, (float)t);
  }
  const size_t baseQK = (size_t)(b * T_SEQ + t0) * KDIM + h * HK;
  const size_t baseV  = (size_t)(b * T_SEQ + t0) * VDIM + h * HV;
  const int i0 = (t >> 4) * 4;
  const int j0 = (t & 15) * 4;
  float acc[4][4] = {};
  for (int s = 0; s < 4; ++s) {              // dk slices of 64
    __syncthreads();
    __builtin_amdgcn_sched_barrier(0);
#pragma unroll
    for (int r = 0; r < 4; ++r) {            // stage 64x64 as float4
      int idx = t + 256 * r;
      int row = idx >> 4, c4 = (idx & 15) * 4;
      *(float4*)&qS[row][c4] = *(const float4*)&q[baseQK + (size_t)row * KDIM + s * 64 + c4];
      *(float4*)&kS[row][c4] = *(const float4*)&k[baseQK + (size_t)row * KDIM + s * 64 + c4];
    }
    __syncthreads();
    __builtin_amdgcn_sched_barrier(0);
    for (int d = 0; d < 64; d += 4) {
      float4 a0 = *(const float4*)&qS[i0 + 0][d];
      float4 a1 = *(const float4*)&qS[i0 + 1][d];
      float4 a2 = *(const float4*)&qS[i0 + 2][d];
      float4 a3 = *(const float4*)&qS[i0 + 3][d];
      float4 b0 = *(const float4*)&kS[j0 + 0][d];
      float4 b1 = *(const float4*)&kS[j0 + 1][d];
      float4 b2 = *(const float4*)&kS[j0 + 2][d];
      float4 b3 = *(const float4*)&kS[j0 + 3][d];
      acc[0][0]=fmaf(a0.x,b0.x,acc[0][0]); acc[0][0]=fmaf(a0.y,b0.y,acc[0][0]); acc[0][0]=fmaf(a0.z,b0.z,acc[0][0]); acc[0][0]=fmaf(a0.w,b0.w,acc[0][0]);
      acc[0][1]=fmaf(a0.x,b1.x,acc[0][1]); acc[0][1]=fmaf(a0.y,b1.y,acc[0][1]); acc[0][1]=fmaf(a0.z,b1.z,acc[0][1]); acc[0][1]=fmaf(a0.w,b1.w,acc[0][1]);
      acc[0][2]=fmaf(a0.x,b2.x,acc[0][2]); acc[0][2]=fmaf(a0.y,b2.y,acc[0][2]); acc[0][2]=fmaf(a0.z,b2.z,acc[0][2]); acc[0][2]=fmaf(a0.w,b2.w,acc[0][2]);
      acc[0][3]=fmaf(a0.x,b3.x,acc[0][3]); acc[0][3]=fmaf(a0.y,b3.y,acc[0][3]); acc[0][3]=fmaf(a0.z,b3.z,acc[0][3]); acc[0][3]=fmaf(a0.w,b3.w,acc[0][3]);
      acc[1][0]=fmaf(a1.x,b0.x,acc[1][0]); acc[1][0]=fmaf(a1.y,b0.y,acc[1][0]); acc[1][0]=fmaf(a1.z,b0.z,acc[1][0]); acc[1][0]=fmaf(a1.w,b0.w,acc[1][0]);
      acc[1][1]=fmaf(a1.x,b1.x,acc[1][1]); acc[1][1]=fmaf(a1.y,b1.y,acc[1][1]); acc[1][1]=fmaf(a1.z,b1.z,acc[1][1]); acc[1][1]=fmaf(a1.w,b1.w,acc[1][1]);
      acc[1][2]=fmaf(a1.x,b2.x,acc[1][2]); acc[1][2]=fmaf(a1.y,b2.y,acc[1][2]); acc[1][2]=fmaf(a1.z,b2.z,acc[1][2]); acc[1][2]=fmaf(a1.w,b2.w,acc[1][2]);
      acc[1][3]=fmaf(a1.x,b3.x,acc[1][3]); acc[1][3]=fmaf(a1.y,b3.y,acc[1][3]); acc[1][3]=fmaf(a1.z,b3.z,acc[1][3]); acc[1][3]=fmaf(a1.w,b3.w,acc[1][3]);
      acc[2][0]=fmaf(a2.x,b0.x,acc[2][0]); acc[2][0]=fmaf(a2.y,b0.y,acc[2][0]); acc[2][0]=fmaf(a2.z,b0.z,acc[2][0]); acc[2][0]=fmaf(a2.w,b0.w,acc[2][0]);
      acc[2][1]=fmaf(a2.x,b1.x,acc[2][1]); acc[2][1]=fmaf(a2.y,b1.y,acc[2][1]); acc[2][1]=fmaf(a2.z,b1.z,acc[2][1]); acc[2][1]=fmaf(a2.w,b1.w,acc[2][1]);
      acc[2][2]=fmaf(a2.x,b2.x,acc[2][2]); acc[2][2]=fmaf(a2.y,b2.y,acc[2][2]); acc[2][2]=fmaf(a2.z,b2.z,acc[2][2]); acc[2][2]=fmaf(a2.w,b2.w,acc[2][2]);
      acc[2][3]=fmaf(a2.x,b3.x,acc[2][3]); acc[2][3]=fmaf(a2.y,b3.y,acc[2][3]); acc[2][3]=fmaf(a2.z,b3.z,acc[2][3]); acc[2][3]=fmaf(a2.w,b3.w,acc[2][3]);
      acc[3][0]=fmaf(a3.x,b0.x,acc[3][0]); acc[3][0]=fmaf(a3.y,b0.y,acc[3][0]); acc[3][0]=fmaf(a3.z,b0.z,acc[3][0]); acc[3][0]=fmaf(a3.w,b0.w,acc[3][0]);
      acc[3][1]=fmaf(a3.x,b1.x,acc[3][1]); acc[3][1]=fmaf(a3.y,b1.y,acc[3][1]); acc[3][1]=fmaf(a3.z,b1.z,acc[3][1]); acc[3][1]=fmaf(a3.w,b1.w,acc[3][1]);
      acc[3][2]=fmaf(a3.x,b2.x,acc[3][2]); acc[3][2]=fmaf(a3.y,b2.y,acc[3][2]); acc[3][2]=fmaf(a3.z,b2.z,acc[3][2]); acc[3][2]=fmaf(a3.w,b2.w,acc[3][2]);
      acc[3][3]=fmaf(a3.x,b3.x,acc[3][3]); acc[3][3]=fmaf(a3.y,b3.y,acc[3][3]); acc[3][3]=fmaf(a3.z,b3.z,acc[3][3]); acc[3][3]=fmaf(a3.w,b3.w,acc[3][3]);
    }
  }
  __syncthreads();
#pragma unroll
  for (int ii = 0; ii < 4; ++ii)
#pragma unroll
    for (int jj = 0; jj < 4; ++jj) {
      int i = i0 + ii, j = j0 + jj;
      attnS[i][j] = (i >= j) ? acc[ii][jj] * gpow[i - j] : 0.0f;
    }
  float (*vS)[68] = qS;
  for (int vb = 0; vb < 8; ++vb) {
    __syncthreads();
    __builtin_amdgcn_sched_barrier(0);
#pragma unroll
    for (int r = 0; r < 4; ++r) {
      int idx = t + 256 * r;
      int row = idx >> 4, c4 = (idx & 15) * 4;
      *(float4*)&vS[row][c4] = *(const float4*)&v[baseV + (size_t)row * VDIM + vb * 64 + c4];
    }
    __syncthreads();
    __builtin_amdgcn_sched_barrier(0);
    float oa[4][4] = {};
    for (int j = 0; j < 64; j += 4) {
      float4 p0 = *(const float4*)&attnS[i0 + 0][j];
      float4 p1 = *(const float4*)&attnS[i0 + 1][j];
      float4 p2 = *(const float4*)&attnS[i0 + 2][j];
      float4 p3 = *(const float4*)&attnS[i0 + 3][j];
      float4 v0 = *(const float4*)&vS[j + 0][j0];
      float4 v1 = *(const float4*)&vS[j + 1][j0];
      float4 v2 = *(const float4*)&vS[j + 2][j0];
      float4 v3 = *(const float4*)&vS[j + 3][j0];
      oa[0][0]=fmaf(p0.x,v0.x,oa[0][0]); oa[0][0]=fmaf(p0.y,v1.x,oa[0][0]); oa[0][0]=fmaf(p0.z,v2.x,oa[0][0]); oa[0][0]=fmaf(p0.w,v3.x,oa[0][0]);
      oa[0][1]=fmaf(p0.x,v0.y,oa[0][1]); oa[0][1]=fmaf(p0.y,v1.y,oa[0][1]); oa[0][1]=fmaf(p0.z,v2.y,oa[0][1]); oa[0][1]=fmaf(p0.w,v3.y,oa[0][1]);
      oa[0][2]=fmaf(p0.x,v0.z,oa[0][2]); oa[0][2]=fmaf(p0.y,v1.z,oa[0][2]); oa[0][2]=fmaf(p0.z,v2.z,oa[0][2]); oa[0][2]=fmaf(p0.w,v3.z,oa[0][2]);
      oa[0][3]=fmaf(p0.x,v0.w,oa[0][3]); oa[0][3]=fmaf(p0.y,v1.w,oa[0][3]); oa[0][3]=fmaf(p0.z,v2.w,oa[0][3]); oa[0][3]=fmaf(p0.w,v3.w,oa[0][3]);
      oa[1][0]=fmaf(p1.x,v0.x,oa[1][0]); oa[1][0]=fmaf(p1.y,v1.x,oa[1][0]); oa[1][0]=fmaf(p1.z,v2.x,oa[1][0]); oa[1][0]=fmaf(p1.w,v3.x,oa[1][0]);
      oa[1][1]=fmaf(p1.x,v0.y,oa[1][1]); oa[1][1]=fmaf(p1.y,v1.y,oa[1][1]); oa[1][1]=fmaf(p1.z,v2.y,oa[1][1]); oa[1][1]=fmaf(p1.w,v3.y,oa[1][1]);
      oa[1][2]=fmaf(p1.x,v0.z,oa[1][2]); oa[1][2]=fmaf(p1.y,v1.z,oa[1][2]); oa[1][2]=fmaf(p1.z,v2.z,oa[1][2]); oa[1][2]=fmaf(p1.w,v3.z,oa[1][2]);
      oa[1][3]=fmaf(p1.x,v0.w,oa[1][3]); oa[1][3]=fmaf(p1.y,v1.w,oa[1][3]); oa[1][3]=fmaf(p1.z,v2.w,oa[1][3]); oa[1][3]=fmaf(p1.w,v3.w,oa[1][3]);
      oa[2][0]=fmaf(p2.x,v0.x,oa[2][0]); oa[2][0]=fmaf(p2.y,v1.x,oa[2][0]); oa[2][0]=fmaf(p2.z,v2.x,oa[2][0]); oa[2][0]=fmaf(p2.w,v3.x,oa[2][0]);
      oa[2][1]=fmaf(p2.x,v0.y,oa[2][1]); oa[2][1]=fmaf(p2.y,v1.y,oa[2][1]); oa[2][1]=fmaf(p2.z,v2.y,oa[2][1]); oa[2][1]=fmaf(p2.w,v3.y,oa[2][1]);
      oa[2][2]=fmaf(p2.x,v0.z,oa[2][2]); oa[2][2]=fmaf(p2.y,v1.z,oa[2][2]); oa[2][2]=fmaf(p2.z,v2.z,oa[2][2]); oa[2][2]=fmaf(p2.w,v3.z,oa[2][2]);
      oa[2][3]=fmaf(p2.x,v0.w,oa[2][3]); oa[2][3]=fmaf(p2.y,v1.w,oa[2][3]); oa[2][3]=fmaf(p2.z,v2.w,oa[2][3]); oa[2][3]=fmaf(p2.w,v3.w,oa[2][3]);
      oa[3][0]=fmaf(p3.x,v0.x,oa[3][0]); oa[3][0]=fmaf(p3.y,v1.x,oa[3][0]); oa[3][0]=fmaf(p3.z,v2.x,oa[3][0]); oa[3][0]=fmaf(p3.w,v3.x,oa[3][0]);
      oa[3][1]=fmaf(p3.x,v0.y,oa[3][1]); oa[3][1]=fmaf(p3.y,v1.y,oa[3][1]); oa[3][1]=fmaf(p3.z,v2.y,oa[3][1]); oa[3][1]=fmaf(p3.w,v3.y,oa[3][1]);
      oa[3][2]=fmaf(p3.x,v0.z,oa[3][2]); oa[3][2]=fmaf(p3.y,v1.z,oa[3][2]); oa[3][2]=fmaf(p3.z,v2.z,oa[3][2]); oa[3][2]=fmaf(p3.w,v3.z,oa[3][2]);
      oa[3][3]=fmaf(p3.x,v0.w,oa[3][3]); oa[3][3]=fmaf(p3.y,v1.w,oa[3][3]); oa[3][3]=fmaf(p3.z,v2.w,oa[3][3]); oa[3][3]=fmaf(p3.w,v3.w,oa[3][3]);
    }
#pragma unroll
    for (int ii = 0; ii < 4; ++ii)
      *(float4*)&o[baseV + (size_t)(i0 + ii) * VDIM + vb * 64 + j0] =
          make_float4(oa[ii][0], oa[ii][1], oa[ii][2], oa[ii][3]);
  }
}

// =================== Retention inter-chunk: two-level scan ===================
//   A) retn_gstate: per (b,h,group of 8 chunks) local state sums T_g (g=0..2).
//   B) retn_scan: elementwise exclusive scan over groups: T_g -> S_in[g+1].
//   C) retn_inter2: per (b,h,g,dv-tile64) WG carries full dk=256 state in regs
//      (64/thread), seeded from S_in[g]; 8-chunk serial scan; o updated with
//      plain load+add+store (sole writer, NO atomics).
// ROUND-6 POST-MORTEM: 268us, VGPR 112, VALUBusy 56% -- at ~81% of the LDS
// bandwidth roofline for this data movement (65.5K b128/CU x 8-12cyc).
// Round-7 adds only a block-uniform skip of the dead o-phase at g==0&&c==0
// (S==0); barriers remain unconditional.

// ---- pass A: group-local state sums --------------------------------------
__global__ __launch_bounds__(256) void retn_gstate(const float* __restrict__ k,
                                                   const float* __restrict__ v,
                                                   float* __restrict__ Tbuf) {
  // grid (16, 3, 32): x = b*4+h, y = g (0..2), z: dkt = z>>3, dvt = z&7
  const int bh = blockIdx.x; const int b = bh >> 2, h = bh & 3;
  const int g = blockIdx.y;
  const int dkt = blockIdx.z >> 3, dvt = blockIdx.z & 7;
  const int t = threadIdx.x;
  __shared__ float gpow[65];
  __shared__ __align__(16) float kS[64][68];
  __shared__ __align__(16) float vS[64][68];
  if (t <= 64) gpow[t] = powf(1.0f - exp2f(-5.0f - (float)h), (float)t);
  __syncthreads();
  const float gC = gpow[64];
  const size_t baseK = (size_t)(b * T_SEQ + g * 512) * KDIM + h * HK + dkt * 64;
  const size_t baseV = (size_t)(b * T_SEQ + g * 512) * VDIM + h * HV + dvt * 64;
  const int dk0 = (t & 15) * 4, c0 = (t >> 4) * 4;
  float S[4][4] = {};
  for (int c = 0; c < 8; ++c) {
    const int t0 = c * 64;
    __syncthreads();
    __builtin_amdgcn_sched_barrier(0);
#pragma unroll
    for (int r = 0; r < 4; ++r) {
      int idx = t + 256 * r; int row = idx >> 4, c4 = (idx & 15) * 4;
      float4 kv = *(const float4*)&k[baseK + (size_t)(t0 + row) * KDIM + c4];
      float kd = gpow[63 - row];
      kv.x *= kd; kv.y *= kd; kv.z *= kd; kv.w *= kd;
      *(float4*)&kS[row][c4] = kv;
      *(float4*)&vS[row][c4] = *(const float4*)&v[baseV + (size_t)(t0 + row) * VDIM + c4];
    }
    __syncthreads();
    __builtin_amdgcn_sched_barrier(0);
#pragma unroll
    for (int ii = 0; ii < 4; ++ii)
#pragma unroll
      for (int jj = 0; jj < 4; ++jj) S[ii][jj] *= gC;
    for (int j = 0; j < 64; ++j) {
      float4 kv = *(const float4*)&kS[j][dk0];
      float4 vv = *(const float4*)&vS[j][c0];
      S[0][0] = fmaf(kv.x, vv.x, S[0][0]); S[0][1] = fmaf(kv.x, vv.y, S[0][1]);
      S[0][2] = fmaf(kv.x, vv.z, S[0][2]); S[0][3] = fmaf(kv.x, vv.w, S[0][3]);
      S[1][0] = fmaf(kv.y, vv.x, S[1][0]); S[1][1] = fmaf(kv.y, vv.y, S[1][1]);
      S[1][2] = fmaf(kv.y, vv.z, S[1][2]); S[1][3] = fmaf(kv.y, vv.w, S[1][3]);
      S[2][0] = fmaf(kv.z, vv.x, S[2][0]); S[2][1] = fmaf(kv.z, vv.y, S[2][1]);
      S[2][2] = fmaf(kv.z, vv.z, S[2][2]); S[2][3] = fmaf(kv.z, vv.w, S[2][3]);
      S[3][0] = fmaf(kv.w, vv.x, S[3][0]); S[3][1] = fmaf(kv.w, vv.y, S[3][1]);
      S[3][2] = fmaf(kv.w, vv.z, S[3][2]); S[3][3] = fmaf(kv.w, vv.w, S[3][3]);
    }
  }
  const size_t tb = (((size_t)g * 16 + bh) * 256 + dkt * 64 + dk0) * 512 + (size_t)dvt * 64 + c0;
#pragma unroll
  for (int ii = 0; ii < 4; ++ii)
    *(float4*)&Tbuf[tb + (size_t)ii * 512] = make_float4(S[ii][0], S[ii][1], S[ii][2], S[ii][3]);
}

// ---- pass B: exclusive scan over the 4 groups (in-place) ------------------
__global__ __launch_bounds__(256) void retn_scan(float* __restrict__ Tbuf) {
  int i = blockIdx.x * 256 + threadIdx.x;   // float4 index within one g-slab
  int h = (i >> 15) & 3;                    // (i*4)>>17 & 3
  float gamma = 1.0f - exp2f(-5.0f - (float)h);
  float gG = powf(gamma, 512.0f);           // gC^8 = gamma^(64*8)
  float4* T = (float4*)Tbuf;
  const int slab = 524288;                  // 16*256*512/4
  float4 t0 = T[i], t1 = T[i + slab], t2 = T[i + 2 * slab];
  float4 s2, s3;
  s2.x = fmaf(gG, t0.x, t1.x); s2.y = fmaf(gG, t0.y, t1.y);
  s2.z = fmaf(gG, t0.z, t1.z); s2.w = fmaf(gG, t0.w, t1.w);
  s3.x = fmaf(gG, s2.x, t2.x); s3.y = fmaf(gG, s2.y, t2.y);
  s3.z = fmaf(gG, s2.z, t2.z); s3.w = fmaf(gG, s2.w, t2.w);
  T[i + slab] = s2; T[i + 2 * slab] = s3;
}

// ---- pass C: inter-chunk output, full-dk state in regs, no atomics --------
__global__ __launch_bounds__(256) void retn_inter2(const float* __restrict__ q,
                                                   const float* __restrict__ k,
                                                   const float* __restrict__ v,
                                                   float* __restrict__ o,
                                                   const float* __restrict__ Sbuf) {
  // grid (16, 4, 8): x = b*4+h, y = g, z = dvt (64-wide dv tiles)
  const int bh = blockIdx.x; const int b = bh >> 2, h = bh & 3;
  const int g = blockIdx.y;
  const int dvt = blockIdx.z;
  const int t = threadIdx.x;
  __shared__ float gpow[65];
  __shared__ __align__(16) float qS[64][68];  // q~ block (64x64)
  __shared__ __align__(16) float kS[64][68];  // k~ block (64x64)
  __shared__ __align__(16) float sS[64][68];  // state-block publish (64x64)
  __shared__ __align__(16) float vS[64][68];  // v chunk (64x64)
  if (t <= 64) gpow[t] = powf(1.0f - exp2f(-5.0f - (float)h), (float)t);
  __syncthreads();
  const float gC = gpow[64];
  const int rq = (t & 15) * 4;   // state rows within a dk-block (publish/j-loop)
  const int c0 = (t >> 4) * 4;   // state cols (0,4,..,60)
  const int i0 = (t >> 4) * 4;   // o-tile rows
  const int v0 = (t & 15) * 4;   // o-tile cols
  const size_t baseQK = (size_t)(b * T_SEQ + g * 512) * KDIM + h * HK;
  const size_t baseV  = (size_t)(b * T_SEQ + g * 512) * VDIM + h * HV + (size_t)dvt * 64;

  // S: 64 regs/thread, compile-time indices only, never address-taken.
  float S[4][4][4];              // [dk-block][row][col]; cols c0..c0+3
  if (g > 0) {
    const size_t sb = (((size_t)(g - 1) * 16 + bh) * 256) * 512 + (size_t)dvt * 64 + c0;
#pragma unroll
    for (int b4 = 0; b4 < 4; ++b4)
#pragma unroll
      for (int i = 0; i < 4; ++i) {
        float4 tmp = *(const float4*)&Sbuf[sb + (size_t)(b4 * 64 + rq + i) * 512];
        S[b4][i][0] = tmp.x; S[b4][i][1] = tmp.y; S[b4][i][2] = tmp.z; S[b4][i][3] = tmp.w;
      }
  } else {
#pragma unroll
    for (int b4 = 0; b4 < 4; ++b4)
#pragma unroll
      for (int i = 0; i < 4; ++i) {
        S[b4][i][0] = 0.f; S[b4][i][1] = 0.f; S[b4][i][2] = 0.f; S[b4][i][3] = 0.f;
      }
  }

  for (int c = 0; c < 8; ++c) {
    const int t0 = c * 64;
    const bool doO = (g > 0 || c > 0);     // block-uniform; S==0 otherwise
    __syncthreads();                       // prev chunk's vS readers done
    __builtin_amdgcn_sched_barrier(0);
#pragma unroll
    for (int r = 0; r < 4; ++r) {          // stage v chunk 64x64
      int idx = t + 256 * r; int row = idx >> 4, c4 = (idx & 15) * 4;
      *(float4*)&vS[row][c4] = *(const float4*)&v[baseV + (size_t)(t0 + row) * VDIM + c4];
    }
    float oa[4][4] = {};
#pragma unroll
    for (int b4 = 0; b4 < 4; ++b4) {
      __syncthreads();                     // prev b4's qS/kS/sS readers done (covers vS write at b4=0)
      __builtin_amdgcn_sched_barrier(0);
      if (doO) {
        // publish this dk-block of S (OLD state) for the o-phase
#pragma unroll
        for (int i = 0; i < 4; ++i)
          *(float4*)&sS[rq + i][c0] =
              make_float4(S[b4][i][0], S[b4][i][1], S[b4][i][2], S[b4][i][3]);
        // stage q~ block (64x64), scaled by cross_dec
#pragma unroll
        for (int r = 0; r < 4; ++r) {
          int idx = t + 256 * r; int row = idx >> 4, c4 = (idx & 15) * 4;
          float4 qv = *(const float4*)&q[baseQK + (size_t)(t0 + row) * KDIM + b4 * 64 + c4];
          float gp = gpow[row + 1];
          qv.x *= gp; qv.y *= gp; qv.z *= gp; qv.w *= gp;
          *(float4*)&qS[row][c4] = qv;
        }
      }
      // stage k~ block (64x64), scaled by k_dec
#pragma unroll
      for (int r = 0; r < 4; ++r) {
        int idx = t + 256 * r; int row = idx >> 4, c4 = (idx & 15) * 4;
        float4 kv = *(const float4*)&k[baseQK + (size_t)(t0 + row) * KDIM + b4 * 64 + c4];
        float kd = gpow[63 - row];
        kv.x *= kd; kv.y *= kd; kv.z *= kd; kv.w *= kd;
        *(float4*)&kS[row][c4] = kv;
      }
      __syncthreads();
      __builtin_amdgcn_sched_barrier(0);
      if (doO) {
        // o-phase: oa += q~S(64x64) @ sS(64x64), this thread: 4 rows x 4 cols
        for (int d = 0; d < 64; d += 4) {
          float4 a0 = *(const float4*)&qS[i0 + 0][d];
          float4 a1 = *(const float4*)&qS[i0 + 1][d];
          float4 a2 = *(const float4*)&qS[i0 + 2][d];
          float4 a3 = *(const float4*)&qS[i0 + 3][d];
          float4 s0 = *(const float4*)&sS[d + 0][v0];
          float4 s1 = *(const float4*)&sS[d + 1][v0];
          float4 s2 = *(const float4*)&sS[d + 2][v0];
          float4 s3 = *(const float4*)&sS[d + 3][v0];
          oa[0][0]=fmaf(a0.x,s0.x,oa[0][0]); oa[0][0]=fmaf(a0.y,s1.x,oa[0][0]); oa[0][0]=fmaf(a0.z,s2.x,oa[0][0]); oa[0][0]=fmaf(a0.w,s3.x,oa[0][0]);
          oa[0][1]=fmaf(a0.x,s0.y,oa[0][1]); oa[0][1]=fmaf(a0.y,s1.y,oa[0][1]); oa[0][1]=fmaf(a0.z,s2.y,oa[0][1]); oa[0][1]=fmaf(a0.w,s3.y,oa[0][1]);
          oa[0][2]=fmaf(a0.x,s0.z,oa[0][2]); oa[0][2]=fmaf(a0.y,s1.z,oa[0][2]); oa[0][2]=fmaf(a0.z,s2.z,oa[0][2]); oa[0][2]=fmaf(a0.w,s3.z,oa[0][2]);
          oa[0][3]=fmaf(a0.x,s0.w,oa[0][3]); oa[0][3]=fmaf(a0.y,s1.w,oa[0][3]); oa[0][3]=fmaf(a0.z,s2.w,oa[0][3]); oa[0][3]=fmaf(a0.w,s3.w,oa[0][3]);
          oa[1][0]=fmaf(a1.x,s0.x,oa[1][0]); oa[1][0]=fmaf(a1.y,s1.x,oa[1][0]); oa[1][0]=fmaf(a1.z,s2.x,oa[1][0]); oa[1][0]=fmaf(a1.w,s3.x,oa[1][0]);
          oa[1][1]=fmaf(a1.x,s0.y,oa[1][1]); oa[1][1]=fmaf(a1.y,s1.y,oa[1][1]); oa[1][1]=fmaf(a1.z,s2.y,oa[1][1]); oa[1][1]=fmaf(a1.w,s3.y,oa[1][1]);
          oa[1][2]=fmaf(a1.x,s0.z,oa[1][2]); oa[1][2]=fmaf(a1.y,s1.z,oa[1][2]); oa[1][2]=fmaf(a1.z,s2.z,oa[1][2]); oa[1][2]=fmaf(a1.w,s3.z,oa[1][2]);
          oa[1][3]=fmaf(a1.x,s0.w,oa[1][3]); oa[1][3]=fmaf(a1.y,s1.w,oa[1][3]); oa[1][3]=fmaf(a1.z,s2.w,oa[1][3]); oa[1][3]=fmaf(a1.w,s3.w,oa[1][3]);
          oa[2][0]=fmaf(a2.x,s0.x,oa[2][0]); oa[2][0]=fmaf(a2.y,s1.x,oa[2][0]); oa[2][0]=fmaf(a2.z,s2.x,oa[2][0]); oa[2][0]=fmaf(a2.w,s3.x,oa[2][0]);
          oa[2][1]=fmaf(a2.x,s0.y,oa[2][1]); oa[2][1]=fmaf(a2.y,s1.y,oa[2][1]); oa[2][1]=fmaf(a2.z,s2.y,oa[2][1]); oa[2][1]=fmaf(a2.w,s3.y,oa[2][1]);
          oa[2][2]=fmaf(a2.x,s0.z,oa[2][2]); oa[2][2]=fmaf(a2.y,s1.z,oa[2][2]); oa[2][2]=fmaf(a2.z,s2.z,oa[2][2]); oa[2][2]=fmaf(a2.w,s3.z,oa[2][2]);
          oa[2][3]=fmaf(a2.x,s0.w,oa[2][3]); oa[2][3]=fmaf(a2.y,s1.w,oa[2][3]); oa[2][3]=fmaf(a2.z,s2.w,oa[2][3]); oa[2][3]=fmaf(a2.w,s3.w,oa[2][3]);
          oa[3][0]=fmaf(a3.x,s0.x,oa[3][0]); oa[3][0]=fmaf(a3.y,s1.x,oa[3][0]); oa[3][0]=fmaf(a3.z,s2.x,oa[3][0]); oa[3][0]=fmaf(a3.w,s3.x,oa[3][0]);
          oa[3][1]=fmaf(a3.x,s0.y,oa[3][1]); oa[3][1]=fmaf(a3.y,s1.y,oa[3][1]); oa[3][1]=fmaf(a3.z,s2.y,oa[3][1]); oa[3][1]=fmaf(a3.w,s3.y,oa[3][1]);
          oa[3][2]=fmaf(a3.x,s0.z,oa[3][2]); oa[3][2]=fmaf(a3.y,s1.z,oa[3][2]); oa[3][2]=fmaf(a3.z,s2.z,oa[3][2]); oa[3][2]=fmaf(a3.w,s3.z,oa[3][2]);
          oa[3][3]=fmaf(a3.x,s0.w,oa[3][3]); oa[3][3]=fmaf(a3.y,s1.w,oa[3][3]); oa[3][3]=fmaf(a3.z,s2.w,oa[3][3]); oa[3][3]=fmaf(a3.w,s3.w,oa[3][3]);
        }
      }
      // update: S[b4] = gC*S[b4] + k~^T v (rows rq..rq+3, cols c0..c0+3)
#pragma unroll
      for (int ii = 0; ii < 4; ++ii) {
        S[b4][ii][0] *= gC; S[b4][ii][1] *= gC; S[b4][ii][2] *= gC; S[b4][ii][3] *= gC;
      }
      for (int j = 0; j < 64; ++j) {
        float4 kv = *(const float4*)&kS[j][rq];
        float4 vv = *(const float4*)&vS[j][c0];
        S[b4][0][0] = fmaf(kv.x, vv.x, S[b4][0][0]); S[b4][0][1] = fmaf(kv.x, vv.y, S[b4][0][1]);
        S[b4][0][2] = fmaf(kv.x, vv.z, S[b4][0][2]); S[b4][0][3] = fmaf(kv.x, vv.w, S[b4][0][3]);
        S[b4][1][0] = fmaf(kv.y, vv.x, S[b4][1][0]); S[b4][1][1] = fmaf(kv.y, vv.y, S[b4][1][1]);
        S[b4][1][2] = fmaf(kv.y, vv.z, S[b4][1][2]); S[b4][1][3] = fmaf(kv.y, vv.w, S[b4][1][3]);
        S[b4][2][0] = fmaf(kv.z, vv.x, S[b4][2][0]); S[b4][2][1] = fmaf(kv.z, vv.y, S[b4][2][1]);
        S[b4][2][2] = fmaf(kv.z, vv.z, S[b4][2][2]); S[b4][2][3] = fmaf(kv.z, vv.w, S[b4][2][3]);
        S[b4][3][0] = fmaf(kv.w, vv.x, S[b4][3][0]); S[b4][3][1] = fmaf(kv.w, vv.y, S[b4][3][1]);
        S[b4][3][2] = fmaf(kv.w, vv.z, S[b4][3][2]); S[b4][3][3] = fmaf(kv.w, vv.w, S[b4][3][3]);
      }
    }
    // o += oa (skipped when S was all-zero: oa == 0)
    if (doO) {
#pragma unroll
      for (int ii = 0; ii < 4; ++ii) {
        size_t addr = baseV + (size_t)(t0 + i0 + ii) * VDIM + v0;
        float4 ov = *(const float4*)&o[addr];
        ov.x += oa[ii][0]; ov.y += oa[ii][1]; ov.z += oa[ii][2]; ov.w += oa[ii][3];
        *(float4*)&o[addr] = ov;
      }
    }
  }
}

// ------- RMS group-norm + SiLU(g) gate + bf16 hi/lo split (fused) ------------
// Writes oh/ol directly; gated o never materialized in f32 (saves 128MB HBM).
// Same ops in the same order as the previous norm_gate + cast_split pair.
__global__ __launch_bounds__(256) void norm_gate_cast(const float* __restrict__ o,
                                                      const float* __restrict__ g,
                                                      const float* __restrict__ gnw,
                                                      unsigned short* __restrict__ oh,
                                                      unsigned short* __restrict__ ol) {
  const int row = blockIdx.x;
  const size_t base = (size_t)row * 512;
  const int t = threadIdx.x;
  float x0 = o[base + t], x1 = o[base + t + 256];
  float ss = x0 * x0 + x1 * x1;
#pragma unroll
  for (int off = 32; off > 0; off >>= 1) ss += __shfl_down(ss, off, 64);
  __shared__ float wsum[4];
  if ((t & 63) == 0) wsum[t >> 6] = ss;
  __syncthreads();
  float tot = wsum[0] + wsum[1] + wsum[2] + wsum[3];
  float scale = rsqrtf(tot * (1.0f / 512.0f) + 1e-5f);
  float g0 = g[base + t], g1 = g[base + t + 256];
  float r0 = x0 * scale * gnw[t]       * (g0 / (1.0f + expf(-g0)));
  float r1 = x1 * scale * gnw[t + 256] * (g1 / (1.0f + expf(-g1)));
  unsigned short h0 = f2bf(r0);
  unsigned short h1 = f2bf(r1);
  oh[base + t]       = h0; ol[base + t]       = f2bf(r0 - bf2f(h0));
  oh[base + t + 256] = h1; ol[base + t + 256] = f2bf(r1 - bf2f(h1));
}

extern "C" void kernel_launch(void* const* d_in, const int* in_sizes, int n_in,
                              void* d_out, int out_size, void* d_ws, size_t ws_size,
                              hipStream_t stream) {
  const float* x   = (const float*)d_in[0];
  const float* Wq  = (const float*)d_in[1];
  const float* Wk  = (const float*)d_in[2];
  const float* Wv  = (const float*)d_in[3];
  const float* Wg  = (const float*)d_in[4];
  const float* Wo  = (const float*)d_in[5];
  const float* gnw = (const float*)d_in[6];
  float* out = (float*)d_out;

  // workspace = 256 MiB exactly:
  // [q 32][k 32][v 64][o 64][x-splits 32][W-splits 32]
  // o-splits (64) alias dead v; g (64) aliases dead q+k.
  // d_out (32 MiB) doubles as group-state scratch (24 MiB) until final GEMM.
  const size_t M8 = (size_t)8192;
  float* q  = (float*)d_ws;
  float* kk = q  + M8 * 1024;
  float* v  = kk + M8 * 1024;
  float* o  = v  + M8 * 2048;
  unsigned short* xh  = (unsigned short*)(o + M8 * 2048);
  unsigned short* xl  = xh  + M8 * 1024;
  unsigned short* wqh = xl  + M8 * 1024;
  unsigned short* wql = wqh + (size_t)1024 * 1024;
  unsigned short* wkh = wql + (size_t)1024 * 1024;
  unsigned short* wkl = wkh + (size_t)1024 * 1024;
  unsigned short* wvh = wkl + (size_t)1024 * 1024;
  unsigned short* wvl = wvh + (size_t)2048 * 1024;
  unsigned short* wgh = wvl + (size_t)2048 * 1024;
  unsigned short* wgl = wgh + (size_t)2048 * 1024;
  unsigned short* woh = wgl + (size_t)2048 * 1024;
  unsigned short* wol = woh + (size_t)2048 * 1024;
  unsigned short* oh  = (unsigned short*)v;
  unsigned short* ol  = oh + M8 * 2048;
  float* g = q;
  float* Tbuf = (float*)d_out;   // 24 MiB scratch, dead until final GEMM

  dim3 blk(256);
  cast_split<<<dim3(8192), blk, 0, stream>>>(x,  xh,  xl,  2097152);
  cast_split<<<dim3(1024), blk, 0, stream>>>(Wq, wqh, wql, 262144);
  cast_split<<<dim3(1024), blk, 0, stream>>>(Wk, wkh, wkl, 262144);
  cast_split<<<dim3(2048), blk, 0, stream>>>(Wv, wvh, wvl, 524288);
  cast_split<<<dim3(2048), blk, 0, stream>>>(Wg, wgh, wgl, 524288);
  cast_split<<<dim3(2048), blk, 0, stream>>>(Wo, woh, wol, 524288);

  gemm_qkv<<<dim3(32, 64), blk, 0, stream>>>(xh, xl, wqh, wql, wkh, wkl, wvh, wvl, q, kk, v);
  rope_kernel<<<dim3(16384), blk, 0, stream>>>(q, kk);
  retn_gstate<<<dim3(16, 3, 32), blk, 0, stream>>>(kk, v, Tbuf);
  retn_scan<<<dim3(2048), blk, 0, stream>>>(Tbuf);
  retn_intra<<<dim3(32, 4, 4),  blk, 0, stream>>>(q, kk, v, o);
  retn_inter2<<<dim3(16, 4, 8), blk, 0, stream>>>(q, kk, v, o, Tbuf);
  gemm_bf16s<<<dim3(16, 64), blk, 0, stream>>>(xh, xl, wgh, wgl, g, 8192, 2048, 1024);
  norm_gate_cast<<<dim3(32768), blk, 0, stream>>>(o, g, gnw, oh, ol);
  gemm_bf16s<<<dim3(8, 64),  blk, 0, stream>>>(oh, ol, woh, wol, out, 8192, 1024, 2048);
}